// Round 1
// baseline (1134.842 us; speedup 1.0000x reference)
//
#include <hip/hip_runtime.h>
#include <math.h>

#define B_  64
#define E_  32
#define L_  512
#define D_  768
#define C_  1024
#define H_  8
#define EG_ 32768
#define SH_ 512
#define N_  2048   // B*E

// ---------------------------------------------------------------- helpers

__global__ void k_att_init(const float* __restrict__ b2, float* __restrict__ att) {
  int i = blockIdx.x * 256 + threadIdx.x;   // grid 128 -> 32768
  att[i] = b2[0];
}

// ------------------------------------------------- span MLP (fused GEMM)
// att[row] += sum_j relu( X[row]@W1[:,j] + b1[j] ) * W2[j]
// 128 rows x 128 cols per block; grid = 256 rowblocks * 4 colblocks.
__global__ void k_span(const float* __restrict__ X, const float* __restrict__ W1,
                       const float* __restrict__ b1, const float* __restrict__ W2,
                       float* __restrict__ att) {
  int rb = blockIdx.x & 255, cb = blockIdx.x >> 8;
  int row0 = rb * 128, col0 = cb * 128;
  __shared__ __align__(16) float Xs[8][132];
  __shared__ __align__(16) float Ws[8][132];
  int tid = threadIdx.x;
  int tr = tid >> 4, tc = tid & 15;
  float acc[64];
#pragma unroll
  for (int i = 0; i < 64; i++) acc[i] = 0.f;

  int lr = tid >> 1, kq = (tid & 1) * 4;     // X staging: 128 rows x 8 k
  int lk = tid >> 5, c4 = (tid & 31) * 4;    // W staging: 8 k x 128 cols

  for (int k0 = 0; k0 < D_; k0 += 8) {
    float4 xv = *(const float4*)&X[(row0 + lr) * D_ + k0 + kq];
    Xs[kq + 0][lr] = xv.x; Xs[kq + 1][lr] = xv.y;
    Xs[kq + 2][lr] = xv.z; Xs[kq + 3][lr] = xv.w;
    *(float4*)&Ws[lk][c4] = *(const float4*)&W1[(k0 + lk) * SH_ + col0 + c4];
    __syncthreads();
#pragma unroll
    for (int kk = 0; kk < 8; kk++) {
      float4 a0 = *(const float4*)&Xs[kk][tr * 8];
      float4 a1 = *(const float4*)&Xs[kk][tr * 8 + 4];
      float4 b0 = *(const float4*)&Ws[kk][tc * 8];
      float4 b1v = *(const float4*)&Ws[kk][tc * 8 + 4];
      float av[8] = {a0.x, a0.y, a0.z, a0.w, a1.x, a1.y, a1.z, a1.w};
      float bv[8] = {b0.x, b0.y, b0.z, b0.w, b1v.x, b1v.y, b1v.z, b1v.w};
#pragma unroll
      for (int i = 0; i < 8; i++)
#pragma unroll
        for (int j = 0; j < 8; j++) acc[i * 8 + j] += av[i] * bv[j];
    }
    __syncthreads();
  }
  // epilogue: +b1, relu, dot with W2 -> per-row partial
  float rp[8];
#pragma unroll
  for (int i = 0; i < 8; i++) rp[i] = 0.f;
#pragma unroll
  for (int j = 0; j < 8; j++) {
    int col = col0 + tc * 8 + j;
    float bb = b1[col], w2 = W2[col];
#pragma unroll
    for (int i = 0; i < 8; i++) {
      float h = acc[i * 8 + j] + bb;
      h = h > 0.f ? h : 0.f;
      rp[i] += h * w2;
    }
  }
#pragma unroll
  for (int o = 8; o; o >>= 1)
#pragma unroll
    for (int i = 0; i < 8; i++) rp[i] += __shfl_xor(rp[i], o);
  if (tc == 0) {
#pragma unroll
    for (int i = 0; i < 8; i++) atomicAdd(&att[row0 + tr * 8 + i], rp[i]);
  }
}

// ------------------------------------------------- masked-softmax pooling
// grid: (b, group-of-8-edus) = 64*4 blocks; computes node0 rows.
__global__ void k_pool(const float* __restrict__ lh, const float* __restrict__ att,
                       const float* __restrict__ mask, float* __restrict__ node0) {
  int bi = blockIdx.x >> 2, eg4 = blockIdx.x & 3;
  int tid = threadIdx.x;
  __shared__ float probs[8][512];
  __shared__ float red[4];
  float a0 = att[bi * L_ + tid];
  float a1 = att[bi * L_ + 256 + tid];
  for (int ei = 0; ei < 8; ei++) {
    int e = eg4 * 8 + ei;
    const float* mrow = &mask[(bi * E_ + e) * L_];
    float l0 = a0 - 1e5f * (1.f - mrow[tid]);
    float l1 = a1 - 1e5f * (1.f - mrow[256 + tid]);
    float mx = fmaxf(l0, l1);
#pragma unroll
    for (int o = 32; o; o >>= 1) mx = fmaxf(mx, __shfl_xor(mx, o));
    if ((tid & 63) == 0) red[tid >> 6] = mx;
    __syncthreads();
    mx = fmaxf(fmaxf(red[0], red[1]), fmaxf(red[2], red[3]));
    __syncthreads();
    float e0 = expf(l0 - mx), e1 = expf(l1 - mx);
    float s = e0 + e1;
#pragma unroll
    for (int o = 32; o; o >>= 1) s += __shfl_xor(s, o);
    if ((tid & 63) == 0) red[tid >> 6] = s;
    __syncthreads();
    s = red[0] + red[1] + red[2] + red[3];
    float inv = 1.f / s;
    probs[ei][tid] = e0 * inv;
    probs[ei][256 + tid] = e1 * inv;
    __syncthreads();
  }
  float acc0[8], acc1[8], acc2[8];
#pragma unroll
  for (int e = 0; e < 8; e++) { acc0[e] = 0.f; acc1[e] = 0.f; acc2[e] = 0.f; }
  const float* lb = &lh[bi * L_ * D_];
  for (int l = 0; l < L_; l++) {
    float v0 = lb[l * D_ + tid];
    float v1 = lb[l * D_ + 256 + tid];
    float v2 = lb[l * D_ + 512 + tid];
#pragma unroll
    for (int e = 0; e < 8; e++) {
      float p = probs[e][l];
      acc0[e] += p * v0; acc1[e] += p * v1; acc2[e] += p * v2;
    }
  }
#pragma unroll
  for (int e = 0; e < 8; e++) {
    float* orow = &node0[(bi * E_ + eg4 * 8 + e) * D_];
    orow[tid] = acc0[e]; orow[256 + tid] = acc1[e]; orow[512 + tid] = acc2[e];
  }
}

// -------------------------------------- 10-combo edge embedding @ We
// out[c][j] = sum_k (t(c)*Wr[k]+m(c)*Wm[k]+br[k]+bm[k]) * eW[k][j]
__global__ void k_combo(const float* __restrict__ Wr, const float* __restrict__ br,
                        const float* __restrict__ Wm, const float* __restrict__ bm,
                        const float* __restrict__ eW, float* __restrict__ out) {
  int j = blockIdx.x * 256 + threadIdx.x;  // grid 4 -> 1024 cols
  __shared__ float ea[10][1024];
  for (int i = threadIdx.x; i < 1024; i += 256) {
    float wr = Wr[i], wm = Wm[i], bs = br[i] + bm[i];
#pragma unroll
    for (int c = 0; c < 10; c++) ea[c][i] = (float)(c >> 1) * wr + (float)(c & 1) * wm + bs;
  }
  __syncthreads();
  float acc[10];
#pragma unroll
  for (int c = 0; c < 10; c++) acc[c] = 0.f;
  for (int kk = 0; kk < 1024; kk++) {
    float w = eW[kk * 1024 + j];
#pragma unroll
    for (int c = 0; c < 10; c++) acc[c] += ea[c][kk] * w;
  }
#pragma unroll
  for (int c = 0; c < 10; c++) out[c * 1024 + j] = acc[c];
}

// ------------------------------------------------- CSR build
__global__ void k_count(const int* __restrict__ dst, int* __restrict__ cnt) {
  int eg = blockIdx.x * 256 + threadIdx.x;  // grid 128
  atomicAdd(&cnt[dst[eg]], 1);
}

__global__ void k_scan(const int* __restrict__ cnt, int* __restrict__ off) {
  __shared__ int part[256];
  int t = threadIdx.x;
  int local[8]; int s = 0;
#pragma unroll
  for (int i = 0; i < 8; i++) { local[i] = cnt[t * 8 + i]; s += local[i]; }
  part[t] = s;
  __syncthreads();
  if (t == 0) {
    int r = 0;
    for (int i = 0; i < 256; i++) { int v = part[i]; part[i] = r; r += v; }
    off[N_] = r;
  }
  __syncthreads();
  int r = part[t];
#pragma unroll
  for (int i = 0; i < 8; i++) { off[t * 8 + i] = r; r += local[i]; }
}

__global__ void k_scatter(const int* __restrict__ dst, int* __restrict__ wcnt,
                          const int* __restrict__ off, int* __restrict__ perm) {
  int eg = blockIdx.x * 256 + threadIdx.x;
  int d = dst[eg];
  int p = atomicAdd(&wcnt[d], 1);
  perm[off[d] + p] = eg;
}

// ------------------------------------------------- fused q/k/v/skip GEMM
// X[M=2048,K] @ {Wq,Wk,Wv,Ws}[K,1024] + bias -> 4 outputs. 128x128 tiles.
__global__ void k_gemm4(const float* __restrict__ X, int K,
                        const float* __restrict__ W0, const float* __restrict__ W1,
                        const float* __restrict__ W2, const float* __restrict__ W3,
                        const float* __restrict__ bb0, const float* __restrict__ bb1,
                        const float* __restrict__ bb2, const float* __restrict__ bb3,
                        float* __restrict__ O0, float* __restrict__ O1,
                        float* __restrict__ O2, float* __restrict__ O3) {
  int rb = blockIdx.x & 15;       // 2048/128
  int cbm = blockIdx.x >> 4;      // mat*8 + colblk
  int mat = cbm >> 3;
  int col0 = (cbm & 7) * 128;
  int row0 = rb * 128;
  const float* W; const float* bias; float* O;
  if (mat == 0)      { W = W0; bias = bb0; O = O0; }
  else if (mat == 1) { W = W1; bias = bb1; O = O1; }
  else if (mat == 2) { W = W2; bias = bb2; O = O2; }
  else               { W = W3; bias = bb3; O = O3; }

  __shared__ __align__(16) float Xs[8][132];
  __shared__ __align__(16) float Ws[8][132];
  int tid = threadIdx.x;
  int tr = tid >> 4, tc = tid & 15;
  float acc[64];
#pragma unroll
  for (int i = 0; i < 64; i++) acc[i] = 0.f;

  int lr = tid >> 1, kq = (tid & 1) * 4;
  int lk = tid >> 5, c4 = (tid & 31) * 4;

  for (int k0 = 0; k0 < K; k0 += 8) {
    float4 xv = *(const float4*)&X[(row0 + lr) * K + k0 + kq];
    Xs[kq + 0][lr] = xv.x; Xs[kq + 1][lr] = xv.y;
    Xs[kq + 2][lr] = xv.z; Xs[kq + 3][lr] = xv.w;
    *(float4*)&Ws[lk][c4] = *(const float4*)&W[(k0 + lk) * C_ + col0 + c4];
    __syncthreads();
#pragma unroll
    for (int kk = 0; kk < 8; kk++) {
      float4 a0 = *(const float4*)&Xs[kk][tr * 8];
      float4 a1 = *(const float4*)&Xs[kk][tr * 8 + 4];
      float4 b0 = *(const float4*)&Ws[kk][tc * 8];
      float4 b1v = *(const float4*)&Ws[kk][tc * 8 + 4];
      float av[8] = {a0.x, a0.y, a0.z, a0.w, a1.x, a1.y, a1.z, a1.w};
      float bv[8] = {b0.x, b0.y, b0.z, b0.w, b1v.x, b1v.y, b1v.z, b1v.w};
#pragma unroll
      for (int i = 0; i < 8; i++)
#pragma unroll
        for (int j = 0; j < 8; j++) acc[i * 8 + j] += av[i] * bv[j];
    }
    __syncthreads();
  }
  float bl[8];
#pragma unroll
  for (int j = 0; j < 8; j++) bl[j] = bias[col0 + tc * 8 + j];
#pragma unroll
  for (int i = 0; i < 8; i++) {
    int row = row0 + tr * 8 + i;
    float4 o0, o1;
    o0.x = acc[i * 8 + 0] + bl[0]; o0.y = acc[i * 8 + 1] + bl[1];
    o0.z = acc[i * 8 + 2] + bl[2]; o0.w = acc[i * 8 + 3] + bl[3];
    o1.x = acc[i * 8 + 4] + bl[4]; o1.y = acc[i * 8 + 5] + bl[5];
    o1.z = acc[i * 8 + 6] + bl[6]; o1.w = acc[i * 8 + 7] + bl[7];
    *(float4*)&O[row * C_ + col0 + tc * 8] = o0;
    *(float4*)&O[row * C_ + col0 + tc * 8 + 4] = o1;
  }
}

// ------------------------------------------------- per-dst attention agg
// One block per dst node: logits -> softmax -> alpha-weighted (v+e) sum,
// added onto O (which already holds the skip connection x@Ws+bs).
__global__ void k_agg(const float* __restrict__ q, const float* __restrict__ k,
                      const float* __restrict__ v, const float* __restrict__ ec,
                      const int* __restrict__ srcA, const float* __restrict__ etype,
                      const float* __restrict__ emain, const int* __restrict__ off,
                      const int* __restrict__ perm, float* __restrict__ O) {
  int dst = blockIdx.x;
  int beg = off[dst];
  int cntE = off[dst + 1] - beg;
  if (cntE == 0) return;
  if (cntE > 128) cntE = 128;  // never expected (Poisson mean 16)
  int tid = threadIdx.x;
  __shared__ float lg[128][8];
  __shared__ int srcs[128];
  __shared__ int cids[128];
  for (int e = tid; e < cntE; e += 256) {
    int eg = perm[beg + e];
    srcs[e] = srcA[eg];
    cids[e] = ((int)(etype[eg] + 0.5f)) * 2 + (int)(emain[eg] + 0.5f);
  }
  __syncthreads();
  int c = tid * 4;
  int h = tid >> 5;
  float4 qv = *(const float4*)&q[dst * C_ + c];
  const float scale = 0.08838834764831845f;  // 1/sqrt(128)
  for (int e = 0; e < cntE; e++) {
    int s = srcs[e], ci = cids[e];
    float4 kv = *(const float4*)&k[s * C_ + c];
    float4 ev = *(const float4*)&ec[ci * C_ + c];
    float p = qv.x * (kv.x + ev.x) + qv.y * (kv.y + ev.y) +
              qv.z * (kv.z + ev.z) + qv.w * (kv.w + ev.w);
#pragma unroll
    for (int o = 16; o; o >>= 1) p += __shfl_xor(p, o);
    if ((tid & 31) == 0) lg[e][h] = p * scale;
  }
  __syncthreads();
  if (tid < 8) {
    float m = -1e30f;
    for (int e = 0; e < cntE; e++) m = fmaxf(m, lg[e][tid]);
    float ssum = 0.f;
    for (int e = 0; e < cntE; e++) { float x = expf(lg[e][tid] - m); lg[e][tid] = x; ssum += x; }
    float inv = 1.f / ssum;
    for (int e = 0; e < cntE; e++) lg[e][tid] *= inv;
  }
  __syncthreads();
  float4 acc = {0.f, 0.f, 0.f, 0.f};
  for (int e = 0; e < cntE; e++) {
    float a = lg[e][h];
    int s = srcs[e], ci = cids[e];
    float4 vv = *(const float4*)&v[s * C_ + c];
    float4 ev = *(const float4*)&ec[ci * C_ + c];
    acc.x += a * (vv.x + ev.x); acc.y += a * (vv.y + ev.y);
    acc.z += a * (vv.z + ev.z); acc.w += a * (vv.w + ev.w);
  }
  float4 o = *(const float4*)&O[dst * C_ + c];
  o.x += acc.x; o.y += acc.y; o.z += acc.z; o.w += acc.w;
  *(float4*)&O[dst * C_ + c] = o;
}

// ------------------------------------------------- final gather + FC
__global__ void k_final(const float* __restrict__ nB, const int* __restrict__ lens,
                        const float* __restrict__ fcW, const float* __restrict__ fcb,
                        float* __restrict__ out) {
  int b = blockIdx.x;
  int idx = lens[b] - 1;
  const float* row = &nB[(b * E_ + idx) * C_];
  int tid = threadIdx.x;
  int c = tid * 4;
  float4 r = *(const float4*)&row[c];
  float4 w0 = *(const float4*)&fcW[(c + 0) * 4];
  float4 w1 = *(const float4*)&fcW[(c + 1) * 4];
  float4 w2 = *(const float4*)&fcW[(c + 2) * 4];
  float4 w3 = *(const float4*)&fcW[(c + 3) * 4];
  float p0 = r.x * w0.x + r.y * w1.x + r.z * w2.x + r.w * w3.x;
  float p1 = r.x * w0.y + r.y * w1.y + r.z * w2.y + r.w * w3.y;
  float p2 = r.x * w0.z + r.y * w1.z + r.z * w2.z + r.w * w3.z;
  float p3 = r.x * w0.w + r.y * w1.w + r.z * w2.w + r.w * w3.w;
#pragma unroll
  for (int o = 32; o; o >>= 1) {
    p0 += __shfl_xor(p0, o); p1 += __shfl_xor(p1, o);
    p2 += __shfl_xor(p2, o); p3 += __shfl_xor(p3, o);
  }
  __shared__ float red[4][4];
  if ((tid & 63) == 0) {
    int w = tid >> 6;
    red[w][0] = p0; red[w][1] = p1; red[w][2] = p2; red[w][3] = p3;
  }
  __syncthreads();
  if (tid == 0) {
#pragma unroll
    for (int j = 0; j < 4; j++)
      out[b * 4 + j] = red[0][j] + red[1][j] + red[2][j] + red[3][j] + fcb[j];
  }
}

// ================================================================ launch
extern "C" void kernel_launch(void* const* d_in, const int* in_sizes, int n_in,
                              void* d_out, int out_size, void* d_ws, size_t ws_size,
                              hipStream_t stream) {
  (void)in_sizes; (void)n_in; (void)out_size; (void)ws_size;
  const float* lh    = (const float*)d_in[0];
  const float* mask  = (const float*)d_in[1];
  const int*   lens  = (const int*)d_in[2];
  const int*   edge  = (const int*)d_in[3];
  const float* etype = (const float*)d_in[4];
  const float* emain = (const float*)d_in[5];
  const float* W1   = (const float*)d_in[6];
  const float* b1   = (const float*)d_in[7];
  const float* W2   = (const float*)d_in[8];
  const float* b2   = (const float*)d_in[9];
  const float* Wr1  = (const float*)d_in[10];
  const float* br1  = (const float*)d_in[11];
  const float* Wm1  = (const float*)d_in[12];
  const float* bm1  = (const float*)d_in[13];
  const float* Wr2  = (const float*)d_in[14];
  const float* br2  = (const float*)d_in[15];
  const float* Wm2  = (const float*)d_in[16];
  const float* bm2  = (const float*)d_in[17];
  const float* q1W  = (const float*)d_in[18];
  const float* q1b  = (const float*)d_in[19];
  const float* k1W  = (const float*)d_in[20];
  const float* k1b  = (const float*)d_in[21];
  const float* v1W  = (const float*)d_in[22];
  const float* v1b  = (const float*)d_in[23];
  const float* e1W  = (const float*)d_in[24];
  const float* s1W  = (const float*)d_in[25];
  const float* s1b  = (const float*)d_in[26];
  const float* q2W  = (const float*)d_in[27];
  const float* q2b  = (const float*)d_in[28];
  const float* k2W  = (const float*)d_in[29];
  const float* k2b  = (const float*)d_in[30];
  const float* v2W  = (const float*)d_in[31];
  const float* v2b  = (const float*)d_in[32];
  const float* e2W  = (const float*)d_in[33];
  const float* s2W  = (const float*)d_in[34];
  const float* s2b  = (const float*)d_in[35];
  const float* fcW  = (const float*)d_in[36];
  const float* fcb  = (const float*)d_in[37];

  float* ws    = (float*)d_ws;
  float* att   = ws;                       // 32768
  float* node0 = att + 32768;              // 2048*768
  float* e1c   = node0 + N_ * D_;          // 10*1024
  float* e2c   = e1c + 10 * 1024;          // 10*1024
  float* qb    = e2c + 10 * 1024;          // 2048*1024
  float* kb    = qb + N_ * C_;
  float* vb    = kb + N_ * C_;
  float* nA    = vb + N_ * C_;
  float* nBuf  = nA + N_ * C_;
  int* cnt  = (int*)(nBuf + N_ * C_);      // 2048
  int* wcnt = cnt + N_;                    // 2048
  int* off  = wcnt + N_;                   // 2049
  int* perm = off + (N_ + 1);              // 32768

  const int* srcA = edge;
  const int* dstA = edge + EG_;

  // CSR build (shared by both convs)
  hipMemsetAsync(cnt, 0, 2 * N_ * sizeof(int), stream);
  k_count<<<EG_ / 256, 256, 0, stream>>>(dstA, cnt);
  k_scan<<<1, 256, 0, stream>>>(cnt, off);
  k_scatter<<<EG_ / 256, 256, 0, stream>>>(dstA, wcnt, off, perm);

  // span attention -> att
  k_att_init<<<128, 256, 0, stream>>>(b2, att);
  k_span<<<1024, 256, 0, stream>>>(lh, W1, b1, W2, att);

  // 10-combo edge embeddings
  k_combo<<<4, 256, 0, stream>>>(Wr1, br1, Wm1, bm1, e1W, e1c);
  k_combo<<<4, 256, 0, stream>>>(Wr2, br2, Wm2, bm2, e2W, e2c);

  // pooling -> node0
  k_pool<<<256, 256, 0, stream>>>(lh, att, mask, node0);

  // conv1
  k_gemm4<<<512, 256, 0, stream>>>(node0, D_, q1W, k1W, v1W, s1W,
                                   q1b, k1b, v1b, s1b, qb, kb, vb, nA);
  k_agg<<<N_, 256, 0, stream>>>(qb, kb, vb, e1c, srcA, etype, emain, off, perm, nA);

  // conv2
  k_gemm4<<<512, 256, 0, stream>>>(nA, C_, q2W, k2W, v2W, s2W,
                                   q2b, k2b, v2b, s2b, qb, kb, vb, nBuf);
  k_agg<<<N_, 256, 0, stream>>>(qb, kb, vb, e2c, srcA, etype, emain, off, perm, nBuf);

  // final
  k_final<<<B_, 256, 0, stream>>>(nBuf, lens, fcW, fcb, (float*)d_out);
}

// Round 3
// 690.734 us; speedup vs baseline: 1.6430x; 1.6430x over previous
//
#include <hip/hip_runtime.h>
#include <math.h>
#include <stdint.h>

#define B_  64
#define E_  32
#define L_  512
#define D_  768
#define C_  1024
#define H_  8
#define EG_ 32768
#define SH_ 512
#define N_  2048   // B*E

typedef __bf16 bf16x8 __attribute__((ext_vector_type(8)));
typedef float f32x4 __attribute__((ext_vector_type(4)));
typedef unsigned short u16;
typedef u16 u16x4 __attribute__((ext_vector_type(4)));

// ---------------------------------------------------------------- helpers

__device__ __forceinline__ u16 bf16_rn(float x) {
  unsigned u = __builtin_bit_cast(unsigned, x);
  unsigned r = u + 0x7FFFu + ((u >> 16) & 1u);
  return (u16)(r >> 16);
}

__device__ __forceinline__ void split_bf16(float x, u16& h, u16& l) {
  h = bf16_rn(x);
  float hf = __builtin_bit_cast(float, (unsigned)h << 16);
  l = bf16_rn(x - hf);
}

__device__ __forceinline__ void gload16(const void* g, void* l) {
  __builtin_amdgcn_global_load_lds(
      (const __attribute__((address_space(1))) void*)(unsigned long long)(uintptr_t)g,
      (__attribute__((address_space(3))) void*)(unsigned int)(uintptr_t)l,
      16, 0, 0);
}

__global__ void k_att_init(const float* __restrict__ b2, float* __restrict__ att) {
  int i = blockIdx.x * 256 + threadIdx.x;   // grid 128 -> 32768
  att[i] = b2[0];
}

// ------------------------------------------------- weight prep: transpose + split
// W [K][Nc] fp32  ->  TH/TL [Nc][K] bf16 (hi/lo)
__global__ void k_wt(const float* __restrict__ W, u16* __restrict__ TH, u16* __restrict__ TL,
                     int K, int Nc) {
  __shared__ float Ts[32][33];
  int nbk = K >> 5;
  int bk = blockIdx.x % nbk, bn = blockIdx.x / nbk;
  int tid = threadIdx.x;
  int tx = tid & 31, ty = tid >> 5;
  for (int r = ty; r < 32; r += 8)
    Ts[r][tx] = W[(size_t)(bk * 32 + r) * Nc + bn * 32 + tx];
  __syncthreads();
  for (int r = ty; r < 32; r += 8) {
    float v = Ts[tx][r];               // = W[bk*32+tx][bn*32+r]
    u16 h, l; split_bf16(v, h, l);
    size_t o = (size_t)(bn * 32 + r) * K + bk * 32 + tx;
    TH[o] = h; TL[o] = l;
  }
}

// ------------------------------------------------- MFMA GEMM core
// C[128x128] = X(fp32)[row0..+128][0..K) @ Bt(hi/lo bf16)[col0..+128][0..K)^T
// split-bf16 3-product accumulation. 256 threads = 4 waves, wave = 64x64.
__device__ __forceinline__ void gemm_core(
    const float* __restrict__ X, const u16* __restrict__ BtH, const u16* __restrict__ BtL,
    int K, int row0, int col0,
    u16* Ah, u16* Al, u16* Bh, u16* Bl, f32x4 acc[4][4])
{
  int tid = threadIdx.x;
  int lane = tid & 63, w = tid >> 6;
  int wrow = (w & 1) * 64, wcol = (w >> 1) * 64;

  int aoff[4], boff[4];
#pragma unroll
  for (int i = 0; i < 4; i++) {
    int kc = lane >> 4;
    int rT = wrow + i * 16 + (lane & 15);
    aoff[i] = rT * 64 + (((kc ^ ((rT >> 1) & 3)) & 3) << 4);
    int cT = wcol + i * 16 + (lane & 15);
    boff[i] = cT * 64 + (((kc ^ ((cT >> 1) & 3)) & 3) << 4);
  }

  int nkt = K >> 5;
  for (int kt = 0; kt < nkt; kt++) {
    int k0 = kt << 5;
    if (kt) __syncthreads();
    // ---- stage A: fp32 -> hi/lo bf16, swizzled ds_write
#pragma unroll
    for (int p = 0; p < 4; p++) {
      int idx = tid + p * 256;          // 0..1023
      int r = idx >> 3, c4 = idx & 7;   // row 0..127, 4-float chunk 0..7
      float4 v = *(const float4*)&X[(size_t)(row0 + r) * K + k0 + c4 * 4];
      u16 h0, h1, h2, h3, l0, l1, l2, l3;
      split_bf16(v.x, h0, l0);
      split_bf16(v.y, h1, l1);
      split_bf16(v.z, h2, l2);
      split_bf16(v.w, h3, l3);
      u16x4 hi = {h0, h1, h2, h3};
      u16x4 lo = {l0, l1, l2, l3};
      int off = r * 64 + ((((c4 >> 1) ^ ((r >> 1) & 3)) & 3) << 4) + (c4 & 1) * 8;
      *(u16x4*)((char*)Ah + off) = hi;
      *(u16x4*)((char*)Al + off) = lo;
    }
    // ---- stage B: global_load_lds (linear dest, inverse-swizzled source)
#pragma unroll
    for (int q = 0; q < 2; q++) {
      int rT = w * 32 + q * 16 + (lane >> 2);
      int kc = lane & 3;
      size_t gb = (size_t)(col0 + rT) * K + k0 + (((kc ^ ((rT >> 1) & 3)) & 3) << 3);
      int lb = (w * 32 + q * 16) * 32;  // u16 units, wave-uniform
      gload16(&BtH[gb], &Bh[lb]);
      gload16(&BtL[gb], &Bl[lb]);
    }
    __syncthreads();
    // ---- fragments + MFMA
    bf16x8 ah[4], al[4];
#pragma unroll
    for (int i = 0; i < 4; i++) {
      ah[i] = *(const bf16x8*)((const char*)Ah + aoff[i]);
      al[i] = *(const bf16x8*)((const char*)Al + aoff[i]);
    }
#pragma unroll
    for (int j = 0; j < 4; j++) {
      bf16x8 bh = *(const bf16x8*)((const char*)Bh + boff[j]);
      bf16x8 bl = *(const bf16x8*)((const char*)Bl + boff[j]);
#pragma unroll
      for (int i = 0; i < 4; i++) {
        acc[i][j] = __builtin_amdgcn_mfma_f32_16x16x32_bf16(ah[i], bh, acc[i][j], 0, 0, 0);
        acc[i][j] = __builtin_amdgcn_mfma_f32_16x16x32_bf16(ah[i], bl, acc[i][j], 0, 0, 0);
        acc[i][j] = __builtin_amdgcn_mfma_f32_16x16x32_bf16(al[i], bh, acc[i][j], 0, 0, 0);
      }
    }
  }
}

// ------------------------------------------------- span MLP (MFMA, fused epilogue)
__global__ __launch_bounds__(256) void k_span_m(
    const float* __restrict__ lh, const u16* __restrict__ W1tH, const u16* __restrict__ W1tL,
    const float* __restrict__ b1, const float* __restrict__ W2, float* __restrict__ att) {
  __shared__ __align__(16) u16 Ah[128 * 32], Al[128 * 32], Bh[128 * 32], Bl[128 * 32];
  int rb = blockIdx.x & 255, cb = blockIdx.x >> 8;
  int row0 = rb * 128, col0 = cb * 128;
  f32x4 acc[4][4];
#pragma unroll
  for (int i = 0; i < 4; i++)
#pragma unroll
    for (int j = 0; j < 4; j++) acc[i][j] = (f32x4){0.f, 0.f, 0.f, 0.f};
  gemm_core(lh, W1tH, W1tL, D_, row0, col0, Ah, Al, Bh, Bl, acc);

  int lane = threadIdx.x & 63, w = threadIdx.x >> 6;
  int wrow = (w & 1) * 64, wcol = (w >> 1) * 64;
  float b1v[4], w2v[4];
#pragma unroll
  for (int j = 0; j < 4; j++) {
    int col = col0 + wcol + j * 16 + (lane & 15);
    b1v[j] = b1[col]; w2v[j] = W2[col];
  }
#pragma unroll
  for (int i = 0; i < 4; i++) {
#pragma unroll
    for (int r = 0; r < 4; r++) {
      float s = 0.f;
#pragma unroll
      for (int j = 0; j < 4; j++) {
        float h = acc[i][j][r] + b1v[j];
        s += fmaxf(h, 0.f) * w2v[j];
      }
      s += __shfl_xor(s, 1); s += __shfl_xor(s, 2);
      s += __shfl_xor(s, 4); s += __shfl_xor(s, 8);
      if ((lane & 15) == 0)
        atomicAdd(&att[row0 + wrow + i * 16 + (lane >> 4) * 4 + r], s);
    }
  }
}

// ------------------------------------------------- fused q/k/v/skip GEMM (MFMA)
__global__ __launch_bounds__(256) void k_gemm4_m(
    const float* __restrict__ X, int K,
    const u16* __restrict__ WtH, const u16* __restrict__ WtL,
    const float* __restrict__ bb0, const float* __restrict__ bb1,
    const float* __restrict__ bb2, const float* __restrict__ bb3,
    float* __restrict__ O0, float* __restrict__ O1,
    float* __restrict__ O2, float* __restrict__ O3) {
  __shared__ __align__(16) u16 Ah[128 * 32], Al[128 * 32], Bh[128 * 32], Bl[128 * 32];
  int rb = blockIdx.x & 15, cbm = blockIdx.x >> 4;
  int mat = cbm >> 3;
  int col0 = (cbm & 7) * 128, row0 = rb * 128;
  const u16* BtH = WtH + (size_t)mat * C_ * K;
  const u16* BtL = WtL + (size_t)mat * C_ * K;
  const float* bias; float* O;
  if (mat == 0)      { bias = bb0; O = O0; }
  else if (mat == 1) { bias = bb1; O = O1; }
  else if (mat == 2) { bias = bb2; O = O2; }
  else               { bias = bb3; O = O3; }

  f32x4 acc[4][4];
#pragma unroll
  for (int i = 0; i < 4; i++)
#pragma unroll
    for (int j = 0; j < 4; j++) acc[i][j] = (f32x4){0.f, 0.f, 0.f, 0.f};
  gemm_core(X, BtH, BtL, K, row0, col0, Ah, Al, Bh, Bl, acc);

  int lane = threadIdx.x & 63, w = threadIdx.x >> 6;
  int wrow = (w & 1) * 64, wcol = (w >> 1) * 64;
#pragma unroll
  for (int j = 0; j < 4; j++) {
    int col = col0 + wcol + j * 16 + (lane & 15);
    float bv = bias[col];
#pragma unroll
    for (int i = 0; i < 4; i++) {
      int rowb = row0 + wrow + i * 16 + (lane >> 4) * 4;
#pragma unroll
      for (int r = 0; r < 4; r++)
        O[(size_t)(rowb + r) * C_ + col] = acc[i][j][r] + bv;
    }
  }
}

// ------------------------------------------------- masked-softmax pooling
__global__ void k_pool(const float* __restrict__ lh, const float* __restrict__ att,
                       const float* __restrict__ mask, float* __restrict__ node0) {
  int bi = blockIdx.x >> 2, eg4 = blockIdx.x & 3;
  int tid = threadIdx.x;
  __shared__ float probs[8][512];
  __shared__ float red[4];
  float a0 = att[bi * L_ + tid];
  float a1 = att[bi * L_ + 256 + tid];
  for (int ei = 0; ei < 8; ei++) {
    int e = eg4 * 8 + ei;
    const float* mrow = &mask[(bi * E_ + e) * L_];
    float l0 = a0 - 1e5f * (1.f - mrow[tid]);
    float l1 = a1 - 1e5f * (1.f - mrow[256 + tid]);
    float mx = fmaxf(l0, l1);
#pragma unroll
    for (int o = 32; o; o >>= 1) mx = fmaxf(mx, __shfl_xor(mx, o));
    if ((tid & 63) == 0) red[tid >> 6] = mx;
    __syncthreads();
    mx = fmaxf(fmaxf(red[0], red[1]), fmaxf(red[2], red[3]));
    __syncthreads();
    float e0 = expf(l0 - mx), e1 = expf(l1 - mx);
    float s = e0 + e1;
#pragma unroll
    for (int o = 32; o; o >>= 1) s += __shfl_xor(s, o);
    if ((tid & 63) == 0) red[tid >> 6] = s;
    __syncthreads();
    s = red[0] + red[1] + red[2] + red[3];
    float inv = 1.f / s;
    probs[ei][tid] = e0 * inv;
    probs[ei][256 + tid] = e1 * inv;
    __syncthreads();
  }
  float acc0[8], acc1[8], acc2[8];
#pragma unroll
  for (int e = 0; e < 8; e++) { acc0[e] = 0.f; acc1[e] = 0.f; acc2[e] = 0.f; }
  const float* lb = &lh[bi * L_ * D_];
  for (int l = 0; l < L_; l++) {
    float v0 = lb[l * D_ + tid];
    float v1 = lb[l * D_ + 256 + tid];
    float v2 = lb[l * D_ + 512 + tid];
#pragma unroll
    for (int e = 0; e < 8; e++) {
      float p = probs[e][l];
      acc0[e] += p * v0; acc1[e] += p * v1; acc2[e] += p * v2;
    }
  }
#pragma unroll
  for (int e = 0; e < 8; e++) {
    float* orow = &node0[(bi * E_ + eg4 * 8 + e) * D_];
    orow[tid] = acc0[e]; orow[256 + tid] = acc1[e]; orow[512 + tid] = acc2[e];
  }
}

// -------------------------------------- 10-combo edge embedding @ We
__global__ void k_combo(const float* __restrict__ Wr, const float* __restrict__ br,
                        const float* __restrict__ Wm, const float* __restrict__ bm,
                        const float* __restrict__ eW, float* __restrict__ out) {
  int j = blockIdx.x * 256 + threadIdx.x;  // grid 4 -> 1024 cols
  __shared__ float ea[10][1024];
  for (int i = threadIdx.x; i < 1024; i += 256) {
    float wr = Wr[i], wm = Wm[i], bs = br[i] + bm[i];
#pragma unroll
    for (int c = 0; c < 10; c++) ea[c][i] = (float)(c >> 1) * wr + (float)(c & 1) * wm + bs;
  }
  __syncthreads();
  float acc[10];
#pragma unroll
  for (int c = 0; c < 10; c++) acc[c] = 0.f;
  for (int kk = 0; kk < 1024; kk++) {
    float wv = eW[kk * 1024 + j];
#pragma unroll
    for (int c = 0; c < 10; c++) acc[c] += ea[c][kk] * wv;
  }
#pragma unroll
  for (int c = 0; c < 10; c++) out[c * 1024 + j] = acc[c];
}

// ------------------------------------------------- CSR build
__global__ void k_count(const int* __restrict__ dst, int* __restrict__ cnt) {
  int eg = blockIdx.x * 256 + threadIdx.x;
  atomicAdd(&cnt[dst[eg]], 1);
}

__global__ void k_scan(const int* __restrict__ cnt, int* __restrict__ off) {
  __shared__ int part[256];
  int t = threadIdx.x;
  int local[8]; int s = 0;
#pragma unroll
  for (int i = 0; i < 8; i++) { local[i] = cnt[t * 8 + i]; s += local[i]; }
  part[t] = s;
  __syncthreads();
  if (t == 0) {
    int r = 0;
    for (int i = 0; i < 256; i++) { int v = part[i]; part[i] = r; r += v; }
    off[N_] = r;
  }
  __syncthreads();
  int r = part[t];
#pragma unroll
  for (int i = 0; i < 8; i++) { off[t * 8 + i] = r; r += local[i]; }
}

__global__ void k_scatter(const int* __restrict__ dst, int* __restrict__ wcnt,
                          const int* __restrict__ off, int* __restrict__ perm) {
  int eg = blockIdx.x * 256 + threadIdx.x;
  int d = dst[eg];
  int p = atomicAdd(&wcnt[d], 1);
  perm[off[d] + p] = eg;
}

// ------------------------------------------------- per-dst attention agg
__global__ void k_agg(const float* __restrict__ q, const float* __restrict__ k,
                      const float* __restrict__ v, const float* __restrict__ ec,
                      const int* __restrict__ srcA, const float* __restrict__ etype,
                      const float* __restrict__ emain, const int* __restrict__ off,
                      const int* __restrict__ perm, float* __restrict__ O) {
  int dst = blockIdx.x;
  int beg = off[dst];
  int cntE = off[dst + 1] - beg;
  if (cntE == 0) return;
  if (cntE > 128) cntE = 128;
  int tid = threadIdx.x;
  __shared__ float lg[128][8];
  __shared__ int srcs[128];
  __shared__ int cids[128];
  for (int e = tid; e < cntE; e += 256) {
    int eg = perm[beg + e];
    srcs[e] = srcA[eg];
    cids[e] = ((int)(etype[eg] + 0.5f)) * 2 + (int)(emain[eg] + 0.5f);
  }
  __syncthreads();
  int c = tid * 4;
  int h = tid >> 5;
  float4 qv = *(const float4*)&q[dst * C_ + c];
  const float scale = 0.08838834764831845f;  // 1/sqrt(128)
  for (int e = 0; e < cntE; e++) {
    int s = srcs[e], ci = cids[e];
    float4 kv = *(const float4*)&k[s * C_ + c];
    float4 ev = *(const float4*)&ec[ci * C_ + c];
    float p = qv.x * (kv.x + ev.x) + qv.y * (kv.y + ev.y) +
              qv.z * (kv.z + ev.z) + qv.w * (kv.w + ev.w);
#pragma unroll
    for (int o = 16; o; o >>= 1) p += __shfl_xor(p, o);
    if ((tid & 31) == 0) lg[e][h] = p * scale;
  }
  __syncthreads();
  if (tid < 8) {
    float m = -1e30f;
    for (int e = 0; e < cntE; e++) m = fmaxf(m, lg[e][tid]);
    float ssum = 0.f;
    for (int e = 0; e < cntE; e++) { float x = expf(lg[e][tid] - m); lg[e][tid] = x; ssum += x; }
    float inv = 1.f / ssum;
    for (int e = 0; e < cntE; e++) lg[e][tid] *= inv;
  }
  __syncthreads();
  float4 acc = {0.f, 0.f, 0.f, 0.f};
  for (int e = 0; e < cntE; e++) {
    float a = lg[e][h];
    int s = srcs[e], ci = cids[e];
    float4 vv = *(const float4*)&v[s * C_ + c];
    float4 ev = *(const float4*)&ec[ci * C_ + c];
    acc.x += a * (vv.x + ev.x); acc.y += a * (vv.y + ev.y);
    acc.z += a * (vv.z + ev.z); acc.w += a * (vv.w + ev.w);
  }
  float4 o = *(const float4*)&O[dst * C_ + c];
  o.x += acc.x; o.y += acc.y; o.z += acc.z; o.w += acc.w;
  *(float4*)&O[dst * C_ + c] = o;
}

// ------------------------------------------------- final gather + FC
__global__ void k_final(const float* __restrict__ nB, const int* __restrict__ lens,
                        const float* __restrict__ fcW, const float* __restrict__ fcb,
                        float* __restrict__ out) {
  int b = blockIdx.x;
  int idx = lens[b] - 1;
  const float* row = &nB[(b * E_ + idx) * C_];
  int tid = threadIdx.x;
  int c = tid * 4;
  float4 r = *(const float4*)&row[c];
  float4 w0 = *(const float4*)&fcW[(c + 0) * 4];
  float4 w1 = *(const float4*)&fcW[(c + 1) * 4];
  float4 w2 = *(const float4*)&fcW[(c + 2) * 4];
  float4 w3 = *(const float4*)&fcW[(c + 3) * 4];
  float p0 = r.x * w0.x + r.y * w1.x + r.z * w2.x + r.w * w3.x;
  float p1 = r.x * w0.y + r.y * w1.y + r.z * w2.y + r.w * w3.y;
  float p2 = r.x * w0.z + r.y * w1.z + r.z * w2.z + r.w * w3.z;
  float p3 = r.x * w0.w + r.y * w1.w + r.z * w2.w + r.w * w3.w;
#pragma unroll
  for (int o = 32; o; o >>= 1) {
    p0 += __shfl_xor(p0, o); p1 += __shfl_xor(p1, o);
    p2 += __shfl_xor(p2, o); p3 += __shfl_xor(p3, o);
  }
  __shared__ float red[4][4];
  if ((tid & 63) == 0) {
    int w = tid >> 6;
    red[w][0] = p0; red[w][1] = p1; red[w][2] = p2; red[w][3] = p3;
  }
  __syncthreads();
  if (tid == 0) {
#pragma unroll
    for (int j = 0; j < 4; j++)
      out[b * 4 + j] = red[0][j] + red[1][j] + red[2][j] + red[3][j] + fcb[j];
  }
}

// ================================================================ launch
extern "C" void kernel_launch(void* const* d_in, const int* in_sizes, int n_in,
                              void* d_out, int out_size, void* d_ws, size_t ws_size,
                              hipStream_t stream) {
  (void)in_sizes; (void)n_in; (void)out_size; (void)ws_size;
  const float* lh    = (const float*)d_in[0];
  const float* mask  = (const float*)d_in[1];
  const int*   lens  = (const int*)d_in[2];
  const int*   edge  = (const int*)d_in[3];
  const float* etype = (const float*)d_in[4];
  const float* emain = (const float*)d_in[5];
  const float* W1   = (const float*)d_in[6];
  const float* b1   = (const float*)d_in[7];
  const float* W2   = (const float*)d_in[8];
  const float* b2   = (const float*)d_in[9];
  const float* Wr1  = (const float*)d_in[10];
  const float* br1  = (const float*)d_in[11];
  const float* Wm1  = (const float*)d_in[12];
  const float* bm1  = (const float*)d_in[13];
  const float* Wr2  = (const float*)d_in[14];
  const float* br2  = (const float*)d_in[15];
  const float* Wm2  = (const float*)d_in[16];
  const float* bm2  = (const float*)d_in[17];
  const float* q1W  = (const float*)d_in[18];
  const float* q1b  = (const float*)d_in[19];
  const float* k1W  = (const float*)d_in[20];
  const float* k1b  = (const float*)d_in[21];
  const float* v1W  = (const float*)d_in[22];
  const float* v1b  = (const float*)d_in[23];
  const float* e1W  = (const float*)d_in[24];
  const float* s1W  = (const float*)d_in[25];
  const float* s1b  = (const float*)d_in[26];
  const float* q2W  = (const float*)d_in[27];
  const float* q2b  = (const float*)d_in[28];
  const float* k2W  = (const float*)d_in[29];
  const float* k2b  = (const float*)d_in[30];
  const float* v2W  = (const float*)d_in[31];
  const float* v2b  = (const float*)d_in[32];
  const float* e2W  = (const float*)d_in[33];
  const float* s2W  = (const float*)d_in[34];
  const float* s2b  = (const float*)d_in[35];
  const float* fcW  = (const float*)d_in[36];
  const float* fcb  = (const float*)d_in[37];

  float* ws    = (float*)d_ws;
  float* att   = ws;                       // 32768
  float* node0 = att + 32768;              // 2048*768
  float* e1c   = node0 + N_ * D_;          // 10*1024
  float* e2c   = e1c + 10 * 1024;
  float* qb    = e2c + 10 * 1024;          // 2048*1024 each
  float* kb    = qb + N_ * C_;
  float* vb    = kb + N_ * C_;
  float* nA    = vb + N_ * C_;
  float* nBuf  = nA + N_ * C_;
  int* cnt  = (int*)(nBuf + N_ * C_);      // 2048
  int* wcnt = cnt + N_;                    // 2048
  int* off  = wcnt + N_;                   // 2049 (pad to 2056)
  int* perm = off + (N_ + 8);              // 32768
  u16* w1tH = (u16*)(perm + EG_);          // 512*768
  u16* w1tL = w1tH + SH_ * D_;
  u16* wt1H = w1tL + SH_ * D_;             // 4*1024*768
  u16* wt1L = wt1H + 4 * C_ * D_;
  u16* wt2H = wt1L + 4 * C_ * D_;          // 4*1024*1024
  u16* wt2L = wt2H + 4 * C_ * C_;

  const int* srcA = edge;
  const int* dstA = edge + EG_;

  // CSR build (shared by both convs)
  (void)hipMemsetAsync(cnt, 0, 2 * N_ * sizeof(int), stream);
  k_count<<<EG_ / 256, 256, 0, stream>>>(dstA, cnt);
  k_scan<<<1, 256, 0, stream>>>(cnt, off);
  k_scatter<<<EG_ / 256, 256, 0, stream>>>(dstA, wcnt, off, perm);

  // weight prep: transpose + bf16 hi/lo split
  k_wt<<<(D_ / 32) * (SH_ / 32), 256, 0, stream>>>(W1, w1tH, w1tL, D_, SH_);
  k_wt<<<(D_ / 32) * (C_ / 32), 256, 0, stream>>>(q1W, wt1H + 0 * C_ * D_, wt1L + 0 * C_ * D_, D_, C_);
  k_wt<<<(D_ / 32) * (C_ / 32), 256, 0, stream>>>(k1W, wt1H + 1 * C_ * D_, wt1L + 1 * C_ * D_, D_, C_);
  k_wt<<<(D_ / 32) * (C_ / 32), 256, 0, stream>>>(v1W, wt1H + 2 * C_ * D_, wt1L + 2 * C_ * D_, D_, C_);
  k_wt<<<(D_ / 32) * (C_ / 32), 256, 0, stream>>>(s1W, wt1H + 3 * C_ * D_, wt1L + 3 * C_ * D_, D_, C_);
  k_wt<<<(C_ / 32) * (C_ / 32), 256, 0, stream>>>(q2W, wt2H + 0 * C_ * C_, wt2L + 0 * C_ * C_, C_, C_);
  k_wt<<<(C_ / 32) * (C_ / 32), 256, 0, stream>>>(k2W, wt2H + 1 * C_ * C_, wt2L + 1 * C_ * C_, C_, C_);
  k_wt<<<(C_ / 32) * (C_ / 32), 256, 0, stream>>>(v2W, wt2H + 2 * C_ * C_, wt2L + 2 * C_ * C_, C_, C_);
  k_wt<<<(C_ / 32) * (C_ / 32), 256, 0, stream>>>(s2W, wt2H + 3 * C_ * C_, wt2L + 3 * C_ * C_, C_, C_);

  // span attention -> att
  k_att_init<<<128, 256, 0, stream>>>(b2, att);
  k_span_m<<<1024, 256, 0, stream>>>(lh, w1tH, w1tL, b1, W2, att);

  // 10-combo edge embeddings
  k_combo<<<4, 256, 0, stream>>>(Wr1, br1, Wm1, bm1, e1W, e1c);
  k_combo<<<4, 256, 0, stream>>>(Wr2, br2, Wm2, bm2, e2W, e2c);

  // pooling -> node0
  k_pool<<<256, 256, 0, stream>>>(lh, att, mask, node0);

  // conv1
  k_gemm4_m<<<512, 256, 0, stream>>>(node0, D_, wt1H, wt1L,
                                     q1b, k1b, v1b, s1b, qb, kb, vb, nA);
  k_agg<<<N_, 256, 0, stream>>>(qb, kb, vb, e1c, srcA, etype, emain, off, perm, nA);

  // conv2
  k_gemm4_m<<<512, 256, 0, stream>>>(nA, C_, wt2H, wt2L,
                                     q2b, k2b, v2b, s2b, qb, kb, vb, nBuf);
  k_agg<<<N_, 256, 0, stream>>>(qb, kb, vb, e2c, srcA, etype, emain, off, perm, nBuf);

  // final
  k_final<<<B_, 256, 0, stream>>>(nBuf, lens, fcW, fcb, (float*)d_out);
}

// Round 4
// 467.328 us; speedup vs baseline: 2.4284x; 1.4780x over previous
//
#include <hip/hip_runtime.h>
#include <math.h>
#include <stdint.h>

#define B_  64
#define E_  32
#define L_  512
#define D_  768
#define C_  1024
#define H_  8
#define EG_ 32768
#define SH_ 512
#define N_  2048   // B*E

typedef __bf16 bf16x8 __attribute__((ext_vector_type(8)));
typedef float f32x4 __attribute__((ext_vector_type(4)));
typedef unsigned short u16;
typedef u16 u16x4 __attribute__((ext_vector_type(4)));

// ---------------------------------------------------------------- helpers

__device__ __forceinline__ u16 bf16_rn(float x) {
  unsigned u = __builtin_bit_cast(unsigned, x);
  unsigned r = u + 0x7FFFu + ((u >> 16) & 1u);
  return (u16)(r >> 16);
}

__device__ __forceinline__ void split_bf16(float x, u16& h, u16& l) {
  h = bf16_rn(x);
  float hf = __builtin_bit_cast(float, (unsigned)h << 16);
  l = bf16_rn(x - hf);
}

__device__ __forceinline__ void gload16(const void* g, void* l) {
  __builtin_amdgcn_global_load_lds(
      (const __attribute__((address_space(1))) void*)(unsigned long long)(uintptr_t)g,
      (__attribute__((address_space(3))) void*)(unsigned int)(uintptr_t)l,
      16, 0, 0);
}

__global__ void k_att_init(const float* __restrict__ b2, float* __restrict__ att) {
  int i = blockIdx.x * 256 + threadIdx.x;   // grid 128 -> 32768
  att[i] = b2[0];
}

// ------------------------------------------------- weight prep: transpose + split
// W [K][Nc] fp32  ->  TH/TL [Nc][K] bf16 (hi/lo)
__global__ void k_wt(const float* __restrict__ W, u16* __restrict__ TH, u16* __restrict__ TL,
                     int K, int Nc) {
  __shared__ float Ts[32][33];
  int nbk = K >> 5;
  int bk = blockIdx.x % nbk, bn = blockIdx.x / nbk;
  int tid = threadIdx.x;
  int tx = tid & 31, ty = tid >> 5;
  for (int r = ty; r < 32; r += 8)
    Ts[r][tx] = W[(size_t)(bk * 32 + r) * Nc + bn * 32 + tx];
  __syncthreads();
  for (int r = ty; r < 32; r += 8) {
    float v = Ts[tx][r];               // = W[bk*32+tx][bn*32+r]
    u16 h, l; split_bf16(v, h, l);
    size_t o = (size_t)(bn * 32 + r) * K + bk * 32 + tx;
    TH[o] = h; TL[o] = l;
  }
}

// ------------------------------------------------- MFMA GEMM core
// C[128x128] = X(fp32)[row0..+128][0..K) @ Bt(hi/lo bf16)[col0..+128][0..K)^T
// split-bf16 3-product accumulation. 256 threads = 4 waves, wave = 64x64.
__device__ __forceinline__ void gemm_core(
    const float* __restrict__ X, const u16* __restrict__ BtH, const u16* __restrict__ BtL,
    int K, int row0, int col0,
    u16* Ah, u16* Al, u16* Bh, u16* Bl, f32x4 acc[4][4])
{
  int tid = threadIdx.x;
  int lane = tid & 63, w = tid >> 6;
  int wrow = (w & 1) * 64, wcol = (w >> 1) * 64;

  int aoff[4], boff[4];
#pragma unroll
  for (int i = 0; i < 4; i++) {
    int kc = lane >> 4;
    int rT = wrow + i * 16 + (lane & 15);
    aoff[i] = rT * 64 + (((kc ^ ((rT >> 1) & 3)) & 3) << 4);
    int cT = wcol + i * 16 + (lane & 15);
    boff[i] = cT * 64 + (((kc ^ ((cT >> 1) & 3)) & 3) << 4);
  }

  int nkt = K >> 5;
  for (int kt = 0; kt < nkt; kt++) {
    int k0 = kt << 5;
    if (kt) __syncthreads();
    // ---- stage A: fp32 -> hi/lo bf16, swizzled ds_write
#pragma unroll
    for (int p = 0; p < 4; p++) {
      int idx = tid + p * 256;          // 0..1023
      int r = idx >> 3, c4 = idx & 7;   // row 0..127, 4-float chunk 0..7
      float4 v = *(const float4*)&X[(size_t)(row0 + r) * K + k0 + c4 * 4];
      u16 h0, h1, h2, h3, l0, l1, l2, l3;
      split_bf16(v.x, h0, l0);
      split_bf16(v.y, h1, l1);
      split_bf16(v.z, h2, l2);
      split_bf16(v.w, h3, l3);
      u16x4 hi = {h0, h1, h2, h3};
      u16x4 lo = {l0, l1, l2, l3};
      int off = r * 64 + ((((c4 >> 1) ^ ((r >> 1) & 3)) & 3) << 4) + (c4 & 1) * 8;
      *(u16x4*)((char*)Ah + off) = hi;
      *(u16x4*)((char*)Al + off) = lo;
    }
    // ---- stage B: global_load_lds (linear dest, inverse-swizzled source)
#pragma unroll
    for (int q = 0; q < 2; q++) {
      int rT = w * 32 + q * 16 + (lane >> 2);
      int kc = lane & 3;
      size_t gb = (size_t)(col0 + rT) * K + k0 + (((kc ^ ((rT >> 1) & 3)) & 3) << 3);
      int lb = (w * 32 + q * 16) * 32;  // u16 units, wave-uniform
      gload16(&BtH[gb], &Bh[lb]);
      gload16(&BtL[gb], &Bl[lb]);
    }
    __syncthreads();
    // ---- fragments + MFMA
    bf16x8 ah[4], al[4];
#pragma unroll
    for (int i = 0; i < 4; i++) {
      ah[i] = *(const bf16x8*)((const char*)Ah + aoff[i]);
      al[i] = *(const bf16x8*)((const char*)Al + aoff[i]);
    }
#pragma unroll
    for (int j = 0; j < 4; j++) {
      bf16x8 bh = *(const bf16x8*)((const char*)Bh + boff[j]);
      bf16x8 bl = *(const bf16x8*)((const char*)Bl + boff[j]);
#pragma unroll
      for (int i = 0; i < 4; i++) {
        acc[i][j] = __builtin_amdgcn_mfma_f32_16x16x32_bf16(ah[i], bh, acc[i][j], 0, 0, 0);
        acc[i][j] = __builtin_amdgcn_mfma_f32_16x16x32_bf16(ah[i], bl, acc[i][j], 0, 0, 0);
        acc[i][j] = __builtin_amdgcn_mfma_f32_16x16x32_bf16(al[i], bh, acc[i][j], 0, 0, 0);
      }
    }
  }
}

// ------------------------------------------------- span MLP (MFMA, fused epilogue)
__global__ __launch_bounds__(256) void k_span_m(
    const float* __restrict__ lh, const u16* __restrict__ W1tH, const u16* __restrict__ W1tL,
    const float* __restrict__ b1, const float* __restrict__ W2, float* __restrict__ att) {
  __shared__ __align__(16) u16 Ah[128 * 32], Al[128 * 32], Bh[128 * 32], Bl[128 * 32];
  int rb = blockIdx.x & 255, cb = blockIdx.x >> 8;
  int row0 = rb * 128, col0 = cb * 128;
  f32x4 acc[4][4];
#pragma unroll
  for (int i = 0; i < 4; i++)
#pragma unroll
    for (int j = 0; j < 4; j++) acc[i][j] = (f32x4){0.f, 0.f, 0.f, 0.f};
  gemm_core(lh, W1tH, W1tL, D_, row0, col0, Ah, Al, Bh, Bl, acc);

  int lane = threadIdx.x & 63, w = threadIdx.x >> 6;
  int wrow = (w & 1) * 64, wcol = (w >> 1) * 64;
  float b1v[4], w2v[4];
#pragma unroll
  for (int j = 0; j < 4; j++) {
    int col = col0 + wcol + j * 16 + (lane & 15);
    b1v[j] = b1[col]; w2v[j] = W2[col];
  }
#pragma unroll
  for (int i = 0; i < 4; i++) {
#pragma unroll
    for (int r = 0; r < 4; r++) {
      float s = 0.f;
#pragma unroll
      for (int j = 0; j < 4; j++) {
        float h = acc[i][j][r] + b1v[j];
        s += fmaxf(h, 0.f) * w2v[j];
      }
      s += __shfl_xor(s, 1); s += __shfl_xor(s, 2);
      s += __shfl_xor(s, 4); s += __shfl_xor(s, 8);
      if ((lane & 15) == 0)
        atomicAdd(&att[row0 + wrow + i * 16 + (lane >> 4) * 4 + r], s);
    }
  }
}

// ------------------------------------------------- fused q/k/v/skip GEMM (MFMA)
__global__ __launch_bounds__(256) void k_gemm4_m(
    const float* __restrict__ X, int K,
    const u16* __restrict__ WtH, const u16* __restrict__ WtL,
    const float* __restrict__ bb0, const float* __restrict__ bb1,
    const float* __restrict__ bb2, const float* __restrict__ bb3,
    float* __restrict__ O0, float* __restrict__ O1,
    float* __restrict__ O2, float* __restrict__ O3) {
  __shared__ __align__(16) u16 Ah[128 * 32], Al[128 * 32], Bh[128 * 32], Bl[128 * 32];
  int rb = blockIdx.x & 15, cbm = blockIdx.x >> 4;
  int mat = cbm >> 3;
  int col0 = (cbm & 7) * 128, row0 = rb * 128;
  const u16* BtH = WtH + (size_t)mat * C_ * K;
  const u16* BtL = WtL + (size_t)mat * C_ * K;
  const float* bias; float* O;
  if (mat == 0)      { bias = bb0; O = O0; }
  else if (mat == 1) { bias = bb1; O = O1; }
  else if (mat == 2) { bias = bb2; O = O2; }
  else               { bias = bb3; O = O3; }

  f32x4 acc[4][4];
#pragma unroll
  for (int i = 0; i < 4; i++)
#pragma unroll
    for (int j = 0; j < 4; j++) acc[i][j] = (f32x4){0.f, 0.f, 0.f, 0.f};
  gemm_core(X, BtH, BtL, K, row0, col0, Ah, Al, Bh, Bl, acc);

  int lane = threadIdx.x & 63, w = threadIdx.x >> 6;
  int wrow = (w & 1) * 64, wcol = (w >> 1) * 64;
#pragma unroll
  for (int j = 0; j < 4; j++) {
    int col = col0 + wcol + j * 16 + (lane & 15);
    float bv = bias[col];
#pragma unroll
    for (int i = 0; i < 4; i++) {
      int rowb = row0 + wrow + i * 16 + (lane >> 4) * 4;
#pragma unroll
      for (int r = 0; r < 4; r++)
        O[(size_t)(rowb + r) * C_ + col] = acc[i][j][r] + bv;
    }
  }
}

// ------------------------------------------------- masked-softmax pooling
__global__ void k_pool(const float* __restrict__ lh, const float* __restrict__ att,
                       const float* __restrict__ mask, float* __restrict__ node0) {
  int bi = blockIdx.x >> 2, eg4 = blockIdx.x & 3;
  int tid = threadIdx.x;
  __shared__ float probs[8][512];
  __shared__ float red[4];
  float a0 = att[bi * L_ + tid];
  float a1 = att[bi * L_ + 256 + tid];
  for (int ei = 0; ei < 8; ei++) {
    int e = eg4 * 8 + ei;
    const float* mrow = &mask[(bi * E_ + e) * L_];
    float l0 = a0 - 1e5f * (1.f - mrow[tid]);
    float l1 = a1 - 1e5f * (1.f - mrow[256 + tid]);
    float mx = fmaxf(l0, l1);
#pragma unroll
    for (int o = 32; o; o >>= 1) mx = fmaxf(mx, __shfl_xor(mx, o));
    if ((tid & 63) == 0) red[tid >> 6] = mx;
    __syncthreads();
    mx = fmaxf(fmaxf(red[0], red[1]), fmaxf(red[2], red[3]));
    __syncthreads();
    float e0 = expf(l0 - mx), e1 = expf(l1 - mx);
    float s = e0 + e1;
#pragma unroll
    for (int o = 32; o; o >>= 1) s += __shfl_xor(s, o);
    if ((tid & 63) == 0) red[tid >> 6] = s;
    __syncthreads();
    s = red[0] + red[1] + red[2] + red[3];
    float inv = 1.f / s;
    probs[ei][tid] = e0 * inv;
    probs[ei][256 + tid] = e1 * inv;
    __syncthreads();
  }
  float acc0[8], acc1[8], acc2[8];
#pragma unroll
  for (int e = 0; e < 8; e++) { acc0[e] = 0.f; acc1[e] = 0.f; acc2[e] = 0.f; }
  const float* lb = &lh[bi * L_ * D_];
  for (int l = 0; l < L_; l++) {
    float v0 = lb[l * D_ + tid];
    float v1 = lb[l * D_ + 256 + tid];
    float v2 = lb[l * D_ + 512 + tid];
#pragma unroll
    for (int e = 0; e < 8; e++) {
      float p = probs[e][l];
      acc0[e] += p * v0; acc1[e] += p * v1; acc2[e] += p * v2;
    }
  }
#pragma unroll
  for (int e = 0; e < 8; e++) {
    float* orow = &node0[(bi * E_ + eg4 * 8 + e) * D_];
    orow[tid] = acc0[e]; orow[256 + tid] = acc1[e]; orow[512 + tid] = acc2[e];
  }
}

// -------------------------------------- edge embedding @ We, rank-3 form
// out[c][j] = t(c)*(Wr@eW)[j] + m(c)*(Wm@eW)[j] + ((br+bm)@eW)[j]
// grid 128: conv(2) x kchunk(16) x jblock(4); 256 threads = 1 col each.
__global__ void k_combo2(const float* __restrict__ Wr1, const float* __restrict__ br1,
                         const float* __restrict__ Wm1, const float* __restrict__ bm1,
                         const float* __restrict__ e1W,
                         const float* __restrict__ Wr2, const float* __restrict__ br2,
                         const float* __restrict__ Wm2, const float* __restrict__ bm2,
                         const float* __restrict__ e2W,
                         float* __restrict__ e1c, float* __restrict__ e2c) {
  int x = blockIdx.x;
  int conv = x >> 6;
  int jb = x & 3, kb = (x >> 2) & 15;
  const float *Wr, *br, *Wm, *bm, *eW; float* out;
  if (conv == 0) { Wr = Wr1; br = br1; Wm = Wm1; bm = bm1; eW = e1W; out = e1c; }
  else           { Wr = Wr2; br = br2; Wm = Wm2; bm = bm2; eW = e2W; out = e2c; }
  int tid = threadIdx.x;
  __shared__ float sw[3][64];
  int k0 = kb * 64;
  if (tid < 64) {
    sw[0][tid] = Wr[k0 + tid];
    sw[1][tid] = Wm[k0 + tid];
    sw[2][tid] = br[k0 + tid] + bm[k0 + tid];
  }
  __syncthreads();
  int j = jb * 256 + tid;
  float a0 = 0.f, a1 = 0.f, a2 = 0.f;
#pragma unroll 8
  for (int kk = 0; kk < 64; kk++) {
    float w = eW[(size_t)(k0 + kk) * C_ + j];
    a0 += sw[0][kk] * w; a1 += sw[1][kk] * w; a2 += sw[2][kk] * w;
  }
#pragma unroll
  for (int c = 0; c < 10; c++)
    atomicAdd(&out[c * C_ + j], (float)(c >> 1) * a0 + (float)(c & 1) * a1 + a2);
}

// ------------------------------------------------- CSR build
__global__ void k_count(const int* __restrict__ dst, int* __restrict__ cnt) {
  int eg = blockIdx.x * 256 + threadIdx.x;
  atomicAdd(&cnt[dst[eg]], 1);
}

__global__ void k_scan(const int* __restrict__ cnt, int* __restrict__ off) {
  __shared__ int part[256];
  int t = threadIdx.x;
  int local[8]; int s = 0;
#pragma unroll
  for (int i = 0; i < 8; i++) { local[i] = cnt[t * 8 + i]; s += local[i]; }
  part[t] = s;
  __syncthreads();
  if (t == 0) {
    int r = 0;
    for (int i = 0; i < 256; i++) { int v = part[i]; part[i] = r; r += v; }
    off[N_] = r;
  }
  __syncthreads();
  int r = part[t];
#pragma unroll
  for (int i = 0; i < 8; i++) { off[t * 8 + i] = r; r += local[i]; }
}

__global__ void k_scatter(const int* __restrict__ dst, int* __restrict__ wcnt,
                          const int* __restrict__ off, int* __restrict__ perm) {
  int eg = blockIdx.x * 256 + threadIdx.x;
  int d = dst[eg];
  int p = atomicAdd(&wcnt[d], 1);
  perm[off[d] + p] = eg;
}

// ------------------------------------------------- per-dst attention agg
__global__ void k_agg(const float* __restrict__ q, const float* __restrict__ k,
                      const float* __restrict__ v, const float* __restrict__ ec,
                      const int* __restrict__ srcA, const float* __restrict__ etype,
                      const float* __restrict__ emain, const int* __restrict__ off,
                      const int* __restrict__ perm, float* __restrict__ O) {
  int dst = blockIdx.x;
  int beg = off[dst];
  int cntE = off[dst + 1] - beg;
  if (cntE == 0) return;
  if (cntE > 128) cntE = 128;
  int tid = threadIdx.x;
  __shared__ float lg[128][8];
  __shared__ int srcs[128];
  __shared__ int cids[128];
  for (int e = tid; e < cntE; e += 256) {
    int eg = perm[beg + e];
    srcs[e] = srcA[eg];
    cids[e] = ((int)(etype[eg] + 0.5f)) * 2 + (int)(emain[eg] + 0.5f);
  }
  __syncthreads();
  int c = tid * 4;
  int h = tid >> 5;
  float4 qv = *(const float4*)&q[dst * C_ + c];
  const float scale = 0.08838834764831845f;  // 1/sqrt(128)
  for (int e = 0; e < cntE; e++) {
    int s = srcs[e], ci = cids[e];
    float4 kv = *(const float4*)&k[s * C_ + c];
    float4 ev = *(const float4*)&ec[ci * C_ + c];
    float p = qv.x * (kv.x + ev.x) + qv.y * (kv.y + ev.y) +
              qv.z * (kv.z + ev.z) + qv.w * (kv.w + ev.w);
#pragma unroll
    for (int o = 16; o; o >>= 1) p += __shfl_xor(p, o);
    if ((tid & 31) == 0) lg[e][h] = p * scale;
  }
  __syncthreads();
  if (tid < 8) {
    float m = -1e30f;
    for (int e = 0; e < cntE; e++) m = fmaxf(m, lg[e][tid]);
    float ssum = 0.f;
    for (int e = 0; e < cntE; e++) { float x = expf(lg[e][tid] - m); lg[e][tid] = x; ssum += x; }
    float inv = 1.f / ssum;
    for (int e = 0; e < cntE; e++) lg[e][tid] *= inv;
  }
  __syncthreads();
  float4 acc = {0.f, 0.f, 0.f, 0.f};
  for (int e = 0; e < cntE; e++) {
    float a = lg[e][h];
    int s = srcs[e], ci = cids[e];
    float4 vv = *(const float4*)&v[s * C_ + c];
    float4 ev = *(const float4*)&ec[ci * C_ + c];
    acc.x += a * (vv.x + ev.x); acc.y += a * (vv.y + ev.y);
    acc.z += a * (vv.z + ev.z); acc.w += a * (vv.w + ev.w);
  }
  float4 o = *(const float4*)&O[dst * C_ + c];
  o.x += acc.x; o.y += acc.y; o.z += acc.z; o.w += acc.w;
  *(float4*)&O[dst * C_ + c] = o;
}

// ------------------------------------------------- final gather + FC
__global__ void k_final(const float* __restrict__ nB, const int* __restrict__ lens,
                        const float* __restrict__ fcW, const float* __restrict__ fcb,
                        float* __restrict__ out) {
  int b = blockIdx.x;
  int idx = lens[b] - 1;
  const float* row = &nB[(b * E_ + idx) * C_];
  int tid = threadIdx.x;
  int c = tid * 4;
  float4 r = *(const float4*)&row[c];
  float4 w0 = *(const float4*)&fcW[(c + 0) * 4];
  float4 w1 = *(const float4*)&fcW[(c + 1) * 4];
  float4 w2 = *(const float4*)&fcW[(c + 2) * 4];
  float4 w3 = *(const float4*)&fcW[(c + 3) * 4];
  float p0 = r.x * w0.x + r.y * w1.x + r.z * w2.x + r.w * w3.x;
  float p1 = r.x * w0.y + r.y * w1.y + r.z * w2.y + r.w * w3.y;
  float p2 = r.x * w0.z + r.y * w1.z + r.z * w2.z + r.w * w3.z;
  float p3 = r.x * w0.w + r.y * w1.w + r.z * w2.w + r.w * w3.w;
#pragma unroll
  for (int o = 32; o; o >>= 1) {
    p0 += __shfl_xor(p0, o); p1 += __shfl_xor(p1, o);
    p2 += __shfl_xor(p2, o); p3 += __shfl_xor(p3, o);
  }
  __shared__ float red[4][4];
  if ((tid & 63) == 0) {
    int w = tid >> 6;
    red[w][0] = p0; red[w][1] = p1; red[w][2] = p2; red[w][3] = p3;
  }
  __syncthreads();
  if (tid == 0) {
#pragma unroll
    for (int j = 0; j < 4; j++)
      out[b * 4 + j] = red[0][j] + red[1][j] + red[2][j] + red[3][j] + fcb[j];
  }
}

// ================================================================ launch
extern "C" void kernel_launch(void* const* d_in, const int* in_sizes, int n_in,
                              void* d_out, int out_size, void* d_ws, size_t ws_size,
                              hipStream_t stream) {
  (void)in_sizes; (void)n_in; (void)out_size; (void)ws_size;
  const float* lh    = (const float*)d_in[0];
  const float* mask  = (const float*)d_in[1];
  const int*   lens  = (const int*)d_in[2];
  const int*   edge  = (const int*)d_in[3];
  const float* etype = (const float*)d_in[4];
  const float* emain = (const float*)d_in[5];
  const float* W1   = (const float*)d_in[6];
  const float* b1   = (const float*)d_in[7];
  const float* W2   = (const float*)d_in[8];
  const float* b2   = (const float*)d_in[9];
  const float* Wr1  = (const float*)d_in[10];
  const float* br1  = (const float*)d_in[11];
  const float* Wm1  = (const float*)d_in[12];
  const float* bm1  = (const float*)d_in[13];
  const float* Wr2  = (const float*)d_in[14];
  const float* br2  = (const float*)d_in[15];
  const float* Wm2  = (const float*)d_in[16];
  const float* bm2  = (const float*)d_in[17];
  const float* q1W  = (const float*)d_in[18];
  const float* q1b  = (const float*)d_in[19];
  const float* k1W  = (const float*)d_in[20];
  const float* k1b  = (const float*)d_in[21];
  const float* v1W  = (const float*)d_in[22];
  const float* v1b  = (const float*)d_in[23];
  const float* e1W  = (const float*)d_in[24];
  const float* s1W  = (const float*)d_in[25];
  const float* s1b  = (const float*)d_in[26];
  const float* q2W  = (const float*)d_in[27];
  const float* q2b  = (const float*)d_in[28];
  const float* k2W  = (const float*)d_in[29];
  const float* k2b  = (const float*)d_in[30];
  const float* v2W  = (const float*)d_in[31];
  const float* v2b  = (const float*)d_in[32];
  const float* e2W  = (const float*)d_in[33];
  const float* s2W  = (const float*)d_in[34];
  const float* s2b  = (const float*)d_in[35];
  const float* fcW  = (const float*)d_in[36];
  const float* fcb  = (const float*)d_in[37];

  float* ws    = (float*)d_ws;
  float* att   = ws;                       // 32768
  float* node0 = att + 32768;              // 2048*768
  float* e1c   = node0 + N_ * D_;          // 10*1024
  float* e2c   = e1c + 10 * 1024;
  float* qb    = e2c + 10 * 1024;          // 2048*1024 each
  float* kb    = qb + N_ * C_;
  float* vb    = kb + N_ * C_;
  float* nA    = vb + N_ * C_;
  float* nBuf  = nA + N_ * C_;
  int* cnt  = (int*)(nBuf + N_ * C_);      // 2048
  int* wcnt = cnt + N_;                    // 2048
  int* off  = wcnt + N_;                   // 2049 (pad to 2056)
  int* perm = off + (N_ + 8);              // 32768
  u16* w1tH = (u16*)(perm + EG_);          // 512*768
  u16* w1tL = w1tH + SH_ * D_;
  u16* wt1H = w1tL + SH_ * D_;             // 4*1024*768
  u16* wt1L = wt1H + 4 * C_ * D_;
  u16* wt2H = wt1L + 4 * C_ * D_;          // 4*1024*1024
  u16* wt2L = wt2H + 4 * C_ * C_;

  const int* srcA = edge;
  const int* dstA = edge + EG_;

  // CSR build (shared by both convs)
  (void)hipMemsetAsync(cnt, 0, 2 * N_ * sizeof(int), stream);
  k_count<<<EG_ / 256, 256, 0, stream>>>(dstA, cnt);
  k_scan<<<1, 256, 0, stream>>>(cnt, off);
  k_scatter<<<EG_ / 256, 256, 0, stream>>>(dstA, wcnt, off, perm);

  // weight prep: transpose + bf16 hi/lo split
  k_wt<<<(D_ / 32) * (SH_ / 32), 256, 0, stream>>>(W1, w1tH, w1tL, D_, SH_);
  k_wt<<<(D_ / 32) * (C_ / 32), 256, 0, stream>>>(q1W, wt1H + 0 * C_ * D_, wt1L + 0 * C_ * D_, D_, C_);
  k_wt<<<(D_ / 32) * (C_ / 32), 256, 0, stream>>>(k1W, wt1H + 1 * C_ * D_, wt1L + 1 * C_ * D_, D_, C_);
  k_wt<<<(D_ / 32) * (C_ / 32), 256, 0, stream>>>(v1W, wt1H + 2 * C_ * D_, wt1L + 2 * C_ * D_, D_, C_);
  k_wt<<<(D_ / 32) * (C_ / 32), 256, 0, stream>>>(s1W, wt1H + 3 * C_ * D_, wt1L + 3 * C_ * D_, D_, C_);
  k_wt<<<(C_ / 32) * (C_ / 32), 256, 0, stream>>>(q2W, wt2H + 0 * C_ * C_, wt2L + 0 * C_ * C_, C_, C_);
  k_wt<<<(C_ / 32) * (C_ / 32), 256, 0, stream>>>(k2W, wt2H + 1 * C_ * C_, wt2L + 1 * C_ * C_, C_, C_);
  k_wt<<<(C_ / 32) * (C_ / 32), 256, 0, stream>>>(v2W, wt2H + 2 * C_ * C_, wt2L + 2 * C_ * C_, C_, C_);
  k_wt<<<(C_ / 32) * (C_ / 32), 256, 0, stream>>>(s2W, wt2H + 3 * C_ * C_, wt2L + 3 * C_ * C_, C_, C_);

  // span attention -> att
  k_att_init<<<128, 256, 0, stream>>>(b2, att);
  k_span_m<<<1024, 256, 0, stream>>>(lh, w1tH, w1tL, b1, W2, att);

  // 10-combo edge embeddings (rank-3 decomposition, both convs in one launch)
  (void)hipMemsetAsync(e1c, 0, 20 * C_ * sizeof(float), stream);
  k_combo2<<<128, 256, 0, stream>>>(Wr1, br1, Wm1, bm1, e1W,
                                    Wr2, br2, Wm2, bm2, e2W, e1c, e2c);

  // pooling -> node0
  k_pool<<<256, 256, 0, stream>>>(lh, att, mask, node0);

  // conv1
  k_gemm4_m<<<512, 256, 0, stream>>>(node0, D_, wt1H, wt1L,
                                     q1b, k1b, v1b, s1b, qb, kb, vb, nA);
  k_agg<<<N_, 256, 0, stream>>>(qb, kb, vb, e1c, srcA, etype, emain, off, perm, nA);

  // conv2
  k_gemm4_m<<<512, 256, 0, stream>>>(nA, C_, wt2H, wt2L,
                                     q2b, k2b, v2b, s2b, qb, kb, vb, nBuf);
  k_agg<<<N_, 256, 0, stream>>>(qb, kb, vb, e2c, srcA, etype, emain, off, perm, nBuf);

  // final
  k_final<<<B_, 256, 0, stream>>>(nBuf, lens, fcW, fcb, (float*)d_out);
}

// Round 5
// 425.414 us; speedup vs baseline: 2.6676x; 1.0985x over previous
//
#include <hip/hip_runtime.h>
#include <math.h>
#include <stdint.h>

#define B_  64
#define E_  32
#define L_  512
#define D_  768
#define C_  1024
#define H_  8
#define EG_ 32768
#define SH_ 512
#define N_  2048   // B*E

typedef __bf16 bf16x8 __attribute__((ext_vector_type(8)));
typedef float f32x4 __attribute__((ext_vector_type(4)));
typedef unsigned short u16;
typedef u16 u16x4 __attribute__((ext_vector_type(4)));

// ---------------------------------------------------------------- helpers

__device__ __forceinline__ u16 bf16_rn(float x) {
  unsigned u = __builtin_bit_cast(unsigned, x);
  unsigned r = u + 0x7FFFu + ((u >> 16) & 1u);
  return (u16)(r >> 16);
}

__device__ __forceinline__ void gload16(const void* g, void* l) {
  __builtin_amdgcn_global_load_lds(
      (const __attribute__((address_space(1))) void*)(unsigned long long)(uintptr_t)g,
      (__attribute__((address_space(3))) void*)(unsigned int)(uintptr_t)l,
      16, 0, 0);
}

__global__ void k_att_init(const float* __restrict__ b2, float* __restrict__ att) {
  int i = blockIdx.x * 256 + threadIdx.x;   // grid 128 -> 32768
  att[i] = b2[0];
}

// ------------------------------------------------- weight prep: transpose -> bf16
// W [K][Nc] fp32  ->  TH [Nc][K] bf16 (round-to-nearest)
__global__ void k_wt(const float* __restrict__ W, u16* __restrict__ TH, int K, int Nc) {
  __shared__ float Ts[32][33];
  int nbk = K >> 5;
  int bk = blockIdx.x % nbk, bn = blockIdx.x / nbk;
  int tid = threadIdx.x;
  int tx = tid & 31, ty = tid >> 5;
  for (int r = ty; r < 32; r += 8)
    Ts[r][tx] = W[(size_t)(bk * 32 + r) * Nc + bn * 32 + tx];
  __syncthreads();
  for (int r = ty; r < 32; r += 8) {
    float v = Ts[tx][r];               // = W[bk*32+tx][bn*32+r]
    TH[(size_t)(bn * 32 + r) * K + bk * 32 + tx] = bf16_rn(v);
  }
}

// ------------------------------------------------- MFMA GEMM core (plain bf16)
// C[128x128] = X(fp32->bf16)[row0..+128][0..K) @ Bt(bf16)[col0..+128][0..K)^T
// 256 threads = 4 waves, wave = 64x64 quadrant.
__device__ __forceinline__ void gemm_core(
    const float* __restrict__ X, const u16* __restrict__ Bt,
    int K, int row0, int col0,
    u16* Ah, u16* Bh, f32x4 acc[4][4])
{
  int tid = threadIdx.x;
  int lane = tid & 63, w = tid >> 6;
  int wrow = (w & 1) * 64, wcol = (w >> 1) * 64;

  int aoff[4], boff[4];
#pragma unroll
  for (int i = 0; i < 4; i++) {
    int kc = lane >> 4;
    int rT = wrow + i * 16 + (lane & 15);
    aoff[i] = rT * 64 + (((kc ^ ((rT >> 1) & 3)) & 3) << 4);
    int cT = wcol + i * 16 + (lane & 15);
    boff[i] = cT * 64 + (((kc ^ ((cT >> 1) & 3)) & 3) << 4);
  }

  int nkt = K >> 5;
  for (int kt = 0; kt < nkt; kt++) {
    int k0 = kt << 5;
    if (kt) __syncthreads();
    // ---- stage A: fp32 -> bf16, swizzled ds_write
#pragma unroll
    for (int p = 0; p < 4; p++) {
      int idx = tid + p * 256;          // 0..1023
      int r = idx >> 3, c4 = idx & 7;   // row 0..127, 4-float chunk 0..7
      float4 v = *(const float4*)&X[(size_t)(row0 + r) * K + k0 + c4 * 4];
      u16x4 hi = {bf16_rn(v.x), bf16_rn(v.y), bf16_rn(v.z), bf16_rn(v.w)};
      int off = r * 64 + ((((c4 >> 1) ^ ((r >> 1) & 3)) & 3) << 4) + (c4 & 1) * 8;
      *(u16x4*)((char*)Ah + off) = hi;
    }
    // ---- stage B: global_load_lds (linear dest, inverse-swizzled source)
#pragma unroll
    for (int q = 0; q < 2; q++) {
      int rT = w * 32 + q * 16 + (lane >> 2);
      int kc = lane & 3;
      size_t gb = (size_t)(col0 + rT) * K + k0 + (((kc ^ ((rT >> 1) & 3)) & 3) << 3);
      int lb = (w * 32 + q * 16) * 32;  // u16 units, wave-uniform
      gload16(&Bt[gb], &Bh[lb]);
    }
    __syncthreads();
    // ---- fragments + MFMA
    bf16x8 ah[4];
#pragma unroll
    for (int i = 0; i < 4; i++)
      ah[i] = *(const bf16x8*)((const char*)Ah + aoff[i]);
#pragma unroll
    for (int j = 0; j < 4; j++) {
      bf16x8 bh = *(const bf16x8*)((const char*)Bh + boff[j]);
#pragma unroll
      for (int i = 0; i < 4; i++)
        acc[i][j] = __builtin_amdgcn_mfma_f32_16x16x32_bf16(ah[i], bh, acc[i][j], 0, 0, 0);
    }
  }
}

// ------------------------------------------------- span MLP (MFMA, fused epilogue)
__global__ __launch_bounds__(256) void k_span_m(
    const float* __restrict__ lh, const u16* __restrict__ W1t,
    const float* __restrict__ b1, const float* __restrict__ W2, float* __restrict__ att) {
  __shared__ __align__(16) u16 Ah[128 * 32], Bh[128 * 32];
  int rb = blockIdx.x & 255, cb = blockIdx.x >> 8;
  int row0 = rb * 128, col0 = cb * 128;
  f32x4 acc[4][4];
#pragma unroll
  for (int i = 0; i < 4; i++)
#pragma unroll
    for (int j = 0; j < 4; j++) acc[i][j] = (f32x4){0.f, 0.f, 0.f, 0.f};
  gemm_core(lh, W1t, D_, row0, col0, Ah, Bh, acc);

  int lane = threadIdx.x & 63, w = threadIdx.x >> 6;
  int wrow = (w & 1) * 64, wcol = (w >> 1) * 64;
  float b1v[4], w2v[4];
#pragma unroll
  for (int j = 0; j < 4; j++) {
    int col = col0 + wcol + j * 16 + (lane & 15);
    b1v[j] = b1[col]; w2v[j] = W2[col];
  }
#pragma unroll
  for (int i = 0; i < 4; i++) {
#pragma unroll
    for (int r = 0; r < 4; r++) {
      float s = 0.f;
#pragma unroll
      for (int j = 0; j < 4; j++) {
        float h = acc[i][j][r] + b1v[j];
        s += fmaxf(h, 0.f) * w2v[j];
      }
      s += __shfl_xor(s, 1); s += __shfl_xor(s, 2);
      s += __shfl_xor(s, 4); s += __shfl_xor(s, 8);
      if ((lane & 15) == 0)
        atomicAdd(&att[row0 + wrow + i * 16 + (lane >> 4) * 4 + r], s);
    }
  }
}

// ------------------------------------------------- fused q/k/v/skip GEMM (MFMA)
__global__ __launch_bounds__(256) void k_gemm4_m(
    const float* __restrict__ X, int K,
    const u16* __restrict__ Wt,
    const float* __restrict__ bb0, const float* __restrict__ bb1,
    const float* __restrict__ bb2, const float* __restrict__ bb3,
    float* __restrict__ O0, float* __restrict__ O1,
    float* __restrict__ O2, float* __restrict__ O3) {
  __shared__ __align__(16) u16 Ah[128 * 32], Bh[128 * 32];
  int rb = blockIdx.x & 15, cbm = blockIdx.x >> 4;
  int mat = cbm >> 3;
  int col0 = (cbm & 7) * 128, row0 = rb * 128;
  const u16* Bt = Wt + (size_t)mat * C_ * K;
  const float* bias; float* O;
  if (mat == 0)      { bias = bb0; O = O0; }
  else if (mat == 1) { bias = bb1; O = O1; }
  else if (mat == 2) { bias = bb2; O = O2; }
  else               { bias = bb3; O = O3; }

  f32x4 acc[4][4];
#pragma unroll
  for (int i = 0; i < 4; i++)
#pragma unroll
    for (int j = 0; j < 4; j++) acc[i][j] = (f32x4){0.f, 0.f, 0.f, 0.f};
  gemm_core(X, Bt, K, row0, col0, Ah, Bh, acc);

  int lane = threadIdx.x & 63, w = threadIdx.x >> 6;
  int wrow = (w & 1) * 64, wcol = (w >> 1) * 64;
#pragma unroll
  for (int j = 0; j < 4; j++) {
    int col = col0 + wcol + j * 16 + (lane & 15);
    float bv = bias[col];
#pragma unroll
    for (int i = 0; i < 4; i++) {
      int rowb = row0 + wrow + i * 16 + (lane >> 4) * 4;
#pragma unroll
      for (int r = 0; r < 4; r++)
        O[(size_t)(rowb + r) * C_ + col] = acc[i][j][r] + bv;
    }
  }
}

// ------------------------------------------------- masked-softmax pooling
__global__ void k_pool(const float* __restrict__ lh, const float* __restrict__ att,
                       const float* __restrict__ mask, float* __restrict__ node0) {
  int bi = blockIdx.x >> 2, eg4 = blockIdx.x & 3;
  int tid = threadIdx.x;
  __shared__ float probs[8][512];
  __shared__ float red[4];
  float a0 = att[bi * L_ + tid];
  float a1 = att[bi * L_ + 256 + tid];
  for (int ei = 0; ei < 8; ei++) {
    int e = eg4 * 8 + ei;
    const float* mrow = &mask[(bi * E_ + e) * L_];
    float l0 = a0 - 1e5f * (1.f - mrow[tid]);
    float l1 = a1 - 1e5f * (1.f - mrow[256 + tid]);
    float mx = fmaxf(l0, l1);
#pragma unroll
    for (int o = 32; o; o >>= 1) mx = fmaxf(mx, __shfl_xor(mx, o));
    if ((tid & 63) == 0) red[tid >> 6] = mx;
    __syncthreads();
    mx = fmaxf(fmaxf(red[0], red[1]), fmaxf(red[2], red[3]));
    __syncthreads();
    float e0 = expf(l0 - mx), e1 = expf(l1 - mx);
    float s = e0 + e1;
#pragma unroll
    for (int o = 32; o; o >>= 1) s += __shfl_xor(s, o);
    if ((tid & 63) == 0) red[tid >> 6] = s;
    __syncthreads();
    s = red[0] + red[1] + red[2] + red[3];
    float inv = 1.f / s;
    probs[ei][tid] = e0 * inv;
    probs[ei][256 + tid] = e1 * inv;
    __syncthreads();
  }
  float acc0[8], acc1[8], acc2[8];
#pragma unroll
  for (int e = 0; e < 8; e++) { acc0[e] = 0.f; acc1[e] = 0.f; acc2[e] = 0.f; }
  const float* lb = &lh[bi * L_ * D_];
  for (int l = 0; l < L_; l++) {
    float v0 = lb[l * D_ + tid];
    float v1 = lb[l * D_ + 256 + tid];
    float v2 = lb[l * D_ + 512 + tid];
#pragma unroll
    for (int e = 0; e < 8; e++) {
      float p = probs[e][l];
      acc0[e] += p * v0; acc1[e] += p * v1; acc2[e] += p * v2;
    }
  }
#pragma unroll
  for (int e = 0; e < 8; e++) {
    float* orow = &node0[(bi * E_ + eg4 * 8 + e) * D_];
    orow[tid] = acc0[e]; orow[256 + tid] = acc1[e]; orow[512 + tid] = acc2[e];
  }
}

// -------------------------------------- edge embedding @ We, rank-3 form
__global__ void k_combo2(const float* __restrict__ Wr1, const float* __restrict__ br1,
                         const float* __restrict__ Wm1, const float* __restrict__ bm1,
                         const float* __restrict__ e1W,
                         const float* __restrict__ Wr2, const float* __restrict__ br2,
                         const float* __restrict__ Wm2, const float* __restrict__ bm2,
                         const float* __restrict__ e2W,
                         float* __restrict__ e1c, float* __restrict__ e2c) {
  int x = blockIdx.x;
  int conv = x >> 6;
  int jb = x & 3, kb = (x >> 2) & 15;
  const float *Wr, *br, *Wm, *bm, *eW; float* out;
  if (conv == 0) { Wr = Wr1; br = br1; Wm = Wm1; bm = bm1; eW = e1W; out = e1c; }
  else           { Wr = Wr2; br = br2; Wm = Wm2; bm = bm2; eW = e2W; out = e2c; }
  int tid = threadIdx.x;
  __shared__ float sw[3][64];
  int k0 = kb * 64;
  if (tid < 64) {
    sw[0][tid] = Wr[k0 + tid];
    sw[1][tid] = Wm[k0 + tid];
    sw[2][tid] = br[k0 + tid] + bm[k0 + tid];
  }
  __syncthreads();
  int j = jb * 256 + tid;
  float a0 = 0.f, a1 = 0.f, a2 = 0.f;
#pragma unroll 8
  for (int kk = 0; kk < 64; kk++) {
    float w = eW[(size_t)(k0 + kk) * C_ + j];
    a0 += sw[0][kk] * w; a1 += sw[1][kk] * w; a2 += sw[2][kk] * w;
  }
#pragma unroll
  for (int c = 0; c < 10; c++)
    atomicAdd(&out[c * C_ + j], (float)(c >> 1) * a0 + (float)(c & 1) * a1 + a2);
}

// ------------------------------------------------- CSR build
__global__ void k_count(const int* __restrict__ dst, int* __restrict__ cnt) {
  int eg = blockIdx.x * 256 + threadIdx.x;
  atomicAdd(&cnt[dst[eg]], 1);
}

__global__ void k_scan(const int* __restrict__ cnt, int* __restrict__ off) {
  __shared__ int part[256];
  int t = threadIdx.x;
  int local[8]; int s = 0;
#pragma unroll
  for (int i = 0; i < 8; i++) { local[i] = cnt[t * 8 + i]; s += local[i]; }
  part[t] = s;
  __syncthreads();
  if (t == 0) {
    int r = 0;
    for (int i = 0; i < 256; i++) { int v = part[i]; part[i] = r; r += v; }
    off[N_] = r;
  }
  __syncthreads();
  int r = part[t];
#pragma unroll
  for (int i = 0; i < 8; i++) { off[t * 8 + i] = r; r += local[i]; }
}

__global__ void k_scatter(const int* __restrict__ dst, int* __restrict__ wcnt,
                          const int* __restrict__ off, int* __restrict__ perm) {
  int eg = blockIdx.x * 256 + threadIdx.x;
  int d = dst[eg];
  int p = atomicAdd(&wcnt[d], 1);
  perm[off[d] + p] = eg;
}

// ------------------------------------------------- per-dst attention agg
__global__ void k_agg(const float* __restrict__ q, const float* __restrict__ k,
                      const float* __restrict__ v, const float* __restrict__ ec,
                      const int* __restrict__ srcA, const float* __restrict__ etype,
                      const float* __restrict__ emain, const int* __restrict__ off,
                      const int* __restrict__ perm, float* __restrict__ O) {
  int dst = blockIdx.x;
  int beg = off[dst];
  int cntE = off[dst + 1] - beg;
  if (cntE == 0) return;
  if (cntE > 128) cntE = 128;
  int tid = threadIdx.x;
  __shared__ float lg[128][8];
  __shared__ int srcs[128];
  __shared__ int cids[128];
  for (int e = tid; e < cntE; e += 256) {
    int eg = perm[beg + e];
    srcs[e] = srcA[eg];
    cids[e] = ((int)(etype[eg] + 0.5f)) * 2 + (int)(emain[eg] + 0.5f);
  }
  __syncthreads();
  int c = tid * 4;
  int h = tid >> 5;
  float4 qv = *(const float4*)&q[dst * C_ + c];
  const float scale = 0.08838834764831845f;  // 1/sqrt(128)
  for (int e = 0; e < cntE; e++) {
    int s = srcs[e], ci = cids[e];
    float4 kv = *(const float4*)&k[s * C_ + c];
    float4 ev = *(const float4*)&ec[ci * C_ + c];
    float p = qv.x * (kv.x + ev.x) + qv.y * (kv.y + ev.y) +
              qv.z * (kv.z + ev.z) + qv.w * (kv.w + ev.w);
#pragma unroll
    for (int o = 16; o; o >>= 1) p += __shfl_xor(p, o);
    if ((tid & 31) == 0) lg[e][h] = p * scale;
  }
  __syncthreads();
  if (tid < 8) {
    float m = -1e30f;
    for (int e = 0; e < cntE; e++) m = fmaxf(m, lg[e][tid]);
    float ssum = 0.f;
    for (int e = 0; e < cntE; e++) { float x = expf(lg[e][tid] - m); lg[e][tid] = x; ssum += x; }
    float inv = 1.f / ssum;
    for (int e = 0; e < cntE; e++) lg[e][tid] *= inv;
  }
  __syncthreads();
  float4 acc = {0.f, 0.f, 0.f, 0.f};
  for (int e = 0; e < cntE; e++) {
    float a = lg[e][h];
    int s = srcs[e], ci = cids[e];
    float4 vv = *(const float4*)&v[s * C_ + c];
    float4 ev = *(const float4*)&ec[ci * C_ + c];
    acc.x += a * (vv.x + ev.x); acc.y += a * (vv.y + ev.y);
    acc.z += a * (vv.z + ev.z); acc.w += a * (vv.w + ev.w);
  }
  float4 o = *(const float4*)&O[dst * C_ + c];
  o.x += acc.x; o.y += acc.y; o.z += acc.z; o.w += acc.w;
  *(float4*)&O[dst * C_ + c] = o;
}

// ------------------------------------------------- final gather + FC
__global__ void k_final(const float* __restrict__ nB, const int* __restrict__ lens,
                        const float* __restrict__ fcW, const float* __restrict__ fcb,
                        float* __restrict__ out) {
  int b = blockIdx.x;
  int idx = lens[b] - 1;
  const float* row = &nB[(b * E_ + idx) * C_];
  int tid = threadIdx.x;
  int c = tid * 4;
  float4 r = *(const float4*)&row[c];
  float4 w0 = *(const float4*)&fcW[(c + 0) * 4];
  float4 w1 = *(const float4*)&fcW[(c + 1) * 4];
  float4 w2 = *(const float4*)&fcW[(c + 2) * 4];
  float4 w3 = *(const float4*)&fcW[(c + 3) * 4];
  float p0 = r.x * w0.x + r.y * w1.x + r.z * w2.x + r.w * w3.x;
  float p1 = r.x * w0.y + r.y * w1.y + r.z * w2.y + r.w * w3.y;
  float p2 = r.x * w0.z + r.y * w1.z + r.z * w2.z + r.w * w3.z;
  float p3 = r.x * w0.w + r.y * w1.w + r.z * w2.w + r.w * w3.w;
#pragma unroll
  for (int o = 32; o; o >>= 1) {
    p0 += __shfl_xor(p0, o); p1 += __shfl_xor(p1, o);
    p2 += __shfl_xor(p2, o); p3 += __shfl_xor(p3, o);
  }
  __shared__ float red[4][4];
  if ((tid & 63) == 0) {
    int w = tid >> 6;
    red[w][0] = p0; red[w][1] = p1; red[w][2] = p2; red[w][3] = p3;
  }
  __syncthreads();
  if (tid == 0) {
#pragma unroll
    for (int j = 0; j < 4; j++)
      out[b * 4 + j] = red[0][j] + red[1][j] + red[2][j] + red[3][j] + fcb[j];
  }
}

// ================================================================ launch
extern "C" void kernel_launch(void* const* d_in, const int* in_sizes, int n_in,
                              void* d_out, int out_size, void* d_ws, size_t ws_size,
                              hipStream_t stream) {
  (void)in_sizes; (void)n_in; (void)out_size; (void)ws_size;
  const float* lh    = (const float*)d_in[0];
  const float* mask  = (const float*)d_in[1];
  const int*   lens  = (const int*)d_in[2];
  const int*   edge  = (const int*)d_in[3];
  const float* etype = (const float*)d_in[4];
  const float* emain = (const float*)d_in[5];
  const float* W1   = (const float*)d_in[6];
  const float* b1   = (const float*)d_in[7];
  const float* W2   = (const float*)d_in[8];
  const float* b2   = (const float*)d_in[9];
  const float* Wr1  = (const float*)d_in[10];
  const float* br1  = (const float*)d_in[11];
  const float* Wm1  = (const float*)d_in[12];
  const float* bm1  = (const float*)d_in[13];
  const float* Wr2  = (const float*)d_in[14];
  const float* br2  = (const float*)d_in[15];
  const float* Wm2  = (const float*)d_in[16];
  const float* bm2  = (const float*)d_in[17];
  const float* q1W  = (const float*)d_in[18];
  const float* q1b  = (const float*)d_in[19];
  const float* k1W  = (const float*)d_in[20];
  const float* k1b  = (const float*)d_in[21];
  const float* v1W  = (const float*)d_in[22];
  const float* v1b  = (const float*)d_in[23];
  const float* e1W  = (const float*)d_in[24];
  const float* s1W  = (const float*)d_in[25];
  const float* s1b  = (const float*)d_in[26];
  const float* q2W  = (const float*)d_in[27];
  const float* q2b  = (const float*)d_in[28];
  const float* k2W  = (const float*)d_in[29];
  const float* k2b  = (const float*)d_in[30];
  const float* v2W  = (const float*)d_in[31];
  const float* v2b  = (const float*)d_in[32];
  const float* e2W  = (const float*)d_in[33];
  const float* s2W  = (const float*)d_in[34];
  const float* s2b  = (const float*)d_in[35];
  const float* fcW  = (const float*)d_in[36];
  const float* fcb  = (const float*)d_in[37];

  float* ws    = (float*)d_ws;
  float* att   = ws;                       // 32768
  float* node0 = att + 32768;              // 2048*768
  float* e1c   = node0 + N_ * D_;          // 10*1024
  float* e2c   = e1c + 10 * 1024;
  float* qb    = e2c + 10 * 1024;          // 2048*1024 each
  float* kb    = qb + N_ * C_;
  float* vb    = kb + N_ * C_;
  float* nA    = vb + N_ * C_;
  float* nBuf  = nA + N_ * C_;
  int* cnt  = (int*)(nBuf + N_ * C_);      // 2048
  int* wcnt = cnt + N_;                    // 2048
  int* off  = wcnt + N_;                   // 2049 (pad to 2056)
  int* perm = off + (N_ + 8);              // 32768
  u16* w1t = (u16*)(perm + EG_);           // 512*768
  u16* wt1 = w1t + SH_ * D_;               // 4*1024*768
  u16* wt2 = wt1 + 4 * C_ * D_;            // 4*1024*1024

  const int* srcA = edge;
  const int* dstA = edge + EG_;

  // CSR build (shared by both convs)
  (void)hipMemsetAsync(cnt, 0, 2 * N_ * sizeof(int), stream);
  k_count<<<EG_ / 256, 256, 0, stream>>>(dstA, cnt);
  k_scan<<<1, 256, 0, stream>>>(cnt, off);
  k_scatter<<<EG_ / 256, 256, 0, stream>>>(dstA, wcnt, off, perm);

  // weight prep: transpose -> bf16
  k_wt<<<(D_ / 32) * (SH_ / 32), 256, 0, stream>>>(W1, w1t, D_, SH_);
  k_wt<<<(D_ / 32) * (C_ / 32), 256, 0, stream>>>(q1W, wt1 + 0 * C_ * D_, D_, C_);
  k_wt<<<(D_ / 32) * (C_ / 32), 256, 0, stream>>>(k1W, wt1 + 1 * C_ * D_, D_, C_);
  k_wt<<<(D_ / 32) * (C_ / 32), 256, 0, stream>>>(v1W, wt1 + 2 * C_ * D_, D_, C_);
  k_wt<<<(D_ / 32) * (C_ / 32), 256, 0, stream>>>(s1W, wt1 + 3 * C_ * D_, D_, C_);
  k_wt<<<(C_ / 32) * (C_ / 32), 256, 0, stream>>>(q2W, wt2 + 0 * C_ * C_, C_, C_);
  k_wt<<<(C_ / 32) * (C_ / 32), 256, 0, stream>>>(k2W, wt2 + 1 * C_ * C_, C_, C_);
  k_wt<<<(C_ / 32) * (C_ / 32), 256, 0, stream>>>(v2W, wt2 + 2 * C_ * C_, C_, C_);
  k_wt<<<(C_ / 32) * (C_ / 32), 256, 0, stream>>>(s2W, wt2 + 3 * C_ * C_, C_, C_);

  // span attention -> att
  k_att_init<<<128, 256, 0, stream>>>(b2, att);
  k_span_m<<<1024, 256, 0, stream>>>(lh, w1t, b1, W2, att);

  // 10-combo edge embeddings (rank-3 decomposition, both convs in one launch)
  (void)hipMemsetAsync(e1c, 0, 20 * C_ * sizeof(float), stream);
  k_combo2<<<128, 256, 0, stream>>>(Wr1, br1, Wm1, bm1, e1W,
                                    Wr2, br2, Wm2, bm2, e2W, e1c, e2c);

  // pooling -> node0
  k_pool<<<256, 256, 0, stream>>>(lh, att, mask, node0);

  // conv1
  k_gemm4_m<<<512, 256, 0, stream>>>(node0, D_, wt1,
                                     q1b, k1b, v1b, s1b, qb, kb, vb, nA);
  k_agg<<<N_, 256, 0, stream>>>(qb, kb, vb, e1c, srcA, etype, emain, off, perm, nA);

  // conv2
  k_gemm4_m<<<512, 256, 0, stream>>>(nA, C_, wt2,
                                     q2b, k2b, v2b, s2b, qb, kb, vb, nBuf);
  k_agg<<<N_, 256, 0, stream>>>(qb, kb, vb, e2c, srcA, etype, emain, off, perm, nBuf);

  // final
  k_final<<<B_, 256, 0, stream>>>(nBuf, lens, fcW, fcb, (float*)d_out);
}

// Round 7
// 411.278 us; speedup vs baseline: 2.7593x; 1.0344x over previous
//
#include <hip/hip_runtime.h>
#include <math.h>
#include <stdint.h>

#define B_  64
#define E_  32
#define L_  512
#define D_  768
#define C_  1024
#define H_  8
#define EG_ 32768
#define SH_ 512
#define N_  2048   // B*E

typedef __bf16 bf16x8 __attribute__((ext_vector_type(8)));
typedef float f32x4 __attribute__((ext_vector_type(4)));
typedef unsigned short u16;
typedef u16 u16x4 __attribute__((ext_vector_type(4)));

// ---------------------------------------------------------------- helpers

__device__ __forceinline__ u16 bf16_rn(float x) {
  unsigned u = __builtin_bit_cast(unsigned, x);
  unsigned r = u + 0x7FFFu + ((u >> 16) & 1u);
  return (u16)(r >> 16);
}

__device__ __forceinline__ void gload16(const void* g, void* l) {
  __builtin_amdgcn_global_load_lds(
      (const __attribute__((address_space(1))) void*)(unsigned long long)(uintptr_t)g,
      (__attribute__((address_space(3))) void*)(unsigned int)(uintptr_t)l,
      16, 0, 0);
}

// ------------------------------------------------- merged weight prep (9 mats)
__global__ void k_wt9(const float* __restrict__ s0, const float* __restrict__ s1,
                      const float* __restrict__ s2, const float* __restrict__ s3,
                      const float* __restrict__ s4, const float* __restrict__ s5,
                      const float* __restrict__ s6, const float* __restrict__ s7,
                      const float* __restrict__ s8, u16* __restrict__ dstBase) {
  int x = blockIdx.x;
  const float* W; u16* TH; int K, Nc;
  if (x < 384) {                       // W1: 768x512
    W = s0; TH = dstBase; K = D_; Nc = SH_;
  } else if (x < 384 + 4 * 768) {      // conv1 q/k/v/s: 768x1024
    int i = (x - 384) / 768; x = (x - 384) % 768;
    W = (i == 0) ? s1 : (i == 1) ? s2 : (i == 2) ? s3 : s4;
    TH = dstBase + SH_ * D_ + (size_t)i * C_ * D_; K = D_; Nc = C_;
  } else {                             // conv2 q/k/v/s: 1024x1024
    int i = (x - 3456) / 1024; x = (x - 3456) % 1024;
    W = (i == 0) ? s5 : (i == 1) ? s6 : (i == 2) ? s7 : s8;
    TH = dstBase + SH_ * D_ + 4 * (size_t)C_ * D_ + (size_t)i * C_ * C_; K = C_; Nc = C_;
  }
  __shared__ float Ts[32][33];
  int nbk = K >> 5;
  int bk = x % nbk, bn = x / nbk;
  int tid = threadIdx.x;
  int tx = tid & 31, ty = tid >> 5;
  for (int r = ty; r < 32; r += 8)
    Ts[r][tx] = W[(size_t)(bk * 32 + r) * Nc + bn * 32 + tx];
  __syncthreads();
  for (int r = ty; r < 32; r += 8) {
    float v = Ts[tx][r];
    TH[(size_t)(bn * 32 + r) * K + bk * 32 + tx] = bf16_rn(v);
  }
}

// ------------------------------------------------- MFMA GEMM core (plain bf16)
__device__ __forceinline__ void gemm_core(
    const float* __restrict__ X, const u16* __restrict__ Bt,
    int K, int row0, int col0,
    u16* Ah, u16* Bh, f32x4 acc[4][4])
{
  int tid = threadIdx.x;
  int lane = tid & 63, w = tid >> 6;
  int wrow = (w & 1) * 64, wcol = (w >> 1) * 64;

  int aoff[4], boff[4];
#pragma unroll
  for (int i = 0; i < 4; i++) {
    int kc = lane >> 4;
    int rT = wrow + i * 16 + (lane & 15);
    aoff[i] = rT * 64 + (((kc ^ ((rT >> 1) & 3)) & 3) << 4);
    int cT = wcol + i * 16 + (lane & 15);
    boff[i] = cT * 64 + (((kc ^ ((cT >> 1) & 3)) & 3) << 4);
  }

  int nkt = K >> 5;
  for (int kt = 0; kt < nkt; kt++) {
    int k0 = kt << 5;
    if (kt) __syncthreads();
#pragma unroll
    for (int p = 0; p < 4; p++) {
      int idx = tid + p * 256;
      int r = idx >> 3, c4 = idx & 7;
      float4 v = *(const float4*)&X[(size_t)(row0 + r) * K + k0 + c4 * 4];
      u16x4 hi = {bf16_rn(v.x), bf16_rn(v.y), bf16_rn(v.z), bf16_rn(v.w)};
      int off = r * 64 + ((((c4 >> 1) ^ ((r >> 1) & 3)) & 3) << 4) + (c4 & 1) * 8;
      *(u16x4*)((char*)Ah + off) = hi;
    }
#pragma unroll
    for (int q = 0; q < 2; q++) {
      int rT = w * 32 + q * 16 + (lane >> 2);
      int kc = lane & 3;
      size_t gb = (size_t)(col0 + rT) * K + k0 + (((kc ^ ((rT >> 1) & 3)) & 3) << 3);
      int lb = (w * 32 + q * 16) * 32;
      gload16(&Bt[gb], &Bh[lb]);
    }
    __syncthreads();
    bf16x8 ah[4];
#pragma unroll
    for (int i = 0; i < 4; i++)
      ah[i] = *(const bf16x8*)((const char*)Ah + aoff[i]);
#pragma unroll
    for (int j = 0; j < 4; j++) {
      bf16x8 bh = *(const bf16x8*)((const char*)Bh + boff[j]);
#pragma unroll
      for (int i = 0; i < 4; i++)
        acc[i][j] = __builtin_amdgcn_mfma_f32_16x16x32_bf16(ah[i], bh, acc[i][j], 0, 0, 0);
    }
  }
}

// ------------------------------------------------- span MLP (MFMA) -> partials
// partial slot = cb*2 + (w>>1): per col-block (4) x per wave-column-half (2).
__global__ __launch_bounds__(256) void k_span_m(
    const float* __restrict__ lh, const u16* __restrict__ W1t,
    const float* __restrict__ b1, const float* __restrict__ W2,
    float* __restrict__ att8) {
  __shared__ __align__(16) u16 Ah[128 * 32], Bh[128 * 32];
  int rb = blockIdx.x & 255, cb = blockIdx.x >> 8;
  int row0 = rb * 128, col0 = cb * 128;
  f32x4 acc[4][4];
#pragma unroll
  for (int i = 0; i < 4; i++)
#pragma unroll
    for (int j = 0; j < 4; j++) acc[i][j] = (f32x4){0.f, 0.f, 0.f, 0.f};
  gemm_core(lh, W1t, D_, row0, col0, Ah, Bh, acc);

  int lane = threadIdx.x & 63, w = threadIdx.x >> 6;
  int wrow = (w & 1) * 64, wcol = (w >> 1) * 64;
  float b1v[4], w2v[4];
#pragma unroll
  for (int j = 0; j < 4; j++) {
    int col = col0 + wcol + j * 16 + (lane & 15);
    b1v[j] = b1[col]; w2v[j] = W2[col];
  }
  float* dst = att8 + (size_t)(cb * 2 + (w >> 1)) * 32768;
#pragma unroll
  for (int i = 0; i < 4; i++) {
#pragma unroll
    for (int r = 0; r < 4; r++) {
      float s = 0.f;
#pragma unroll
      for (int j = 0; j < 4; j++) {
        float h = acc[i][j][r] + b1v[j];
        s += fmaxf(h, 0.f) * w2v[j];
      }
      s += __shfl_xor(s, 1); s += __shfl_xor(s, 2);
      s += __shfl_xor(s, 4); s += __shfl_xor(s, 8);
      // waves with the same (w>>1) cover disjoint row ranges (wrow differs);
      // waves with different (w>>1) write different slots -> store is exclusive.
      if ((lane & 15) == 0)
        dst[row0 + wrow + i * 16 + (lane >> 4) * 4 + r] = s;
    }
  }
}

// ------------------------------------------------- probs: masked softmax
// grid 256 = bi(64) x eg(4); wave-per-EDU, 2 iterations -> 8 EDUs/block.
__global__ void k_probs(const float* __restrict__ att8, const float* __restrict__ b2,
                        const float* __restrict__ mask, float* __restrict__ pr) {
  int bi = blockIdx.x >> 2, eg = blockIdx.x & 3;
  int tid = threadIdx.x, lane = tid & 63, w = tid >> 6;
  __shared__ float att_s[512];
  float b2v = b2[0];
  int r0 = bi * 512 + tid;
  float s0 = b2v, s1 = b2v;
#pragma unroll
  for (int p = 0; p < 8; p++) {
    s0 += att8[(size_t)p * 32768 + r0];
    s1 += att8[(size_t)p * 32768 + r0 + 256];
  }
  att_s[tid] = s0;
  att_s[tid + 256] = s1;
  __syncthreads();
#pragma unroll
  for (int it = 0; it < 2; it++) {
    int e = eg * 8 + it * 4 + w;
    const float* mrow = &mask[(size_t)(bi * E_ + e) * L_];
    float4 m0 = *(const float4*)&mrow[lane * 8];
    float4 m1 = *(const float4*)&mrow[lane * 8 + 4];
    float4 a0 = *(const float4*)&att_s[lane * 8];
    float4 a1 = *(const float4*)&att_s[lane * 8 + 4];
    float v[8];
    v[0] = a0.x - 1e5f * (1.f - m0.x); v[1] = a0.y - 1e5f * (1.f - m0.y);
    v[2] = a0.z - 1e5f * (1.f - m0.z); v[3] = a0.w - 1e5f * (1.f - m0.w);
    v[4] = a1.x - 1e5f * (1.f - m1.x); v[5] = a1.y - 1e5f * (1.f - m1.y);
    v[6] = a1.z - 1e5f * (1.f - m1.z); v[7] = a1.w - 1e5f * (1.f - m1.w);
    float mx = v[0];
#pragma unroll
    for (int i = 1; i < 8; i++) mx = fmaxf(mx, v[i]);
#pragma unroll
    for (int o = 32; o; o >>= 1) mx = fmaxf(mx, __shfl_xor(mx, o));
    float s = 0.f;
#pragma unroll
    for (int i = 0; i < 8; i++) { v[i] = expf(v[i] - mx); s += v[i]; }
#pragma unroll
    for (int o = 32; o; o >>= 1) s += __shfl_xor(s, o);
    float inv = 1.f / s;
    float4 o0 = {v[0] * inv, v[1] * inv, v[2] * inv, v[3] * inv};
    float4 o1 = {v[4] * inv, v[5] * inv, v[6] * inv, v[7] * inv};
    float* prow = &pr[(size_t)(bi * E_ + e) * L_];
    *(float4*)&prow[lane * 8] = o0;
    *(float4*)&prow[lane * 8 + 4] = o1;
  }
}

// ------------------------------------------------- pool accumulate: node0 = probs @ lh
__global__ __launch_bounds__(256) void k_pool_acc(const float* __restrict__ lh,
    const float* __restrict__ pr, float* __restrict__ node0) {
  int x = blockIdx.x;
  int bi = x / 6; int r = x % 6;
  int eh = r / 3, dc = r % 3;
  int d = dc * 256 + threadIdx.x;
  const float* lb = &lh[(size_t)(bi * L_) * D_ + d];
  const float* pb = &pr[(size_t)(bi * E_ + eh * 16) * L_];
  float acc[16];
#pragma unroll
  for (int e = 0; e < 16; e++) acc[e] = 0.f;
  for (int l0 = 0; l0 < L_; l0 += 8) {
    float xv[8];
#pragma unroll
    for (int i = 0; i < 8; i++) xv[i] = lb[(size_t)(l0 + i) * D_];
#pragma unroll
    for (int e = 0; e < 16; e++) {
      const float* pe = &pb[(size_t)e * L_ + l0];
      float4 pA = *(const float4*)&pe[0];
      float4 pB = *(const float4*)&pe[4];
      acc[e] += pA.x * xv[0] + pA.y * xv[1] + pA.z * xv[2] + pA.w * xv[3]
              + pB.x * xv[4] + pB.y * xv[5] + pB.z * xv[6] + pB.w * xv[7];
    }
  }
#pragma unroll
  for (int e = 0; e < 16; e++)
    node0[(size_t)(bi * E_ + eh * 16 + e) * D_ + d] = acc[e];
}

// ------------------------------------------------- fused q/k/v/skip GEMM (MFMA)
__global__ __launch_bounds__(256) void k_gemm4_m(
    const float* __restrict__ X, int K,
    const u16* __restrict__ Wt,
    const float* __restrict__ bb0, const float* __restrict__ bb1,
    const float* __restrict__ bb2, const float* __restrict__ bb3,
    float* __restrict__ O0, float* __restrict__ O1,
    float* __restrict__ O2, float* __restrict__ O3) {
  __shared__ __align__(16) u16 Ah[128 * 32], Bh[128 * 32];
  int rb = blockIdx.x & 15, cbm = blockIdx.x >> 4;
  int mat = cbm >> 3;
  int col0 = (cbm & 7) * 128, row0 = rb * 128;
  const u16* Bt = Wt + (size_t)mat * C_ * K;
  const float* bias; float* O;
  if (mat == 0)      { bias = bb0; O = O0; }
  else if (mat == 1) { bias = bb1; O = O1; }
  else if (mat == 2) { bias = bb2; O = O2; }
  else               { bias = bb3; O = O3; }

  f32x4 acc[4][4];
#pragma unroll
  for (int i = 0; i < 4; i++)
#pragma unroll
    for (int j = 0; j < 4; j++) acc[i][j] = (f32x4){0.f, 0.f, 0.f, 0.f};
  gemm_core(X, Bt, K, row0, col0, Ah, Bh, acc);

  int lane = threadIdx.x & 63, w = threadIdx.x >> 6;
  int wrow = (w & 1) * 64, wcol = (w >> 1) * 64;
#pragma unroll
  for (int j = 0; j < 4; j++) {
    int col = col0 + wcol + j * 16 + (lane & 15);
    float bv = bias[col];
#pragma unroll
    for (int i = 0; i < 4; i++) {
      int rowb = row0 + wrow + i * 16 + (lane >> 4) * 4;
#pragma unroll
      for (int r = 0; r < 4; r++)
        O[(size_t)(rowb + r) * C_ + col] = acc[i][j][r] + bv;
    }
  }
}

// -------------------------------------- edge embedding @ We, rank-3 form
__global__ void k_combo2(const float* __restrict__ Wr1, const float* __restrict__ br1,
                         const float* __restrict__ Wm1, const float* __restrict__ bm1,
                         const float* __restrict__ e1W,
                         const float* __restrict__ Wr2, const float* __restrict__ br2,
                         const float* __restrict__ Wm2, const float* __restrict__ bm2,
                         const float* __restrict__ e2W,
                         float* __restrict__ e1c, float* __restrict__ e2c) {
  int x = blockIdx.x;
  int conv = x >> 6;
  int jb = x & 3, kb = (x >> 2) & 15;
  const float *Wr, *br, *Wm, *bm, *eW; float* out;
  if (conv == 0) { Wr = Wr1; br = br1; Wm = Wm1; bm = bm1; eW = e1W; out = e1c; }
  else           { Wr = Wr2; br = br2; Wm = Wm2; bm = bm2; eW = e2W; out = e2c; }
  int tid = threadIdx.x;
  __shared__ float sw[3][64];
  int k0 = kb * 64;
  if (tid < 64) {
    sw[0][tid] = Wr[k0 + tid];
    sw[1][tid] = Wm[k0 + tid];
    sw[2][tid] = br[k0 + tid] + bm[k0 + tid];
  }
  __syncthreads();
  int j = jb * 256 + tid;
  float a0 = 0.f, a1 = 0.f, a2 = 0.f;
#pragma unroll 8
  for (int kk = 0; kk < 64; kk++) {
    float w = eW[(size_t)(k0 + kk) * C_ + j];
    a0 += sw[0][kk] * w; a1 += sw[1][kk] * w; a2 += sw[2][kk] * w;
  }
#pragma unroll
  for (int c = 0; c < 10; c++)
    atomicAdd(&out[c * C_ + j], (float)(c >> 1) * a0 + (float)(c & 1) * a1 + a2);
}

// ------------------------------------------------- CSR build
__global__ void k_count(const int* __restrict__ dst, int* __restrict__ cnt) {
  int eg = blockIdx.x * 256 + threadIdx.x;
  atomicAdd(&cnt[dst[eg]], 1);
}

__global__ void k_scan(const int* __restrict__ cnt, int* __restrict__ off) {
  __shared__ int part[256];
  int t = threadIdx.x;
  int local[8]; int s = 0;
#pragma unroll
  for (int i = 0; i < 8; i++) { local[i] = cnt[t * 8 + i]; s += local[i]; }
  part[t] = s;
  __syncthreads();
  if (t == 0) {
    int r = 0;
    for (int i = 0; i < 256; i++) { int v = part[i]; part[i] = r; r += v; }
    off[N_] = r;
  }
  __syncthreads();
  int r = part[t];
#pragma unroll
  for (int i = 0; i < 8; i++) { off[t * 8 + i] = r; r += local[i]; }
}

__global__ void k_scatter(const int* __restrict__ dst, int* __restrict__ wcnt,
                          const int* __restrict__ off, int* __restrict__ perm) {
  int eg = blockIdx.x * 256 + threadIdx.x;
  int d = dst[eg];
  int p = atomicAdd(&wcnt[d], 1);
  perm[off[d] + p] = eg;
}

// ------------------------------------------------- per-dst attention agg
__global__ void k_agg(const float* __restrict__ q, const float* __restrict__ k,
                      const float* __restrict__ v, const float* __restrict__ ec,
                      const int* __restrict__ srcA, const float* __restrict__ etype,
                      const float* __restrict__ emain, const int* __restrict__ off,
                      const int* __restrict__ perm, float* __restrict__ O) {
  int dst = blockIdx.x;
  int beg = off[dst];
  int cntE = off[dst + 1] - beg;
  if (cntE == 0) return;
  if (cntE > 128) cntE = 128;
  int tid = threadIdx.x;
  __shared__ float lg[128][8];
  __shared__ int srcs[128];
  __shared__ int cids[128];
  for (int e = tid; e < cntE; e += 256) {
    int eg = perm[beg + e];
    srcs[e] = srcA[eg];
    cids[e] = ((int)(etype[eg] + 0.5f)) * 2 + (int)(emain[eg] + 0.5f);
  }
  __syncthreads();
  int c = tid * 4;
  int h = tid >> 5;
  float4 qv = *(const float4*)&q[dst * C_ + c];
  const float scale = 0.08838834764831845f;  // 1/sqrt(128)
  for (int e = 0; e < cntE; e++) {
    int s = srcs[e], ci = cids[e];
    float4 kv = *(const float4*)&k[s * C_ + c];
    float4 ev = *(const float4*)&ec[ci * C_ + c];
    float p = qv.x * (kv.x + ev.x) + qv.y * (kv.y + ev.y) +
              qv.z * (kv.z + ev.z) + qv.w * (kv.w + ev.w);
#pragma unroll
    for (int o = 16; o; o >>= 1) p += __shfl_xor(p, o);
    if ((tid & 31) == 0) lg[e][h] = p * scale;
  }
  __syncthreads();
  if (tid < 8) {
    float m = -1e30f;
    for (int e = 0; e < cntE; e++) m = fmaxf(m, lg[e][tid]);
    float ssum = 0.f;
    for (int e = 0; e < cntE; e++) { float x = expf(lg[e][tid] - m); lg[e][tid] = x; ssum += x; }
    float inv = 1.f / ssum;
    for (int e = 0; e < cntE; e++) lg[e][tid] *= inv;
  }
  __syncthreads();
  float4 acc = {0.f, 0.f, 0.f, 0.f};
  for (int e = 0; e < cntE; e++) {
    float a = lg[e][h];
    int s = srcs[e], ci = cids[e];
    float4 vv = *(const float4*)&v[s * C_ + c];
    float4 ev = *(const float4*)&ec[ci * C_ + c];
    acc.x += a * (vv.x + ev.x); acc.y += a * (vv.y + ev.y);
    acc.z += a * (vv.z + ev.z); acc.w += a * (vv.w + ev.w);
  }
  float4 o = *(const float4*)&O[dst * C_ + c];
  o.x += acc.x; o.y += acc.y; o.z += acc.z; o.w += acc.w;
  *(float4*)&O[dst * C_ + c] = o;
}

// ------------------------------------------------- final gather + FC
__global__ void k_final(const float* __restrict__ nB, const int* __restrict__ lens,
                        const float* __restrict__ fcW, const float* __restrict__ fcb,
                        float* __restrict__ out) {
  int b = blockIdx.x;
  int idx = lens[b] - 1;
  const float* row = &nB[(b * E_ + idx) * C_];
  int tid = threadIdx.x;
  int c = tid * 4;
  float4 r = *(const float4*)&row[c];
  float4 w0 = *(const float4*)&fcW[(c + 0) * 4];
  float4 w1 = *(const float4*)&fcW[(c + 1) * 4];
  float4 w2 = *(const float4*)&fcW[(c + 2) * 4];
  float4 w3 = *(const float4*)&fcW[(c + 3) * 4];
  float p0 = r.x * w0.x + r.y * w1.x + r.z * w2.x + r.w * w3.x;
  float p1 = r.x * w0.y + r.y * w1.y + r.z * w2.y + r.w * w3.y;
  float p2 = r.x * w0.z + r.y * w1.z + r.z * w2.z + r.w * w3.z;
  float p3 = r.x * w0.w + r.y * w1.w + r.z * w2.w + r.w * w3.w;
#pragma unroll
  for (int o = 32; o; o >>= 1) {
    p0 += __shfl_xor(p0, o); p1 += __shfl_xor(p1, o);
    p2 += __shfl_xor(p2, o); p3 += __shfl_xor(p3, o);
  }
  __shared__ float red[4][4];
  if ((tid & 63) == 0) {
    int w = tid >> 6;
    red[w][0] = p0; red[w][1] = p1; red[w][2] = p2; red[w][3] = p3;
  }
  __syncthreads();
  if (tid == 0) {
#pragma unroll
    for (int j = 0; j < 4; j++)
      out[b * 4 + j] = red[0][j] + red[1][j] + red[2][j] + red[3][j] + fcb[j];
  }
}

// ================================================================ launch
extern "C" void kernel_launch(void* const* d_in, const int* in_sizes, int n_in,
                              void* d_out, int out_size, void* d_ws, size_t ws_size,
                              hipStream_t stream) {
  (void)in_sizes; (void)n_in; (void)out_size; (void)ws_size;
  const float* lh    = (const float*)d_in[0];
  const float* mask  = (const float*)d_in[1];
  const int*   lens  = (const int*)d_in[2];
  const int*   edge  = (const int*)d_in[3];
  const float* etype = (const float*)d_in[4];
  const float* emain = (const float*)d_in[5];
  const float* W1   = (const float*)d_in[6];
  const float* b1   = (const float*)d_in[7];
  const float* W2   = (const float*)d_in[8];
  const float* b2   = (const float*)d_in[9];
  const float* Wr1  = (const float*)d_in[10];
  const float* br1  = (const float*)d_in[11];
  const float* Wm1  = (const float*)d_in[12];
  const float* bm1  = (const float*)d_in[13];
  const float* Wr2  = (const float*)d_in[14];
  const float* br2  = (const float*)d_in[15];
  const float* Wm2  = (const float*)d_in[16];
  const float* bm2  = (const float*)d_in[17];
  const float* q1W  = (const float*)d_in[18];
  const float* q1b  = (const float*)d_in[19];
  const float* k1W  = (const float*)d_in[20];
  const float* k1b  = (const float*)d_in[21];
  const float* v1W  = (const float*)d_in[22];
  const float* v1b  = (const float*)d_in[23];
  const float* e1W  = (const float*)d_in[24];
  const float* s1W  = (const float*)d_in[25];
  const float* s1b  = (const float*)d_in[26];
  const float* q2W  = (const float*)d_in[27];
  const float* q2b  = (const float*)d_in[28];
  const float* k2W  = (const float*)d_in[29];
  const float* k2b  = (const float*)d_in[30];
  const float* v2W  = (const float*)d_in[31];
  const float* v2b  = (const float*)d_in[32];
  const float* e2W  = (const float*)d_in[33];
  const float* s2W  = (const float*)d_in[34];
  const float* s2b  = (const float*)d_in[35];
  const float* fcW  = (const float*)d_in[36];
  const float* fcb  = (const float*)d_in[37];

  float* ws    = (float*)d_ws;
  float* att   = ws;                       // 32768 (spare)
  float* node0 = att + 32768;              // 2048*768
  float* e1c   = node0 + N_ * D_;          // 10*1024
  float* e2c   = e1c + 10 * 1024;
  float* qb    = e2c + 10 * 1024;          // 2048*1024 each
  float* kb    = qb + N_ * C_;
  float* vb    = kb + N_ * C_;
  float* nA    = vb + N_ * C_;
  float* nBuf  = nA + N_ * C_;
  int* cnt  = (int*)(nBuf + N_ * C_);      // 2048
  int* wcnt = cnt + N_;                    // 2048
  int* off  = wcnt + N_;                   // 2049 (pad to 2056)
  int* perm = off + (N_ + 8);              // 32768
  u16* wtb  = (u16*)(perm + EG_);          // all 9 bf16 transposed weights
  u16* w1t  = wtb;                         // 512*768
  u16* wt1  = w1t + SH_ * D_;              // 4*1024*768
  u16* wt2  = wt1 + 4 * C_ * D_;           // 4*1024*1024

  // transient aliases (consumed before conv1 gemm4 overwrites qb/kb)
  float* pr   = qb;                        // probs: 2048*512 fp32
  float* att8 = kb;                        // span partials: 8*32768 (1 MB of 8 MB)

  const int* srcA = edge;
  const int* dstA = edge + EG_;

  // CSR build (shared by both convs)
  (void)hipMemsetAsync(cnt, 0, 2 * N_ * sizeof(int), stream);
  k_count<<<EG_ / 256, 256, 0, stream>>>(dstA, cnt);
  k_scan<<<1, 256, 0, stream>>>(cnt, off);
  k_scatter<<<EG_ / 256, 256, 0, stream>>>(dstA, wcnt, off, perm);

  // weight prep: all 9 transposes in one launch
  k_wt9<<<384 + 4 * 768 + 4 * 1024, 256, 0, stream>>>(
      W1, q1W, k1W, v1W, s1W, q2W, k2W, v2W, s2W, wtb);

  // span attention partials -> att8
  k_span_m<<<1024, 256, 0, stream>>>(lh, w1t, b1, W2, att8);

  // 10-combo edge embeddings (rank-3 decomposition)
  (void)hipMemsetAsync(e1c, 0, 20 * C_ * sizeof(float), stream);
  k_combo2<<<128, 256, 0, stream>>>(Wr1, br1, Wm1, bm1, e1W,
                                    Wr2, br2, Wm2, bm2, e2W, e1c, e2c);

  // pooling: probs then accumulate
  k_probs<<<256, 256, 0, stream>>>(att8, b2, mask, pr);
  k_pool_acc<<<384, 256, 0, stream>>>(lh, pr, node0);

  // conv1
  k_gemm4_m<<<512, 256, 0, stream>>>(node0, D_, wt1,
                                     q1b, k1b, v1b, s1b, qb, kb, vb, nA);
  k_agg<<<N_, 256, 0, stream>>>(qb, kb, vb, e1c, srcA, etype, emain, off, perm, nA);

  // conv2
  k_gemm4_m<<<512, 256, 0, stream>>>(nA, C_, wt2,
                                     q2b, k2b, v2b, s2b, qb, kb, vb, nBuf);
  k_agg<<<N_, 256, 0, stream>>>(qb, kb, vb, e2c, srcA, etype, emain, off, perm, nBuf);

  // final
  k_final<<<B_, 256, 0, stream>>>(nBuf, lens, fcW, fcb, (float*)d_out);
}

// Round 8
// 390.647 us; speedup vs baseline: 2.9050x; 1.0528x over previous
//
#include <hip/hip_runtime.h>
#include <math.h>
#include <stdint.h>

#define B_  64
#define E_  32
#define L_  512
#define D_  768
#define C_  1024
#define H_  8
#define EG_ 32768
#define SH_ 512
#define N_  2048   // B*E
#define ND_ (N_ * D_)   // 1572864

typedef __bf16 bf16x8 __attribute__((ext_vector_type(8)));
typedef float f32x4 __attribute__((ext_vector_type(4)));
typedef unsigned short u16;
typedef u16 u16x4 __attribute__((ext_vector_type(4)));

// ---------------------------------------------------------------- helpers

__device__ __forceinline__ u16 bf16_rn(float x) {
  unsigned u = __builtin_bit_cast(unsigned, x);
  unsigned r = u + 0x7FFFu + ((u >> 16) & 1u);
  return (u16)(r >> 16);
}

__device__ __forceinline__ void gload16(const void* g, void* l) {
  __builtin_amdgcn_global_load_lds(
      (const __attribute__((address_space(1))) void*)(unsigned long long)(uintptr_t)g,
      (__attribute__((address_space(3))) void*)(unsigned int)(uintptr_t)l,
      16, 0, 0);
}

// ------------------------------------------------- merged weight prep (9 mats)
__global__ void k_wt9(const float* __restrict__ s0, const float* __restrict__ s1,
                      const float* __restrict__ s2, const float* __restrict__ s3,
                      const float* __restrict__ s4, const float* __restrict__ s5,
                      const float* __restrict__ s6, const float* __restrict__ s7,
                      const float* __restrict__ s8, u16* __restrict__ dstBase) {
  int x = blockIdx.x;
  const float* W; u16* TH; int K, Nc;
  if (x < 384) {                       // W1: 768x512
    W = s0; TH = dstBase; K = D_; Nc = SH_;
  } else if (x < 384 + 4 * 768) {      // conv1 q/k/v/s: 768x1024
    int i = (x - 384) / 768; x = (x - 384) % 768;
    W = (i == 0) ? s1 : (i == 1) ? s2 : (i == 2) ? s3 : s4;
    TH = dstBase + SH_ * D_ + (size_t)i * C_ * D_; K = D_; Nc = C_;
  } else {                             // conv2 q/k/v/s: 1024x1024
    int i = (x - 3456) / 1024; x = (x - 3456) % 1024;
    W = (i == 0) ? s5 : (i == 1) ? s6 : (i == 2) ? s7 : s8;
    TH = dstBase + SH_ * D_ + 4 * (size_t)C_ * D_ + (size_t)i * C_ * C_; K = C_; Nc = C_;
  }
  __shared__ float Ts[32][33];
  int nbk = K >> 5;
  int bk = x % nbk, bn = x / nbk;
  int tid = threadIdx.x;
  int tx = tid & 31, ty = tid >> 5;
  for (int r = ty; r < 32; r += 8)
    Ts[r][tx] = W[(size_t)(bk * 32 + r) * Nc + bn * 32 + tx];
  __syncthreads();
  for (int r = ty; r < 32; r += 8) {
    float v = Ts[tx][r];
    TH[(size_t)(bn * 32 + r) * K + bk * 32 + tx] = bf16_rn(v);
  }
}

// ------------------------------------------------- MFMA GEMM core (plain bf16)
__device__ __forceinline__ void gemm_core(
    const float* __restrict__ X, const u16* __restrict__ Bt,
    int K, int row0, int col0,
    u16* Ah, u16* Bh, f32x4 acc[4][4])
{
  int tid = threadIdx.x;
  int lane = tid & 63, w = tid >> 6;
  int wrow = (w & 1) * 64, wcol = (w >> 1) * 64;

  int aoff[4], boff[4];
#pragma unroll
  for (int i = 0; i < 4; i++) {
    int kc = lane >> 4;
    int rT = wrow + i * 16 + (lane & 15);
    aoff[i] = rT * 64 + (((kc ^ ((rT >> 1) & 3)) & 3) << 4);
    int cT = wcol + i * 16 + (lane & 15);
    boff[i] = cT * 64 + (((kc ^ ((cT >> 1) & 3)) & 3) << 4);
  }

  int nkt = K >> 5;
  for (int kt = 0; kt < nkt; kt++) {
    int k0 = kt << 5;
    if (kt) __syncthreads();
#pragma unroll
    for (int p = 0; p < 4; p++) {
      int idx = tid + p * 256;
      int r = idx >> 3, c4 = idx & 7;
      float4 v = *(const float4*)&X[(size_t)(row0 + r) * K + k0 + c4 * 4];
      u16x4 hi = {bf16_rn(v.x), bf16_rn(v.y), bf16_rn(v.z), bf16_rn(v.w)};
      int off = r * 64 + ((((c4 >> 1) ^ ((r >> 1) & 3)) & 3) << 4) + (c4 & 1) * 8;
      *(u16x4*)((char*)Ah + off) = hi;
    }
#pragma unroll
    for (int q = 0; q < 2; q++) {
      int rT = w * 32 + q * 16 + (lane >> 2);
      int kc = lane & 3;
      size_t gb = (size_t)(col0 + rT) * K + k0 + (((kc ^ ((rT >> 1) & 3)) & 3) << 3);
      int lb = (w * 32 + q * 16) * 32;
      gload16(&Bt[gb], &Bh[lb]);
    }
    __syncthreads();
    bf16x8 ah[4];
#pragma unroll
    for (int i = 0; i < 4; i++)
      ah[i] = *(const bf16x8*)((const char*)Ah + aoff[i]);
#pragma unroll
    for (int j = 0; j < 4; j++) {
      bf16x8 bh = *(const bf16x8*)((const char*)Bh + boff[j]);
#pragma unroll
      for (int i = 0; i < 4; i++)
        acc[i][j] = __builtin_amdgcn_mfma_f32_16x16x32_bf16(ah[i], bh, acc[i][j], 0, 0, 0);
    }
  }
}

// ------------------------------------------------- span MLP (MFMA) -> partials
// partial slot = cb*2 + (w>>1): per col-block (4) x per wave-column-half (2).
__global__ __launch_bounds__(256) void k_span_m(
    const float* __restrict__ lh, const u16* __restrict__ W1t,
    const float* __restrict__ b1, const float* __restrict__ W2,
    float* __restrict__ att8) {
  __shared__ __align__(16) u16 Ah[128 * 32], Bh[128 * 32];
  int rb = blockIdx.x & 255, cb = blockIdx.x >> 8;
  int row0 = rb * 128, col0 = cb * 128;
  f32x4 acc[4][4];
#pragma unroll
  for (int i = 0; i < 4; i++)
#pragma unroll
    for (int j = 0; j < 4; j++) acc[i][j] = (f32x4){0.f, 0.f, 0.f, 0.f};
  gemm_core(lh, W1t, D_, row0, col0, Ah, Bh, acc);

  int lane = threadIdx.x & 63, w = threadIdx.x >> 6;
  int wrow = (w & 1) * 64, wcol = (w >> 1) * 64;
  float b1v[4], w2v[4];
#pragma unroll
  for (int j = 0; j < 4; j++) {
    int col = col0 + wcol + j * 16 + (lane & 15);
    b1v[j] = b1[col]; w2v[j] = W2[col];
  }
  float* dst = att8 + (size_t)(cb * 2 + (w >> 1)) * 32768;
#pragma unroll
  for (int i = 0; i < 4; i++) {
#pragma unroll
    for (int r = 0; r < 4; r++) {
      float s = 0.f;
#pragma unroll
      for (int j = 0; j < 4; j++) {
        float h = acc[i][j][r] + b1v[j];
        s += fmaxf(h, 0.f) * w2v[j];
      }
      s += __shfl_xor(s, 1); s += __shfl_xor(s, 2);
      s += __shfl_xor(s, 4); s += __shfl_xor(s, 8);
      if ((lane & 15) == 0)
        dst[row0 + wrow + i * 16 + (lane >> 4) * 4 + r] = s;
    }
  }
}

// ------------------------------------------------- probs: masked softmax
__global__ void k_probs(const float* __restrict__ att8, const float* __restrict__ b2,
                        const float* __restrict__ mask, float* __restrict__ pr) {
  int bi = blockIdx.x >> 2, eg = blockIdx.x & 3;
  int tid = threadIdx.x, lane = tid & 63, w = tid >> 6;
  __shared__ float att_s[512];
  float b2v = b2[0];
  int r0 = bi * 512 + tid;
  float s0 = b2v, s1 = b2v;
#pragma unroll
  for (int p = 0; p < 8; p++) {
    s0 += att8[(size_t)p * 32768 + r0];
    s1 += att8[(size_t)p * 32768 + r0 + 256];
  }
  att_s[tid] = s0;
  att_s[tid + 256] = s1;
  __syncthreads();
#pragma unroll
  for (int it = 0; it < 2; it++) {
    int e = eg * 8 + it * 4 + w;
    const float* mrow = &mask[(size_t)(bi * E_ + e) * L_];
    float4 m0 = *(const float4*)&mrow[lane * 8];
    float4 m1 = *(const float4*)&mrow[lane * 8 + 4];
    float4 a0 = *(const float4*)&att_s[lane * 8];
    float4 a1 = *(const float4*)&att_s[lane * 8 + 4];
    float v[8];
    v[0] = a0.x - 1e5f * (1.f - m0.x); v[1] = a0.y - 1e5f * (1.f - m0.y);
    v[2] = a0.z - 1e5f * (1.f - m0.z); v[3] = a0.w - 1e5f * (1.f - m0.w);
    v[4] = a1.x - 1e5f * (1.f - m1.x); v[5] = a1.y - 1e5f * (1.f - m1.y);
    v[6] = a1.z - 1e5f * (1.f - m1.z); v[7] = a1.w - 1e5f * (1.f - m1.w);
    float mx = v[0];
#pragma unroll
    for (int i = 1; i < 8; i++) mx = fmaxf(mx, v[i]);
#pragma unroll
    for (int o = 32; o; o >>= 1) mx = fmaxf(mx, __shfl_xor(mx, o));
    float s = 0.f;
#pragma unroll
    for (int i = 0; i < 8; i++) { v[i] = expf(v[i] - mx); s += v[i]; }
#pragma unroll
    for (int o = 32; o; o >>= 1) s += __shfl_xor(s, o);
    float inv = 1.f / s;
    float4 o0 = {v[0] * inv, v[1] * inv, v[2] * inv, v[3] * inv};
    float4 o1 = {v[4] * inv, v[5] * inv, v[6] * inv, v[7] * inv};
    float* prow = &pr[(size_t)(bi * E_ + e) * L_];
    *(float4*)&prow[lane * 8] = o0;
    *(float4*)&prow[lane * 8 + 4] = o1;
  }
}

// ------------------------------------------------- pool accumulate (l-split partials)
// grid 768 = bi(64) x dc(3) x lc(4); block: 128 l-rows, all 32 EDUs, 256 cols.
__global__ __launch_bounds__(256) void k_pool_acc2(const float* __restrict__ lh,
    const float* __restrict__ pr, float* __restrict__ np) {
  int x = blockIdx.x;
  int lc = x & 3, r = x >> 2;
  int dc = r % 3, bi = r / 3;
  int d = dc * 256 + threadIdx.x;
  int l0b = lc * 128;
  const float* lb = &lh[((size_t)bi * L_ + l0b) * D_ + d];
  const float* pb = &pr[(size_t)bi * E_ * L_ + l0b];
  float acc[32];
#pragma unroll
  for (int e = 0; e < 32; e++) acc[e] = 0.f;
  for (int l0 = 0; l0 < 128; l0 += 8) {
    float xv[8];
#pragma unroll
    for (int i = 0; i < 8; i++) xv[i] = lb[(size_t)(l0 + i) * D_];
#pragma unroll
    for (int e = 0; e < 32; e++) {
      const float* pe = &pb[(size_t)e * L_ + l0];
      float4 pA = *(const float4*)&pe[0];
      float4 pB = *(const float4*)&pe[4];
      acc[e] += pA.x * xv[0] + pA.y * xv[1] + pA.z * xv[2] + pA.w * xv[3]
              + pB.x * xv[4] + pB.y * xv[5] + pB.z * xv[6] + pB.w * xv[7];
    }
  }
  float* o = np + (size_t)lc * ND_ + (size_t)(bi * E_) * D_ + d;
#pragma unroll
  for (int e = 0; e < 32; e++) o[(size_t)e * D_] = acc[e];
}

// ------------------------------------------------- partial reduce -> node0
// grid 1536 x 256: each thread sums one float4 across 4 slices.
__global__ void k_pool_red(const float* __restrict__ np, float* __restrict__ node0) {
  int i = (blockIdx.x * 256 + threadIdx.x) * 4;
  float4 a = *(const float4*)&np[i];
  float4 b = *(const float4*)&np[i + ND_];
  float4 c = *(const float4*)&np[i + 2 * ND_];
  float4 d = *(const float4*)&np[i + 3 * ND_];
  float4 s = {a.x + b.x + c.x + d.x, a.y + b.y + c.y + d.y,
              a.z + b.z + c.z + d.z, a.w + b.w + c.w + d.w};
  *(float4*)&node0[i] = s;
}

// ------------------------------------------------- fused q/k/v/skip GEMM (MFMA)
__global__ __launch_bounds__(256) void k_gemm4_m(
    const float* __restrict__ X, int K,
    const u16* __restrict__ Wt,
    const float* __restrict__ bb0, const float* __restrict__ bb1,
    const float* __restrict__ bb2, const float* __restrict__ bb3,
    float* __restrict__ O0, float* __restrict__ O1,
    float* __restrict__ O2, float* __restrict__ O3) {
  __shared__ __align__(16) u16 Ah[128 * 32], Bh[128 * 32];
  int rb = blockIdx.x & 15, cbm = blockIdx.x >> 4;
  int mat = cbm >> 3;
  int col0 = (cbm & 7) * 128, row0 = rb * 128;
  const u16* Bt = Wt + (size_t)mat * C_ * K;
  const float* bias; float* O;
  if (mat == 0)      { bias = bb0; O = O0; }
  else if (mat == 1) { bias = bb1; O = O1; }
  else if (mat == 2) { bias = bb2; O = O2; }
  else               { bias = bb3; O = O3; }

  f32x4 acc[4][4];
#pragma unroll
  for (int i = 0; i < 4; i++)
#pragma unroll
    for (int j = 0; j < 4; j++) acc[i][j] = (f32x4){0.f, 0.f, 0.f, 0.f};
  gemm_core(X, Bt, K, row0, col0, Ah, Bh, acc);

  int lane = threadIdx.x & 63, w = threadIdx.x >> 6;
  int wrow = (w & 1) * 64, wcol = (w >> 1) * 64;
#pragma unroll
  for (int j = 0; j < 4; j++) {
    int col = col0 + wcol + j * 16 + (lane & 15);
    float bv = bias[col];
#pragma unroll
    for (int i = 0; i < 4; i++) {
      int rowb = row0 + wrow + i * 16 + (lane >> 4) * 4;
#pragma unroll
      for (int r = 0; r < 4; r++)
        O[(size_t)(rowb + r) * C_ + col] = acc[i][j][r] + bv;
    }
  }
}

// -------------------------------------- edge embedding @ We, rank-3 form
__global__ void k_combo2(const float* __restrict__ Wr1, const float* __restrict__ br1,
                         const float* __restrict__ Wm1, const float* __restrict__ bm1,
                         const float* __restrict__ e1W,
                         const float* __restrict__ Wr2, const float* __restrict__ br2,
                         const float* __restrict__ Wm2, const float* __restrict__ bm2,
                         const float* __restrict__ e2W,
                         float* __restrict__ e1c, float* __restrict__ e2c) {
  int x = blockIdx.x;
  int conv = x >> 6;
  int jb = x & 3, kb = (x >> 2) & 15;
  const float *Wr, *br, *Wm, *bm, *eW; float* out;
  if (conv == 0) { Wr = Wr1; br = br1; Wm = Wm1; bm = bm1; eW = e1W; out = e1c; }
  else           { Wr = Wr2; br = br2; Wm = Wm2; bm = bm2; eW = e2W; out = e2c; }
  int tid = threadIdx.x;
  __shared__ float sw[3][64];
  int k0 = kb * 64;
  if (tid < 64) {
    sw[0][tid] = Wr[k0 + tid];
    sw[1][tid] = Wm[k0 + tid];
    sw[2][tid] = br[k0 + tid] + bm[k0 + tid];
  }
  __syncthreads();
  int j = jb * 256 + tid;
  float a0 = 0.f, a1 = 0.f, a2 = 0.f;
#pragma unroll 8
  for (int kk = 0; kk < 64; kk++) {
    float w = eW[(size_t)(k0 + kk) * C_ + j];
    a0 += sw[0][kk] * w; a1 += sw[1][kk] * w; a2 += sw[2][kk] * w;
  }
#pragma unroll
  for (int c = 0; c < 10; c++)
    atomicAdd(&out[c * C_ + j], (float)(c >> 1) * a0 + (float)(c & 1) * a1 + a2);
}

// ------------------------------------------------- CSR build
__global__ void k_count(const int* __restrict__ dst, int* __restrict__ cnt) {
  int eg = blockIdx.x * 256 + threadIdx.x;
  atomicAdd(&cnt[dst[eg]], 1);
}

__global__ void k_scan(const int* __restrict__ cnt, int* __restrict__ off) {
  __shared__ int part[256];
  int t = threadIdx.x;
  int local[8]; int s = 0;
#pragma unroll
  for (int i = 0; i < 8; i++) { local[i] = cnt[t * 8 + i]; s += local[i]; }
  part[t] = s;
  __syncthreads();
  if (t == 0) {
    int r = 0;
    for (int i = 0; i < 256; i++) { int v = part[i]; part[i] = r; r += v; }
    off[N_] = r;
  }
  __syncthreads();
  int r = part[t];
#pragma unroll
  for (int i = 0; i < 8; i++) { off[t * 8 + i] = r; r += local[i]; }
}

__global__ void k_scatter(const int* __restrict__ dst, int* __restrict__ wcnt,
                          const int* __restrict__ off, int* __restrict__ perm) {
  int eg = blockIdx.x * 256 + threadIdx.x;
  int d = dst[eg];
  int p = atomicAdd(&wcnt[d], 1);
  perm[off[d] + p] = eg;
}

// ------------------------------------------------- per-dst attention agg
__global__ void k_agg(const float* __restrict__ q, const float* __restrict__ k,
                      const float* __restrict__ v, const float* __restrict__ ec,
                      const int* __restrict__ srcA, const float* __restrict__ etype,
                      const float* __restrict__ emain, const int* __restrict__ off,
                      const int* __restrict__ perm, float* __restrict__ O) {
  int dst = blockIdx.x;
  int beg = off[dst];
  int cntE = off[dst + 1] - beg;
  if (cntE == 0) return;
  if (cntE > 128) cntE = 128;
  int tid = threadIdx.x;
  __shared__ float lg[128][8];
  __shared__ int srcs[128];
  __shared__ int cids[128];
  for (int e = tid; e < cntE; e += 256) {
    int eg = perm[beg + e];
    srcs[e] = srcA[eg];
    cids[e] = ((int)(etype[eg] + 0.5f)) * 2 + (int)(emain[eg] + 0.5f);
  }
  __syncthreads();
  int c = tid * 4;
  int h = tid >> 5;
  float4 qv = *(const float4*)&q[dst * C_ + c];
  const float scale = 0.08838834764831845f;  // 1/sqrt(128)
  for (int e = 0; e < cntE; e++) {
    int s = srcs[e], ci = cids[e];
    float4 kv = *(const float4*)&k[s * C_ + c];
    float4 ev = *(const float4*)&ec[ci * C_ + c];
    float p = qv.x * (kv.x + ev.x) + qv.y * (kv.y + ev.y) +
              qv.z * (kv.z + ev.z) + qv.w * (kv.w + ev.w);
#pragma unroll
    for (int o = 16; o; o >>= 1) p += __shfl_xor(p, o);
    if ((tid & 31) == 0) lg[e][h] = p * scale;
  }
  __syncthreads();
  if (tid < 8) {
    float m = -1e30f;
    for (int e = 0; e < cntE; e++) m = fmaxf(m, lg[e][tid]);
    float ssum = 0.f;
    for (int e = 0; e < cntE; e++) { float x = expf(lg[e][tid] - m); lg[e][tid] = x; ssum += x; }
    float inv = 1.f / ssum;
    for (int e = 0; e < cntE; e++) lg[e][tid] *= inv;
  }
  __syncthreads();
  float4 acc = {0.f, 0.f, 0.f, 0.f};
  for (int e = 0; e < cntE; e++) {
    float a = lg[e][h];
    int s = srcs[e], ci = cids[e];
    float4 vv = *(const float4*)&v[s * C_ + c];
    float4 ev = *(const float4*)&ec[ci * C_ + c];
    acc.x += a * (vv.x + ev.x); acc.y += a * (vv.y + ev.y);
    acc.z += a * (vv.z + ev.z); acc.w += a * (vv.w + ev.w);
  }
  float4 o = *(const float4*)&O[dst * C_ + c];
  o.x += acc.x; o.y += acc.y; o.z += acc.z; o.w += acc.w;
  *(float4*)&O[dst * C_ + c] = o;
}

// ------------------------------------------------- final gather + FC
__global__ void k_final(const float* __restrict__ nB, const int* __restrict__ lens,
                        const float* __restrict__ fcW, const float* __restrict__ fcb,
                        float* __restrict__ out) {
  int b = blockIdx.x;
  int idx = lens[b] - 1;
  const float* row = &nB[(b * E_ + idx) * C_];
  int tid = threadIdx.x;
  int c = tid * 4;
  float4 r = *(const float4*)&row[c];
  float4 w0 = *(const float4*)&fcW[(c + 0) * 4];
  float4 w1 = *(const float4*)&fcW[(c + 1) * 4];
  float4 w2 = *(const float4*)&fcW[(c + 2) * 4];
  float4 w3 = *(const float4*)&fcW[(c + 3) * 4];
  float p0 = r.x * w0.x + r.y * w1.x + r.z * w2.x + r.w * w3.x;
  float p1 = r.x * w0.y + r.y * w1.y + r.z * w2.y + r.w * w3.y;
  float p2 = r.x * w0.z + r.y * w1.z + r.z * w2.z + r.w * w3.z;
  float p3 = r.x * w0.w + r.y * w1.w + r.z * w2.w + r.w * w3.w;
#pragma unroll
  for (int o = 32; o; o >>= 1) {
    p0 += __shfl_xor(p0, o); p1 += __shfl_xor(p1, o);
    p2 += __shfl_xor(p2, o); p3 += __shfl_xor(p3, o);
  }
  __shared__ float red[4][4];
  if ((tid & 63) == 0) {
    int w = tid >> 6;
    red[w][0] = p0; red[w][1] = p1; red[w][2] = p2; red[w][3] = p3;
  }
  __syncthreads();
  if (tid == 0) {
#pragma unroll
    for (int j = 0; j < 4; j++)
      out[b * 4 + j] = red[0][j] + red[1][j] + red[2][j] + red[3][j] + fcb[j];
  }
}

// ================================================================ launch
extern "C" void kernel_launch(void* const* d_in, const int* in_sizes, int n_in,
                              void* d_out, int out_size, void* d_ws, size_t ws_size,
                              hipStream_t stream) {
  (void)in_sizes; (void)n_in; (void)out_size; (void)ws_size;
  const float* lh    = (const float*)d_in[0];
  const float* mask  = (const float*)d_in[1];
  const int*   lens  = (const int*)d_in[2];
  const int*   edge  = (const int*)d_in[3];
  const float* etype = (const float*)d_in[4];
  const float* emain = (const float*)d_in[5];
  const float* W1   = (const float*)d_in[6];
  const float* b1   = (const float*)d_in[7];
  const float* W2   = (const float*)d_in[8];
  const float* b2   = (const float*)d_in[9];
  const float* Wr1  = (const float*)d_in[10];
  const float* br1  = (const float*)d_in[11];
  const float* Wm1  = (const float*)d_in[12];
  const float* bm1  = (const float*)d_in[13];
  const float* Wr2  = (const float*)d_in[14];
  const float* br2  = (const float*)d_in[15];
  const float* Wm2  = (const float*)d_in[16];
  const float* bm2  = (const float*)d_in[17];
  const float* q1W  = (const float*)d_in[18];
  const float* q1b  = (const float*)d_in[19];
  const float* k1W  = (const float*)d_in[20];
  const float* k1b  = (const float*)d_in[21];
  const float* v1W  = (const float*)d_in[22];
  const float* v1b  = (const float*)d_in[23];
  const float* e1W  = (const float*)d_in[24];
  const float* s1W  = (const float*)d_in[25];
  const float* s1b  = (const float*)d_in[26];
  const float* q2W  = (const float*)d_in[27];
  const float* q2b  = (const float*)d_in[28];
  const float* k2W  = (const float*)d_in[29];
  const float* k2b  = (const float*)d_in[30];
  const float* v2W  = (const float*)d_in[31];
  const float* v2b  = (const float*)d_in[32];
  const float* e2W  = (const float*)d_in[33];
  const float* s2W  = (const float*)d_in[34];
  const float* s2b  = (const float*)d_in[35];
  const float* fcW  = (const float*)d_in[36];
  const float* fcb  = (const float*)d_in[37];

  float* ws    = (float*)d_ws;
  float* att   = ws;                       // 32768 (spare)
  float* node0 = att + 32768;              // 2048*768
  float* e1c   = node0 + ND_;              // 10*1024
  float* e2c   = e1c + 10 * 1024;
  float* qb    = e2c + 10 * 1024;          // 2048*1024 each
  float* kb    = qb + N_ * C_;
  float* vb    = kb + N_ * C_;
  float* nA    = vb + N_ * C_;
  float* nBuf  = nA + N_ * C_;
  int* cnt  = (int*)(nBuf + N_ * C_);      // 2048
  int* wcnt = cnt + N_;                    // 2048
  int* off  = wcnt + N_;                   // 2049 (pad to 2056)
  int* perm = off + (N_ + 8);              // 32768
  u16* wtb  = (u16*)(perm + EG_);          // all 9 bf16 transposed weights
  u16* w1t  = wtb;                         // 512*768
  u16* wt1  = w1t + SH_ * D_;              // 4*1024*768
  u16* wt2  = wt1 + 4 * C_ * D_;           // 4*1024*1024

  // transient aliases (consumed before conv1 gemm4 overwrites them)
  float* pr   = qb;                        // probs: 2048*512 fp32
  float* att8 = kb;                        // span partials: 8*32768
  float* np   = vb;                        // pool l-partials: 4*ND_ = vb..nBuf+end (exact)

  const int* srcA = edge;
  const int* dstA = edge + EG_;

  // CSR build (shared by both convs)
  (void)hipMemsetAsync(cnt, 0, 2 * N_ * sizeof(int), stream);
  k_count<<<EG_ / 256, 256, 0, stream>>>(dstA, cnt);
  k_scan<<<1, 256, 0, stream>>>(cnt, off);
  k_scatter<<<EG_ / 256, 256, 0, stream>>>(dstA, wcnt, off, perm);

  // weight prep: all 9 transposes in one launch
  k_wt9<<<384 + 4 * 768 + 4 * 1024, 256, 0, stream>>>(
      W1, q1W, k1W, v1W, s1W, q2W, k2W, v2W, s2W, wtb);

  // span attention partials -> att8
  k_span_m<<<1024, 256, 0, stream>>>(lh, w1t, b1, W2, att8);

  // 10-combo edge embeddings (rank-3 decomposition)
  (void)hipMemsetAsync(e1c, 0, 20 * C_ * sizeof(float), stream);
  k_combo2<<<128, 256, 0, stream>>>(Wr1, br1, Wm1, bm1, e1W,
                                    Wr2, br2, Wm2, bm2, e2W, e1c, e2c);

  // pooling: probs -> l-split partials -> reduce
  k_probs<<<256, 256, 0, stream>>>(att8, b2, mask, pr);
  k_pool_acc2<<<768, 256, 0, stream>>>(lh, pr, np);
  k_pool_red<<<ND_ / 1024, 256, 0, stream>>>(np, node0);

  // conv1
  k_gemm4_m<<<512, 256, 0, stream>>>(node0, D_, wt1,
                                     q1b, k1b, v1b, s1b, qb, kb, vb, nA);
  k_agg<<<N_, 256, 0, stream>>>(qb, kb, vb, e1c, srcA, etype, emain, off, perm, nA);

  // conv2
  k_gemm4_m<<<512, 256, 0, stream>>>(nA, C_, wt2,
                                     q2b, k2b, v2b, s2b, qb, kb, vb, nBuf);
  k_agg<<<N_, 256, 0, stream>>>(qb, kb, vb, e2c, srcA, etype, emain, off, perm, nBuf);

  // final
  k_final<<<B_, 256, 0, stream>>>(nBuf, lens, fcW, fcb, (float*)d_out);
}

// Round 9
// 323.498 us; speedup vs baseline: 3.5080x; 1.2076x over previous
//
#include <hip/hip_runtime.h>
#include <math.h>
#include <stdint.h>

#define B_  64
#define E_  32
#define L_  512
#define D_  768
#define C_  1024
#define H_  8
#define EG_ 32768
#define SH_ 512
#define N_  2048   // B*E
#define ND_ (N_ * D_)

typedef __bf16 bf16x8 __attribute__((ext_vector_type(8)));
typedef float f32x4 __attribute__((ext_vector_type(4)));
typedef unsigned short u16;
typedef u16 u16x4 __attribute__((ext_vector_type(4)));

// ---------------------------------------------------------------- helpers

__device__ __forceinline__ u16 bf16_rn(float x) {
  unsigned u = __builtin_bit_cast(unsigned, x);
  unsigned r = u + 0x7FFFu + ((u >> 16) & 1u);
  return (u16)(r >> 16);
}

__device__ __forceinline__ void gload16(const void* g, void* l) {
  __builtin_amdgcn_global_load_lds(
      (const __attribute__((address_space(1))) void*)(unsigned long long)(uintptr_t)g,
      (__attribute__((address_space(3))) void*)(unsigned int)(uintptr_t)l,
      16, 0, 0);
}

// ------------------------------------------------- merged weight prep (9 mats)
__global__ void k_wt9(const float* __restrict__ s0, const float* __restrict__ s1,
                      const float* __restrict__ s2, const float* __restrict__ s3,
                      const float* __restrict__ s4, const float* __restrict__ s5,
                      const float* __restrict__ s6, const float* __restrict__ s7,
                      const float* __restrict__ s8, u16* __restrict__ dstBase) {
  int x = blockIdx.x;
  const float* W; u16* TH; int K, Nc;
  if (x < 384) {                       // W1: 768x512
    W = s0; TH = dstBase; K = D_; Nc = SH_;
  } else if (x < 384 + 4 * 768) {      // conv1 q/k/v/s: 768x1024
    int i = (x - 384) / 768; x = (x - 384) % 768;
    W = (i == 0) ? s1 : (i == 1) ? s2 : (i == 2) ? s3 : s4;
    TH = dstBase + SH_ * D_ + (size_t)i * C_ * D_; K = D_; Nc = C_;
  } else {                             // conv2 q/k/v/s: 1024x1024
    int i = (x - 3456) / 1024; x = (x - 3456) % 1024;
    W = (i == 0) ? s5 : (i == 1) ? s6 : (i == 2) ? s7 : s8;
    TH = dstBase + SH_ * D_ + 4 * (size_t)C_ * D_ + (size_t)i * C_ * C_; K = C_; Nc = C_;
  }
  __shared__ float Ts[32][33];
  int nbk = K >> 5;
  int bk = x % nbk, bn = x / nbk;
  int tid = threadIdx.x;
  int tx = tid & 31, ty = tid >> 5;
  for (int r = ty; r < 32; r += 8)
    Ts[r][tx] = W[(size_t)(bk * 32 + r) * Nc + bn * 32 + tx];
  __syncthreads();
  for (int r = ty; r < 32; r += 8) {
    float v = Ts[tx][r];
    TH[(size_t)(bn * 32 + r) * K + bk * 32 + tx] = bf16_rn(v);
  }
}

// ------------------------------------------------- MFMA GEMM core (plain bf16)
__device__ __forceinline__ void gemm_core(
    const float* __restrict__ X, const u16* __restrict__ Bt,
    int K, int row0, int col0,
    u16* Ah, u16* Bh, f32x4 acc[4][4])
{
  int tid = threadIdx.x;
  int lane = tid & 63, w = tid >> 6;

  int aoff[4], boff[4];
#pragma unroll
  for (int i = 0; i < 4; i++) {
    int kc = lane >> 4;
    int rT = (w & 1) * 64 + i * 16 + (lane & 15);
    aoff[i] = rT * 64 + (((kc ^ ((rT >> 1) & 3)) & 3) << 4);
    int cT = (w >> 1) * 64 + i * 16 + (lane & 15);
    boff[i] = cT * 64 + (((kc ^ ((cT >> 1) & 3)) & 3) << 4);
  }

  int nkt = K >> 5;
  for (int kt = 0; kt < nkt; kt++) {
    int k0 = kt << 5;
    if (kt) __syncthreads();
#pragma unroll
    for (int p = 0; p < 4; p++) {
      int idx = tid + p * 256;
      int r = idx >> 3, c4 = idx & 7;
      float4 v = *(const float4*)&X[(size_t)(row0 + r) * K + k0 + c4 * 4];
      u16x4 hi = {bf16_rn(v.x), bf16_rn(v.y), bf16_rn(v.z), bf16_rn(v.w)};
      int off = r * 64 + ((((c4 >> 1) ^ ((r >> 1) & 3)) & 3) << 4) + (c4 & 1) * 8;
      *(u16x4*)((char*)Ah + off) = hi;
    }
#pragma unroll
    for (int q = 0; q < 2; q++) {
      int rT = w * 32 + q * 16 + (lane >> 2);
      int kc = lane & 3;
      size_t gb = (size_t)(col0 + rT) * K + k0 + (((kc ^ ((rT >> 1) & 3)) & 3) << 3);
      int lb = (w * 32 + q * 16) * 32;
      gload16(&Bt[gb], &Bh[lb]);
    }
    __syncthreads();
    bf16x8 ah[4];
#pragma unroll
    for (int i = 0; i < 4; i++)
      ah[i] = *(const bf16x8*)((const char*)Ah + aoff[i]);
#pragma unroll
    for (int j = 0; j < 4; j++) {
      bf16x8 bh = *(const bf16x8*)((const char*)Bh + boff[j]);
#pragma unroll
      for (int i = 0; i < 4; i++)
        acc[i][j] = __builtin_amdgcn_mfma_f32_16x16x32_bf16(ah[i], bh, acc[i][j], 0, 0, 0);
    }
  }
}

// ------------------------------------------------- span MLP (MFMA) -> partials
__global__ __launch_bounds__(256) void k_span_m(
    const float* __restrict__ lh, const u16* __restrict__ W1t,
    const float* __restrict__ b1, const float* __restrict__ W2,
    float* __restrict__ att8) {
  __shared__ __align__(16) u16 Ah[128 * 32], Bh[128 * 32];
  int rb = blockIdx.x & 255, cb = blockIdx.x >> 8;
  int row0 = rb * 128, col0 = cb * 128;
  f32x4 acc[4][4];
#pragma unroll
  for (int i = 0; i < 4; i++)
#pragma unroll
    for (int j = 0; j < 4; j++) acc[i][j] = (f32x4){0.f, 0.f, 0.f, 0.f};
  gemm_core(lh, W1t, D_, row0, col0, Ah, Bh, acc);

  int lane = threadIdx.x & 63, w = threadIdx.x >> 6;
  int wrow = (w & 1) * 64, wcol = (w >> 1) * 64;
  float b1v[4], w2v[4];
#pragma unroll
  for (int j = 0; j < 4; j++) {
    int col = col0 + wcol + j * 16 + (lane & 15);
    b1v[j] = b1[col]; w2v[j] = W2[col];
  }
  float* dst = att8 + (size_t)(cb * 2 + (w >> 1)) * 32768;
#pragma unroll
  for (int i = 0; i < 4; i++) {
#pragma unroll
    for (int r = 0; r < 4; r++) {
      float s = 0.f;
#pragma unroll
      for (int j = 0; j < 4; j++) {
        float h = acc[i][j][r] + b1v[j];
        s += fmaxf(h, 0.f) * w2v[j];
      }
      s += __shfl_xor(s, 1); s += __shfl_xor(s, 2);
      s += __shfl_xor(s, 4); s += __shfl_xor(s, 8);
      if ((lane & 15) == 0)
        dst[row0 + wrow + i * 16 + (lane >> 4) * 4 + r] = s;
    }
  }
}

// ------------------------------------------------- probs: masked softmax
__global__ void k_probs(const float* __restrict__ att8, const float* __restrict__ b2,
                        const float* __restrict__ mask, float* __restrict__ pr) {
  int bi = blockIdx.x >> 2, eg = blockIdx.x & 3;
  int tid = threadIdx.x, lane = tid & 63, w = tid >> 6;
  __shared__ float att_s[512];
  float b2v = b2[0];
  int r0 = bi * 512 + tid;
  float s0 = b2v, s1 = b2v;
#pragma unroll
  for (int p = 0; p < 8; p++) {
    s0 += att8[(size_t)p * 32768 + r0];
    s1 += att8[(size_t)p * 32768 + r0 + 256];
  }
  att_s[tid] = s0;
  att_s[tid + 256] = s1;
  __syncthreads();
#pragma unroll
  for (int it = 0; it < 2; it++) {
    int e = eg * 8 + it * 4 + w;
    const float* mrow = &mask[(size_t)(bi * E_ + e) * L_];
    float4 m0 = *(const float4*)&mrow[lane * 8];
    float4 m1 = *(const float4*)&mrow[lane * 8 + 4];
    float4 a0 = *(const float4*)&att_s[lane * 8];
    float4 a1 = *(const float4*)&att_s[lane * 8 + 4];
    float v[8];
    v[0] = a0.x - 1e5f * (1.f - m0.x); v[1] = a0.y - 1e5f * (1.f - m0.y);
    v[2] = a0.z - 1e5f * (1.f - m0.z); v[3] = a0.w - 1e5f * (1.f - m0.w);
    v[4] = a1.x - 1e5f * (1.f - m1.x); v[5] = a1.y - 1e5f * (1.f - m1.y);
    v[6] = a1.z - 1e5f * (1.f - m1.z); v[7] = a1.w - 1e5f * (1.f - m1.w);
    float mx = v[0];
#pragma unroll
    for (int i = 1; i < 8; i++) mx = fmaxf(mx, v[i]);
#pragma unroll
    for (int o = 32; o; o >>= 1) mx = fmaxf(mx, __shfl_xor(mx, o));
    float s = 0.f;
#pragma unroll
    for (int i = 0; i < 8; i++) { v[i] = expf(v[i] - mx); s += v[i]; }
#pragma unroll
    for (int o = 32; o; o >>= 1) s += __shfl_xor(s, o);
    float inv = 1.f / s;
    float4 o0 = {v[0] * inv, v[1] * inv, v[2] * inv, v[3] * inv};
    float4 o1 = {v[4] * inv, v[5] * inv, v[6] * inv, v[7] * inv};
    float* prow = &pr[(size_t)(bi * E_ + e) * L_];
    *(float4*)&prow[lane * 8] = o0;
    *(float4*)&prow[lane * 8 + 4] = o1;
  }
}

// ------------------------------------------------- pool via MFMA
// grid 384 = bi(64) x dc(6). Block: node0[bi][0..32e][dc*128..+128] =
// P[32x512] @ lh[512x768][:,colblk]. K-loop 16 x 32.
__global__ __launch_bounds__(256) void k_pool_m(const float* __restrict__ lh,
    const float* __restrict__ pr, float* __restrict__ node0) {
  __shared__ __align__(16) u16 As[32 * 32];    // [e][k], XOR-swizzled (2 KB)
  __shared__ __align__(16) u16 Bs[32 * 128];   // [k][col], linear (8 KB)
  int bi = blockIdx.x / 6, dc = blockIdx.x % 6;
  int col0 = dc * 128;
  int tid = threadIdx.x, lane = tid & 63, w = tid >> 6;
  const float* lhb = lh + (size_t)bi * L_ * D_;
  const float* prb = pr + (size_t)bi * E_ * L_;

  f32x4 acc[2][2];
#pragma unroll
  for (int m = 0; m < 2; m++)
#pragma unroll
    for (int c = 0; c < 2; c++) acc[m][c] = (f32x4){0.f, 0.f, 0.f, 0.f};

  int aoff[2];
#pragma unroll
  for (int m = 0; m < 2; m++) {
    int kc = lane >> 4;
    int e = m * 16 + (lane & 15);
    aoff[m] = e * 64 + (((kc ^ ((e >> 1) & 3)) & 3) << 4);
  }
  int se = tid >> 3, sk4 = tid & 7;  // A staging: e 0..31, chunk 0..7
  int saoff = se * 64 + ((((sk4 >> 1) ^ ((se >> 1) & 3)) & 3) << 4) + (sk4 & 1) * 8;

  for (int kt = 0; kt < 16; kt++) {
    int l0 = kt << 5;
    if (kt) __syncthreads();
    // stage A (probs -> bf16, swizzled)
    {
      float4 v = *(const float4*)&prb[(size_t)se * L_ + l0 + sk4 * 4];
      u16x4 hv = {bf16_rn(v.x), bf16_rn(v.y), bf16_rn(v.z), bf16_rn(v.w)};
      *(u16x4*)((char*)As + saoff) = hv;
    }
    // stage B (lh -> bf16, [k][col] linear)
#pragma unroll
    for (int p = 0; p < 4; p++) {
      int idx = tid + p * 256;
      int k = idx >> 5, c4 = idx & 31;
      float4 v = *(const float4*)&lhb[(size_t)(l0 + k) * D_ + col0 + c4 * 4];
      u16x4 hv = {bf16_rn(v.x), bf16_rn(v.y), bf16_rn(v.z), bf16_rn(v.w)};
      *(u16x4*)&Bs[k * 128 + c4 * 4] = hv;
    }
    __syncthreads();
    bf16x8 af[2];
#pragma unroll
    for (int m = 0; m < 2; m++)
      af[m] = *(const bf16x8*)((const char*)As + aoff[m]);
#pragma unroll
    for (int c = 0; c < 2; c++) {
      int colT = w * 32 + c * 16 + (lane & 15);
      int kg = (lane >> 4) * 8;
      union { bf16x8 v; u16 u[8]; } bb;
#pragma unroll
      for (int j = 0; j < 8; j++) bb.u[j] = Bs[(kg + j) * 128 + colT];
#pragma unroll
      for (int m = 0; m < 2; m++)
        acc[m][c] = __builtin_amdgcn_mfma_f32_16x16x32_bf16(af[m], bb.v, acc[m][c], 0, 0, 0);
    }
  }
  // epilogue: C[e][col] -> node0
#pragma unroll
  for (int m = 0; m < 2; m++)
#pragma unroll
    for (int c = 0; c < 2; c++) {
      int col = col0 + w * 32 + c * 16 + (lane & 15);
#pragma unroll
      for (int r = 0; r < 4; r++) {
        int e = m * 16 + (lane >> 4) * 4 + r;
        node0[(size_t)(bi * E_ + e) * D_ + col] = acc[m][c][r];
      }
    }
}

// ------------------------------------------------- fused q/k/v/skip GEMM (MFMA)
__global__ __launch_bounds__(256) void k_gemm4_m(
    const float* __restrict__ X, int K,
    const u16* __restrict__ Wt,
    const float* __restrict__ bb0, const float* __restrict__ bb1,
    const float* __restrict__ bb2, const float* __restrict__ bb3,
    float* __restrict__ O0, float* __restrict__ O1,
    float* __restrict__ O2, float* __restrict__ O3) {
  __shared__ __align__(16) u16 Ah[128 * 32], Bh[128 * 32];
  int rb = blockIdx.x & 15, cbm = blockIdx.x >> 4;
  int mat = cbm >> 3;
  int col0 = (cbm & 7) * 128, row0 = rb * 128;
  const u16* Bt = Wt + (size_t)mat * C_ * K;
  const float* bias; float* O;
  if (mat == 0)      { bias = bb0; O = O0; }
  else if (mat == 1) { bias = bb1; O = O1; }
  else if (mat == 2) { bias = bb2; O = O2; }
  else               { bias = bb3; O = O3; }

  f32x4 acc[4][4];
#pragma unroll
  for (int i = 0; i < 4; i++)
#pragma unroll
    for (int j = 0; j < 4; j++) acc[i][j] = (f32x4){0.f, 0.f, 0.f, 0.f};
  gemm_core(X, Bt, K, row0, col0, Ah, Bh, acc);

  int lane = threadIdx.x & 63, w = threadIdx.x >> 6;
  int wrow = (w & 1) * 64, wcol = (w >> 1) * 64;
#pragma unroll
  for (int j = 0; j < 4; j++) {
    int col = col0 + wcol + j * 16 + (lane & 15);
    float bv = bias[col];
#pragma unroll
    for (int i = 0; i < 4; i++) {
      int rowb = row0 + wrow + i * 16 + (lane >> 4) * 4;
#pragma unroll
      for (int r = 0; r < 4; r++)
        O[(size_t)(rowb + r) * C_ + col] = acc[i][j][r] + bv;
    }
  }
}

// -------------------------------------- edge embedding @ We, rank-3 form
__global__ void k_combo2(const float* __restrict__ Wr1, const float* __restrict__ br1,
                         const float* __restrict__ Wm1, const float* __restrict__ bm1,
                         const float* __restrict__ e1W,
                         const float* __restrict__ Wr2, const float* __restrict__ br2,
                         const float* __restrict__ Wm2, const float* __restrict__ bm2,
                         const float* __restrict__ e2W,
                         float* __restrict__ e1c, float* __restrict__ e2c) {
  int x = blockIdx.x;
  int conv = x >> 6;
  int jb = x & 3, kb = (x >> 2) & 15;
  const float *Wr, *br, *Wm, *bm, *eW; float* out;
  if (conv == 0) { Wr = Wr1; br = br1; Wm = Wm1; bm = bm1; eW = e1W; out = e1c; }
  else           { Wr = Wr2; br = br2; Wm = Wm2; bm = bm2; eW = e2W; out = e2c; }
  int tid = threadIdx.x;
  __shared__ float sw[3][64];
  int k0 = kb * 64;
  if (tid < 64) {
    sw[0][tid] = Wr[k0 + tid];
    sw[1][tid] = Wm[k0 + tid];
    sw[2][tid] = br[k0 + tid] + bm[k0 + tid];
  }
  __syncthreads();
  int j = jb * 256 + tid;
  float a0 = 0.f, a1 = 0.f, a2 = 0.f;
#pragma unroll 8
  for (int kk = 0; kk < 64; kk++) {
    float w = eW[(size_t)(k0 + kk) * C_ + j];
    a0 += sw[0][kk] * w; a1 += sw[1][kk] * w; a2 += sw[2][kk] * w;
  }
#pragma unroll
  for (int c = 0; c < 10; c++)
    atomicAdd(&out[c * C_ + j], (float)(c >> 1) * a0 + (float)(c & 1) * a1 + a2);
}

// ------------------------------------------------- CSR build
__global__ void k_count(const int* __restrict__ dst, int* __restrict__ cnt) {
  int eg = blockIdx.x * 256 + threadIdx.x;
  atomicAdd(&cnt[dst[eg]], 1);
}

__global__ void k_scan(const int* __restrict__ cnt, int* __restrict__ off) {
  __shared__ int part[256];
  int t = threadIdx.x;
  int local[8]; int s = 0;
#pragma unroll
  for (int i = 0; i < 8; i++) { local[i] = cnt[t * 8 + i]; s += local[i]; }
  part[t] = s;
  __syncthreads();
  if (t == 0) {
    int r = 0;
    for (int i = 0; i < 256; i++) { int v = part[i]; part[i] = r; r += v; }
    off[N_] = r;
  }
  __syncthreads();
  int r = part[t];
#pragma unroll
  for (int i = 0; i < 8; i++) { off[t * 8 + i] = r; r += local[i]; }
}

__global__ void k_scatter(const int* __restrict__ dst, int* __restrict__ wcnt,
                          const int* __restrict__ off, int* __restrict__ perm) {
  int eg = blockIdx.x * 256 + threadIdx.x;
  int d = dst[eg];
  int p = atomicAdd(&wcnt[d], 1);
  perm[off[d] + p] = eg;
}

// ------------------------------------------------- per-dst attention agg
__global__ void k_agg(const float* __restrict__ q, const float* __restrict__ k,
                      const float* __restrict__ v, const float* __restrict__ ec,
                      const int* __restrict__ srcA, const float* __restrict__ etype,
                      const float* __restrict__ emain, const int* __restrict__ off,
                      const int* __restrict__ perm, float* __restrict__ O) {
  int dst = blockIdx.x;
  int beg = off[dst];
  int cntE = off[dst + 1] - beg;
  if (cntE == 0) return;
  if (cntE > 128) cntE = 128;
  int tid = threadIdx.x;
  __shared__ float lg[128][8];
  __shared__ int srcs[128];
  __shared__ int cids[128];
  for (int e = tid; e < cntE; e += 256) {
    int eg = perm[beg + e];
    srcs[e] = srcA[eg];
    cids[e] = ((int)(etype[eg] + 0.5f)) * 2 + (int)(emain[eg] + 0.5f);
  }
  __syncthreads();
  int c = tid * 4;
  int h = tid >> 5;
  float4 qv = *(const float4*)&q[dst * C_ + c];
  const float scale = 0.08838834764831845f;  // 1/sqrt(128)
  for (int e = 0; e < cntE; e++) {
    int s = srcs[e], ci = cids[e];
    float4 kv = *(const float4*)&k[s * C_ + c];
    float4 ev = *(const float4*)&ec[ci * C_ + c];
    float p = qv.x * (kv.x + ev.x) + qv.y * (kv.y + ev.y) +
              qv.z * (kv.z + ev.z) + qv.w * (kv.w + ev.w);
#pragma unroll
    for (int o = 16; o; o >>= 1) p += __shfl_xor(p, o);
    if ((tid & 31) == 0) lg[e][h] = p * scale;
  }
  __syncthreads();
  if (tid < 8) {
    float m = -1e30f;
    for (int e = 0; e < cntE; e++) m = fmaxf(m, lg[e][tid]);
    float ssum = 0.f;
    for (int e = 0; e < cntE; e++) { float x = expf(lg[e][tid] - m); lg[e][tid] = x; ssum += x; }
    float inv = 1.f / ssum;
    for (int e = 0; e < cntE; e++) lg[e][tid] *= inv;
  }
  __syncthreads();
  float4 acc = {0.f, 0.f, 0.f, 0.f};
  for (int e = 0; e < cntE; e++) {
    float a = lg[e][h];
    int s = srcs[e], ci = cids[e];
    float4 vv = *(const float4*)&v[s * C_ + c];
    float4 ev = *(const float4*)&ec[ci * C_ + c];
    acc.x += a * (vv.x + ev.x); acc.y += a * (vv.y + ev.y);
    acc.z += a * (vv.z + ev.z); acc.w += a * (vv.w + ev.w);
  }
  float4 o = *(const float4*)&O[dst * C_ + c];
  o.x += acc.x; o.y += acc.y; o.z += acc.z; o.w += acc.w;
  *(float4*)&O[dst * C_ + c] = o;
}

// ------------------------------------------------- final gather + FC
__global__ void k_final(const float* __restrict__ nB, const int* __restrict__ lens,
                        const float* __restrict__ fcW, const float* __restrict__ fcb,
                        float* __restrict__ out) {
  int b = blockIdx.x;
  int idx = lens[b] - 1;
  const float* row = &nB[(b * E_ + idx) * C_];
  int tid = threadIdx.x;
  int c = tid * 4;
  float4 r = *(const float4*)&row[c];
  float4 w0 = *(const float4*)&fcW[(c + 0) * 4];
  float4 w1 = *(const float4*)&fcW[(c + 1) * 4];
  float4 w2 = *(const float4*)&fcW[(c + 2) * 4];
  float4 w3 = *(const float4*)&fcW[(c + 3) * 4];
  float p0 = r.x * w0.x + r.y * w1.x + r.z * w2.x + r.w * w3.x;
  float p1 = r.x * w0.y + r.y * w1.y + r.z * w2.y + r.w * w3.y;
  float p2 = r.x * w0.z + r.y * w1.z + r.z * w2.z + r.w * w3.z;
  float p3 = r.x * w0.w + r.y * w1.w + r.z * w2.w + r.w * w3.w;
#pragma unroll
  for (int o = 32; o; o >>= 1) {
    p0 += __shfl_xor(p0, o); p1 += __shfl_xor(p1, o);
    p2 += __shfl_xor(p2, o); p3 += __shfl_xor(p3, o);
  }
  __shared__ float red[4][4];
  if ((tid & 63) == 0) {
    int w = tid >> 6;
    red[w][0] = p0; red[w][1] = p1; red[w][2] = p2; red[w][3] = p3;
  }
  __syncthreads();
  if (tid == 0) {
#pragma unroll
    for (int j = 0; j < 4; j++)
      out[b * 4 + j] = red[0][j] + red[1][j] + red[2][j] + red[3][j] + fcb[j];
  }
}

// ================================================================ launch
extern "C" void kernel_launch(void* const* d_in, const int* in_sizes, int n_in,
                              void* d_out, int out_size, void* d_ws, size_t ws_size,
                              hipStream_t stream) {
  (void)in_sizes; (void)n_in; (void)out_size; (void)ws_size;
  const float* lh    = (const float*)d_in[0];
  const float* mask  = (const float*)d_in[1];
  const int*   lens  = (const int*)d_in[2];
  const int*   edge  = (const int*)d_in[3];
  const float* etype = (const float*)d_in[4];
  const float* emain = (const float*)d_in[5];
  const float* W1   = (const float*)d_in[6];
  const float* b1   = (const float*)d_in[7];
  const float* W2   = (const float*)d_in[8];
  const float* b2   = (const float*)d_in[9];
  const float* Wr1  = (const float*)d_in[10];
  const float* br1  = (const float*)d_in[11];
  const float* Wm1  = (const float*)d_in[12];
  const float* bm1  = (const float*)d_in[13];
  const float* Wr2  = (const float*)d_in[14];
  const float* br2  = (const float*)d_in[15];
  const float* Wm2  = (const float*)d_in[16];
  const float* bm2  = (const float*)d_in[17];
  const float* q1W  = (const float*)d_in[18];
  const float* q1b  = (const float*)d_in[19];
  const float* k1W  = (const float*)d_in[20];
  const float* k1b  = (const float*)d_in[21];
  const float* v1W  = (const float*)d_in[22];
  const float* v1b  = (const float*)d_in[23];
  const float* e1W  = (const float*)d_in[24];
  const float* s1W  = (const float*)d_in[25];
  const float* s1b  = (const float*)d_in[26];
  const float* q2W  = (const float*)d_in[27];
  const float* q2b  = (const float*)d_in[28];
  const float* k2W  = (const float*)d_in[29];
  const float* k2b  = (const float*)d_in[30];
  const float* v2W  = (const float*)d_in[31];
  const float* v2b  = (const float*)d_in[32];
  const float* e2W  = (const float*)d_in[33];
  const float* s2W  = (const float*)d_in[34];
  const float* s2b  = (const float*)d_in[35];
  const float* fcW  = (const float*)d_in[36];
  const float* fcb  = (const float*)d_in[37];

  float* ws    = (float*)d_ws;
  float* att   = ws;                       // 32768 (spare)
  float* node0 = att + 32768;              // 2048*768
  float* e1c   = node0 + ND_;              // 10*1024
  float* e2c   = e1c + 10 * 1024;
  float* qb    = e2c + 10 * 1024;          // 2048*1024 each
  float* kb    = qb + N_ * C_;
  float* vb    = kb + N_ * C_;
  float* nA    = vb + N_ * C_;
  float* nBuf  = nA + N_ * C_;
  int* cnt  = (int*)(nBuf + N_ * C_);      // 2048
  int* wcnt = cnt + N_;                    // 2048
  int* off  = wcnt + N_;                   // 2049 (pad to 2056)
  int* perm = off + (N_ + 8);              // 32768
  u16* wtb  = (u16*)(perm + EG_);          // all 9 bf16 transposed weights
  u16* w1t  = wtb;                         // 512*768
  u16* wt1  = w1t + SH_ * D_;              // 4*1024*768
  u16* wt2  = wt1 + 4 * C_ * D_;           // 4*1024*1024

  // transient aliases (consumed before conv1 gemm4 overwrites them)
  float* pr   = qb;                        // probs: 2048*512 fp32
  float* att8 = kb;                        // span partials: 8*32768

  const int* srcA = edge;
  const int* dstA = edge + EG_;

  // CSR build (shared by both convs)
  (void)hipMemsetAsync(cnt, 0, 2 * N_ * sizeof(int), stream);
  k_count<<<EG_ / 256, 256, 0, stream>>>(dstA, cnt);
  k_scan<<<1, 256, 0, stream>>>(cnt, off);
  k_scatter<<<EG_ / 256, 256, 0, stream>>>(dstA, wcnt, off, perm);

  // weight prep: all 9 transposes in one launch
  k_wt9<<<384 + 4 * 768 + 4 * 1024, 256, 0, stream>>>(
      W1, q1W, k1W, v1W, s1W, q2W, k2W, v2W, s2W, wtb);

  // span attention partials -> att8
  k_span_m<<<1024, 256, 0, stream>>>(lh, w1t, b1, W2, att8);

  // 10-combo edge embeddings (rank-3 decomposition)
  (void)hipMemsetAsync(e1c, 0, 20 * C_ * sizeof(float), stream);
  k_combo2<<<128, 256, 0, stream>>>(Wr1, br1, Wm1, bm1, e1W,
                                    Wr2, br2, Wm2, bm2, e2W, e1c, e2c);

  // pooling: probs -> MFMA pool
  k_probs<<<256, 256, 0, stream>>>(att8, b2, mask, pr);
  k_pool_m<<<384, 256, 0, stream>>>(lh, pr, node0);

  // conv1
  k_gemm4_m<<<512, 256, 0, stream>>>(node0, D_, wt1,
                                     q1b, k1b, v1b, s1b, qb, kb, vb, nA);
  k_agg<<<N_, 256, 0, stream>>>(qb, kb, vb, e1c, srcA, etype, emain, off, perm, nA);

  // conv2
  k_gemm4_m<<<512, 256, 0, stream>>>(nA, C_, wt2,
                                     q2b, k2b, v2b, s2b, qb, kb, vb, nBuf);
  k_agg<<<N_, 256, 0, stream>>>(qb, kb, vb, e2c, srcA, etype, emain, off, perm, nBuf);

  // final
  k_final<<<B_, 256, 0, stream>>>(nBuf, lens, fcW, fcb, (float*)d_out);
}

// Round 10
// 256.494 us; speedup vs baseline: 4.4244x; 1.2612x over previous
//
#include <hip/hip_runtime.h>
#include <math.h>
#include <stdint.h>

#define B_  64
#define E_  32
#define L_  512
#define D_  768
#define C_  1024
#define H_  8
#define EG_ 32768
#define SH_ 512
#define N_  2048   // B*E
#define ND_ (N_ * D_)

typedef __bf16 bf16x8 __attribute__((ext_vector_type(8)));
typedef float f32x4 __attribute__((ext_vector_type(4)));
typedef unsigned short u16;
typedef u16 u16x4 __attribute__((ext_vector_type(4)));

// ---------------------------------------------------------------- helpers

__device__ __forceinline__ u16 bf16_rn(float x) {
  unsigned u = __builtin_bit_cast(unsigned, x);
  unsigned r = u + 0x7FFFu + ((u >> 16) & 1u);
  return (u16)(r >> 16);
}

__device__ __forceinline__ void gload16(const void* g, void* l) {
  __builtin_amdgcn_global_load_lds(
      (const __attribute__((address_space(1))) void*)(unsigned long long)(uintptr_t)g,
      (__attribute__((address_space(3))) void*)(unsigned int)(uintptr_t)l,
      16, 0, 0);
}

// ------------------------------------------------- merged weight prep (9 mats)
__global__ void k_wt9(const float* __restrict__ s0, const float* __restrict__ s1,
                      const float* __restrict__ s2, const float* __restrict__ s3,
                      const float* __restrict__ s4, const float* __restrict__ s5,
                      const float* __restrict__ s6, const float* __restrict__ s7,
                      const float* __restrict__ s8, u16* __restrict__ dstBase) {
  int x = blockIdx.x;
  const float* W; u16* TH; int K, Nc;
  if (x < 384) {                       // W1: 768x512
    W = s0; TH = dstBase; K = D_; Nc = SH_;
  } else if (x < 384 + 4 * 768) {      // conv1 q/k/v/s: 768x1024
    int i = (x - 384) / 768; x = (x - 384) % 768;
    W = (i == 0) ? s1 : (i == 1) ? s2 : (i == 2) ? s3 : s4;
    TH = dstBase + SH_ * D_ + (size_t)i * C_ * D_; K = D_; Nc = C_;
  } else {                             // conv2 q/k/v/s: 1024x1024
    int i = (x - 3456) / 1024; x = (x - 3456) % 1024;
    W = (i == 0) ? s5 : (i == 1) ? s6 : (i == 2) ? s7 : s8;
    TH = dstBase + SH_ * D_ + 4 * (size_t)C_ * D_ + (size_t)i * C_ * C_; K = C_; Nc = C_;
  }
  __shared__ float Ts[32][33];
  int nbk = K >> 5;
  int bk = x % nbk, bn = x / nbk;
  int tid = threadIdx.x;
  int tx = tid & 31, ty = tid >> 5;
  for (int r = ty; r < 32; r += 8)
    Ts[r][tx] = W[(size_t)(bk * 32 + r) * Nc + bn * 32 + tx];
  __syncthreads();
  for (int r = ty; r < 32; r += 8) {
    float v = Ts[tx][r];
    TH[(size_t)(bn * 32 + r) * K + bk * 32 + tx] = bf16_rn(v);
  }
}

// ------------------------------------------------- MFMA GEMM core, BK=64
// C[128x128] = X(fp32->bf16)[row0..+128][0..K) @ Bt(bf16)[col0..+128][0..K)^T
// LDS row = 64 bf16 = 8 chunks of 16B; chunk c of row r stored at pos c^(r&7).
__device__ __forceinline__ void gemm_core(
    const float* __restrict__ X, const u16* __restrict__ Bt,
    int K, int row0, int col0,
    u16* Ah, u16* Bh, f32x4 acc[4][4])
{
  int tid = threadIdx.x;
  int lane = tid & 63, w = tid >> 6;

  int aoff[4], boff[4];
#pragma unroll
  for (int i = 0; i < 4; i++) {
    int kc = lane >> 4;
    int rT = (w & 1) * 64 + i * 16 + (lane & 15);
    aoff[i] = rT * 128 + (((kc ^ (rT & 7)) & 7) << 4);
    int cT = (w >> 1) * 64 + i * 16 + (lane & 15);
    boff[i] = cT * 128 + (((kc ^ (cT & 7)) & 7) << 4);
  }

  int nkt = K >> 6;
  for (int kt = 0; kt < nkt; kt++) {
    int k0 = kt << 6;
    if (kt) __syncthreads();
    // ---- stage A: fp32 -> bf16, swizzled ds_write (8 float4 / thread)
#pragma unroll
    for (int p = 0; p < 8; p++) {
      int idx = tid + p * 256;           // 0..2047
      int r = idx >> 4, c4 = idx & 15;   // row 0..127, 4-float chunk 0..15
      float4 v = *(const float4*)&X[(size_t)(row0 + r) * K + k0 + c4 * 4];
      u16x4 hv = {bf16_rn(v.x), bf16_rn(v.y), bf16_rn(v.z), bf16_rn(v.w)};
      int off = r * 128 + ((((c4 >> 1) ^ (r & 7)) & 7) << 4) + (c4 & 1) * 8;
      *(u16x4*)((char*)Ah + off) = hv;
    }
    // ---- stage B: global_load_lds (linear dest, inverse-swizzled source)
#pragma unroll
    for (int q = 0; q < 4; q++) {
      int rT = w * 32 + q * 8 + (lane >> 3);
      int cs = (lane & 7) ^ (rT & 7);
      size_t gb = (size_t)(col0 + rT) * K + k0 + cs * 8;
      int lb = (w * 32 + q * 8) * 64;    // u16 units, wave-uniform
      gload16(&Bt[gb], &Bh[lb]);
    }
    __syncthreads();
    // ---- fragments + MFMA (32 per step)
    bf16x8 ah0[4], ah1[4];
#pragma unroll
    for (int i = 0; i < 4; i++) {
      ah0[i] = *(const bf16x8*)((const char*)Ah + aoff[i]);
      ah1[i] = *(const bf16x8*)((const char*)Ah + (aoff[i] ^ 64));
    }
#pragma unroll
    for (int j = 0; j < 4; j++) {
      bf16x8 bh0 = *(const bf16x8*)((const char*)Bh + boff[j]);
#pragma unroll
      for (int i = 0; i < 4; i++)
        acc[i][j] = __builtin_amdgcn_mfma_f32_16x16x32_bf16(ah0[i], bh0, acc[i][j], 0, 0, 0);
      bf16x8 bh1 = *(const bf16x8*)((const char*)Bh + (boff[j] ^ 64));
#pragma unroll
      for (int i = 0; i < 4; i++)
        acc[i][j] = __builtin_amdgcn_mfma_f32_16x16x32_bf16(ah1[i], bh1, acc[i][j], 0, 0, 0);
    }
  }
}

// ------------------------------------------------- span MLP (MFMA) -> partials
__global__ __launch_bounds__(256) void k_span_m(
    const float* __restrict__ lh, const u16* __restrict__ W1t,
    const float* __restrict__ b1, const float* __restrict__ W2,
    float* __restrict__ att8) {
  __shared__ __align__(16) u16 Ah[128 * 64], Bh[128 * 64];
  int rb = blockIdx.x & 255, cb = blockIdx.x >> 8;
  int row0 = rb * 128, col0 = cb * 128;
  f32x4 acc[4][4];
#pragma unroll
  for (int i = 0; i < 4; i++)
#pragma unroll
    for (int j = 0; j < 4; j++) acc[i][j] = (f32x4){0.f, 0.f, 0.f, 0.f};
  gemm_core(lh, W1t, D_, row0, col0, Ah, Bh, acc);

  int lane = threadIdx.x & 63, w = threadIdx.x >> 6;
  int wrow = (w & 1) * 64, wcol = (w >> 1) * 64;
  float b1v[4], w2v[4];
#pragma unroll
  for (int j = 0; j < 4; j++) {
    int col = col0 + wcol + j * 16 + (lane & 15);
    b1v[j] = b1[col]; w2v[j] = W2[col];
  }
  float* dst = att8 + (size_t)(cb * 2 + (w >> 1)) * 32768;
#pragma unroll
  for (int i = 0; i < 4; i++) {
#pragma unroll
    for (int r = 0; r < 4; r++) {
      float s = 0.f;
#pragma unroll
      for (int j = 0; j < 4; j++) {
        float h = acc[i][j][r] + b1v[j];
        s += fmaxf(h, 0.f) * w2v[j];
      }
      s += __shfl_xor(s, 1); s += __shfl_xor(s, 2);
      s += __shfl_xor(s, 4); s += __shfl_xor(s, 8);
      if ((lane & 15) == 0)
        dst[row0 + wrow + i * 16 + (lane >> 4) * 4 + r] = s;
    }
  }
}

// ------------------------------------------------- probs: masked softmax
__global__ void k_probs(const float* __restrict__ att8, const float* __restrict__ b2,
                        const float* __restrict__ mask, float* __restrict__ pr) {
  int bi = blockIdx.x >> 2, eg = blockIdx.x & 3;
  int tid = threadIdx.x, lane = tid & 63, w = tid >> 6;
  __shared__ float att_s[512];
  float b2v = b2[0];
  int r0 = bi * 512 + tid;
  float s0 = b2v, s1 = b2v;
#pragma unroll
  for (int p = 0; p < 8; p++) {
    s0 += att8[(size_t)p * 32768 + r0];
    s1 += att8[(size_t)p * 32768 + r0 + 256];
  }
  att_s[tid] = s0;
  att_s[tid + 256] = s1;
  __syncthreads();
#pragma unroll
  for (int it = 0; it < 2; it++) {
    int e = eg * 8 + it * 4 + w;
    const float* mrow = &mask[(size_t)(bi * E_ + e) * L_];
    float4 m0 = *(const float4*)&mrow[lane * 8];
    float4 m1 = *(const float4*)&mrow[lane * 8 + 4];
    float4 a0 = *(const float4*)&att_s[lane * 8];
    float4 a1 = *(const float4*)&att_s[lane * 8 + 4];
    float v[8];
    v[0] = a0.x - 1e5f * (1.f - m0.x); v[1] = a0.y - 1e5f * (1.f - m0.y);
    v[2] = a0.z - 1e5f * (1.f - m0.z); v[3] = a0.w - 1e5f * (1.f - m0.w);
    v[4] = a1.x - 1e5f * (1.f - m1.x); v[5] = a1.y - 1e5f * (1.f - m1.y);
    v[6] = a1.z - 1e5f * (1.f - m1.z); v[7] = a1.w - 1e5f * (1.f - m1.w);
    float mx = v[0];
#pragma unroll
    for (int i = 1; i < 8; i++) mx = fmaxf(mx, v[i]);
#pragma unroll
    for (int o = 32; o; o >>= 1) mx = fmaxf(mx, __shfl_xor(mx, o));
    float s = 0.f;
#pragma unroll
    for (int i = 0; i < 8; i++) { v[i] = expf(v[i] - mx); s += v[i]; }
#pragma unroll
    for (int o = 32; o; o >>= 1) s += __shfl_xor(s, o);
    float inv = 1.f / s;
    float4 o0 = {v[0] * inv, v[1] * inv, v[2] * inv, v[3] * inv};
    float4 o1 = {v[4] * inv, v[5] * inv, v[6] * inv, v[7] * inv};
    float* prow = &pr[(size_t)(bi * E_ + e) * L_];
    *(float4*)&prow[lane * 8] = o0;
    *(float4*)&prow[lane * 8 + 4] = o1;
  }
}

// ------------------------------------------------- pool via MFMA
// grid 384 = bi(64) x dc(6). node0[bi][e][dc*128..+128] = P[32x512] @ lh-block.
__global__ __launch_bounds__(256) void k_pool_m(const float* __restrict__ lh,
    const float* __restrict__ pr, float* __restrict__ node0) {
  __shared__ __align__(16) u16 As[32 * 32];    // [e][k], XOR-swizzled
  __shared__ __align__(16) u16 Bs[32 * 128];   // [k][col], linear
  int bi = blockIdx.x / 6, dc = blockIdx.x % 6;
  int col0 = dc * 128;
  int tid = threadIdx.x, lane = tid & 63, w = tid >> 6;
  const float* lhb = lh + (size_t)bi * L_ * D_;
  const float* prb = pr + (size_t)bi * E_ * L_;

  f32x4 acc[2][2];
#pragma unroll
  for (int m = 0; m < 2; m++)
#pragma unroll
    for (int c = 0; c < 2; c++) acc[m][c] = (f32x4){0.f, 0.f, 0.f, 0.f};

  int aoff[2];
#pragma unroll
  for (int m = 0; m < 2; m++) {
    int kc = lane >> 4;
    int e = m * 16 + (lane & 15);
    aoff[m] = e * 64 + (((kc ^ ((e >> 1) & 3)) & 3) << 4);
  }
  int se = tid >> 3, sk4 = tid & 7;
  int saoff = se * 64 + ((((sk4 >> 1) ^ ((se >> 1) & 3)) & 3) << 4) + (sk4 & 1) * 8;

  for (int kt = 0; kt < 16; kt++) {
    int l0 = kt << 5;
    if (kt) __syncthreads();
    {
      float4 v = *(const float4*)&prb[(size_t)se * L_ + l0 + sk4 * 4];
      u16x4 hv = {bf16_rn(v.x), bf16_rn(v.y), bf16_rn(v.z), bf16_rn(v.w)};
      *(u16x4*)((char*)As + saoff) = hv;
    }
#pragma unroll
    for (int p = 0; p < 4; p++) {
      int idx = tid + p * 256;
      int k = idx >> 5, c4 = idx & 31;
      float4 v = *(const float4*)&lhb[(size_t)(l0 + k) * D_ + col0 + c4 * 4];
      u16x4 hv = {bf16_rn(v.x), bf16_rn(v.y), bf16_rn(v.z), bf16_rn(v.w)};
      *(u16x4*)&Bs[k * 128 + c4 * 4] = hv;
    }
    __syncthreads();
    bf16x8 af[2];
#pragma unroll
    for (int m = 0; m < 2; m++)
      af[m] = *(const bf16x8*)((const char*)As + aoff[m]);
#pragma unroll
    for (int c = 0; c < 2; c++) {
      int colT = w * 32 + c * 16 + (lane & 15);
      int kg = (lane >> 4) * 8;
      union { bf16x8 v; u16 u[8]; } bb;
#pragma unroll
      for (int j = 0; j < 8; j++) bb.u[j] = Bs[(kg + j) * 128 + colT];
#pragma unroll
      for (int m = 0; m < 2; m++)
        acc[m][c] = __builtin_amdgcn_mfma_f32_16x16x32_bf16(af[m], bb.v, acc[m][c], 0, 0, 0);
    }
  }
#pragma unroll
  for (int m = 0; m < 2; m++)
#pragma unroll
    for (int c = 0; c < 2; c++) {
      int col = col0 + w * 32 + c * 16 + (lane & 15);
#pragma unroll
      for (int r = 0; r < 4; r++) {
        int e = m * 16 + (lane >> 4) * 4 + r;
        node0[(size_t)(bi * E_ + e) * D_ + col] = acc[m][c][r];
      }
    }
}

// ------------------------------------------------- fused q/k/v/skip GEMM (MFMA)
__global__ __launch_bounds__(256) void k_gemm4_m(
    const float* __restrict__ X, int K,
    const u16* __restrict__ Wt,
    const float* __restrict__ bb0, const float* __restrict__ bb1,
    const float* __restrict__ bb2, const float* __restrict__ bb3,
    float* __restrict__ O0, float* __restrict__ O1,
    float* __restrict__ O2, float* __restrict__ O3) {
  __shared__ __align__(16) u16 Ah[128 * 64], Bh[128 * 64];
  int rb = blockIdx.x & 15, cbm = blockIdx.x >> 4;
  int mat = cbm >> 3;
  int col0 = (cbm & 7) * 128, row0 = rb * 128;
  const u16* Bt = Wt + (size_t)mat * C_ * K;
  const float* bias; float* O;
  if (mat == 0)      { bias = bb0; O = O0; }
  else if (mat == 1) { bias = bb1; O = O1; }
  else if (mat == 2) { bias = bb2; O = O2; }
  else               { bias = bb3; O = O3; }

  f32x4 acc[4][4];
#pragma unroll
  for (int i = 0; i < 4; i++)
#pragma unroll
    for (int j = 0; j < 4; j++) acc[i][j] = (f32x4){0.f, 0.f, 0.f, 0.f};
  gemm_core(X, Bt, K, row0, col0, Ah, Bh, acc);

  int lane = threadIdx.x & 63, w = threadIdx.x >> 6;
  int wrow = (w & 1) * 64, wcol = (w >> 1) * 64;
#pragma unroll
  for (int j = 0; j < 4; j++) {
    int col = col0 + wcol + j * 16 + (lane & 15);
    float bv = bias[col];
#pragma unroll
    for (int i = 0; i < 4; i++) {
      int rowb = row0 + wrow + i * 16 + (lane >> 4) * 4;
#pragma unroll
      for (int r = 0; r < 4; r++)
        O[(size_t)(rowb + r) * C_ + col] = acc[i][j][r] + bv;
    }
  }
}

// -------------------------------------- edge embedding @ We, rank-3 form
__global__ void k_combo2(const float* __restrict__ Wr1, const float* __restrict__ br1,
                         const float* __restrict__ Wm1, const float* __restrict__ bm1,
                         const float* __restrict__ e1W,
                         const float* __restrict__ Wr2, const float* __restrict__ br2,
                         const float* __restrict__ Wm2, const float* __restrict__ bm2,
                         const float* __restrict__ e2W,
                         float* __restrict__ e1c, float* __restrict__ e2c) {
  int x = blockIdx.x;
  int conv = x >> 6;
  int jb = x & 3, kb = (x >> 2) & 15;
  const float *Wr, *br, *Wm, *bm, *eW; float* out;
  if (conv == 0) { Wr = Wr1; br = br1; Wm = Wm1; bm = bm1; eW = e1W; out = e1c; }
  else           { Wr = Wr2; br = br2; Wm = Wm2; bm = bm2; eW = e2W; out = e2c; }
  int tid = threadIdx.x;
  __shared__ float sw[3][64];
  int k0 = kb * 64;
  if (tid < 64) {
    sw[0][tid] = Wr[k0 + tid];
    sw[1][tid] = Wm[k0 + tid];
    sw[2][tid] = br[k0 + tid] + bm[k0 + tid];
  }
  __syncthreads();
  int j = jb * 256 + tid;
  float a0 = 0.f, a1 = 0.f, a2 = 0.f;
#pragma unroll 8
  for (int kk = 0; kk < 64; kk++) {
    float w = eW[(size_t)(k0 + kk) * C_ + j];
    a0 += sw[0][kk] * w; a1 += sw[1][kk] * w; a2 += sw[2][kk] * w;
  }
#pragma unroll
  for (int c = 0; c < 10; c++)
    atomicAdd(&out[c * C_ + j], (float)(c >> 1) * a0 + (float)(c & 1) * a1 + a2);
}

// ------------------------------------------------- CSR build
__global__ void k_count(const int* __restrict__ dst, int* __restrict__ cnt) {
  int eg = blockIdx.x * 256 + threadIdx.x;
  atomicAdd(&cnt[dst[eg]], 1);
}

__global__ void k_scan(const int* __restrict__ cnt, int* __restrict__ off) {
  __shared__ int part[256];
  int t = threadIdx.x;
  int local[8]; int s = 0;
#pragma unroll
  for (int i = 0; i < 8; i++) { local[i] = cnt[t * 8 + i]; s += local[i]; }
  part[t] = s;
  __syncthreads();
  if (t == 0) {
    int r = 0;
    for (int i = 0; i < 256; i++) { int v = part[i]; part[i] = r; r += v; }
    off[N_] = r;
  }
  __syncthreads();
  int r = part[t];
#pragma unroll
  for (int i = 0; i < 8; i++) { off[t * 8 + i] = r; r += local[i]; }
}

__global__ void k_scatter(const int* __restrict__ dst, int* __restrict__ wcnt,
                          const int* __restrict__ off, int* __restrict__ perm) {
  int eg = blockIdx.x * 256 + threadIdx.x;
  int d = dst[eg];
  int p = atomicAdd(&wcnt[d], 1);
  perm[off[d] + p] = eg;
}

// ------------------------------------------------- per-dst attention agg
__global__ void k_agg(const float* __restrict__ q, const float* __restrict__ k,
                      const float* __restrict__ v, const float* __restrict__ ec,
                      const int* __restrict__ srcA, const float* __restrict__ etype,
                      const float* __restrict__ emain, const int* __restrict__ off,
                      const int* __restrict__ perm, float* __restrict__ O) {
  int dst = blockIdx.x;
  int beg = off[dst];
  int cntE = off[dst + 1] - beg;
  if (cntE == 0) return;
  if (cntE > 128) cntE = 128;
  int tid = threadIdx.x;
  __shared__ float lg[128][8];
  __shared__ int srcs[128];
  __shared__ int cids[128];
  for (int e = tid; e < cntE; e += 256) {
    int eg = perm[beg + e];
    srcs[e] = srcA[eg];
    cids[e] = ((int)(etype[eg] + 0.5f)) * 2 + (int)(emain[eg] + 0.5f);
  }
  __syncthreads();
  int c = tid * 4;
  int h = tid >> 5;
  float4 qv = *(const float4*)&q[dst * C_ + c];
  const float scale = 0.08838834764831845f;  // 1/sqrt(128)
  for (int e = 0; e < cntE; e++) {
    int s = srcs[e], ci = cids[e];
    float4 kv = *(const float4*)&k[s * C_ + c];
    float4 ev = *(const float4*)&ec[ci * C_ + c];
    float p = qv.x * (kv.x + ev.x) + qv.y * (kv.y + ev.y) +
              qv.z * (kv.z + ev.z) + qv.w * (kv.w + ev.w);
#pragma unroll
    for (int o = 16; o; o >>= 1) p += __shfl_xor(p, o);
    if ((tid & 31) == 0) lg[e][h] = p * scale;
  }
  __syncthreads();
  if (tid < 8) {
    float m = -1e30f;
    for (int e = 0; e < cntE; e++) m = fmaxf(m, lg[e][tid]);
    float ssum = 0.f;
    for (int e = 0; e < cntE; e++) { float x = expf(lg[e][tid] - m); lg[e][tid] = x; ssum += x; }
    float inv = 1.f / ssum;
    for (int e = 0; e < cntE; e++) lg[e][tid] *= inv;
  }
  __syncthreads();
  float4 acc = {0.f, 0.f, 0.f, 0.f};
  for (int e = 0; e < cntE; e++) {
    float a = lg[e][h];
    int s = srcs[e], ci = cids[e];
    float4 vv = *(const float4*)&v[s * C_ + c];
    float4 ev = *(const float4*)&ec[ci * C_ + c];
    acc.x += a * (vv.x + ev.x); acc.y += a * (vv.y + ev.y);
    acc.z += a * (vv.z + ev.z); acc.w += a * (vv.w + ev.w);
  }
  float4 o = *(const float4*)&O[dst * C_ + c];
  o.x += acc.x; o.y += acc.y; o.z += acc.z; o.w += acc.w;
  *(float4*)&O[dst * C_ + c] = o;
}

// ------------------------------------------------- final gather + FC
__global__ void k_final(const float* __restrict__ nB, const int* __restrict__ lens,
                        const float* __restrict__ fcW, const float* __restrict__ fcb,
                        float* __restrict__ out) {
  int b = blockIdx.x;
  int idx = lens[b] - 1;
  const float* row = &nB[(b * E_ + idx) * C_];
  int tid = threadIdx.x;
  int c = tid * 4;
  float4 r = *(const float4*)&row[c];
  float4 w0 = *(const float4*)&fcW[(c + 0) * 4];
  float4 w1 = *(const float4*)&fcW[(c + 1) * 4];
  float4 w2 = *(const float4*)&fcW[(c + 2) * 4];
  float4 w3 = *(const float4*)&fcW[(c + 3) * 4];
  float p0 = r.x * w0.x + r.y * w1.x + r.z * w2.x + r.w * w3.x;
  float p1 = r.x * w0.y + r.y * w1.y + r.z * w2.y + r.w * w3.y;
  float p2 = r.x * w0.z + r.y * w1.z + r.z * w2.z + r.w * w3.z;
  float p3 = r.x * w0.w + r.y * w1.w + r.z * w2.w + r.w * w3.w;
#pragma unroll
  for (int o = 32; o; o >>= 1) {
    p0 += __shfl_xor(p0, o); p1 += __shfl_xor(p1, o);
    p2 += __shfl_xor(p2, o); p3 += __shfl_xor(p3, o);
  }
  __shared__ float red[4][4];
  if ((tid & 63) == 0) {
    int w = tid >> 6;
    red[w][0] = p0; red[w][1] = p1; red[w][2] = p2; red[w][3] = p3;
  }
  __syncthreads();
  if (tid == 0) {
#pragma unroll
    for (int j = 0; j < 4; j++)
      out[b * 4 + j] = red[0][j] + red[1][j] + red[2][j] + red[3][j] + fcb[j];
  }
}

// ================================================================ launch
extern "C" void kernel_launch(void* const* d_in, const int* in_sizes, int n_in,
                              void* d_out, int out_size, void* d_ws, size_t ws_size,
                              hipStream_t stream) {
  (void)in_sizes; (void)n_in; (void)out_size; (void)ws_size;
  const float* lh    = (const float*)d_in[0];
  const float* mask  = (const float*)d_in[1];
  const int*   lens  = (const int*)d_in[2];
  const int*   edge  = (const int*)d_in[3];
  const float* etype = (const float*)d_in[4];
  const float* emain = (const float*)d_in[5];
  const float* W1   = (const float*)d_in[6];
  const float* b1   = (const float*)d_in[7];
  const float* W2   = (const float*)d_in[8];
  const float* b2   = (const float*)d_in[9];
  const float* Wr1  = (const float*)d_in[10];
  const float* br1  = (const float*)d_in[11];
  const float* Wm1  = (const float*)d_in[12];
  const float* bm1  = (const float*)d_in[13];
  const float* Wr2  = (const float*)d_in[14];
  const float* br2  = (const float*)d_in[15];
  const float* Wm2  = (const float*)d_in[16];
  const float* bm2  = (const float*)d_in[17];
  const float* q1W  = (const float*)d_in[18];
  const float* q1b  = (const float*)d_in[19];
  const float* k1W  = (const float*)d_in[20];
  const float* k1b  = (const float*)d_in[21];
  const float* v1W  = (const float*)d_in[22];
  const float* v1b  = (const float*)d_in[23];
  const float* e1W  = (const float*)d_in[24];
  const float* s1W  = (const float*)d_in[25];
  const float* s1b  = (const float*)d_in[26];
  const float* q2W  = (const float*)d_in[27];
  const float* q2b  = (const float*)d_in[28];
  const float* k2W  = (const float*)d_in[29];
  const float* k2b  = (const float*)d_in[30];
  const float* v2W  = (const float*)d_in[31];
  const float* v2b  = (const float*)d_in[32];
  const float* e2W  = (const float*)d_in[33];
  const float* s2W  = (const float*)d_in[34];
  const float* s2b  = (const float*)d_in[35];
  const float* fcW  = (const float*)d_in[36];
  const float* fcb  = (const float*)d_in[37];

  float* ws    = (float*)d_ws;
  float* att   = ws;                       // 32768 (spare)
  float* node0 = att + 32768;              // 2048*768
  float* e1c   = node0 + ND_;              // 10*1024
  float* e2c   = e1c + 10 * 1024;
  float* qb    = e2c + 10 * 1024;          // 2048*1024 each
  float* kb    = qb + N_ * C_;
  float* vb    = kb + N_ * C_;
  float* nA    = vb + N_ * C_;
  float* nBuf  = nA + N_ * C_;
  int* cnt  = (int*)(nBuf + N_ * C_);      // 2048
  int* wcnt = cnt + N_;                    // 2048
  int* off  = wcnt + N_;                   // 2049 (pad to 2056)
  int* perm = off + (N_ + 8);              // 32768
  u16* wtb  = (u16*)(perm + EG_);          // all 9 bf16 transposed weights
  u16* w1t  = wtb;                         // 512*768
  u16* wt1  = w1t + SH_ * D_;              // 4*1024*768
  u16* wt2  = wt1 + 4 * C_ * D_;           // 4*1024*1024

  // transient aliases (consumed before conv1 gemm4 overwrites them)
  float* pr   = qb;                        // probs: 2048*512 fp32
  float* att8 = kb;                        // span partials: 8*32768

  const int* srcA = edge;
  const int* dstA = edge + EG_;

  // CSR build (shared by both convs)
  (void)hipMemsetAsync(cnt, 0, 2 * N_ * sizeof(int), stream);
  k_count<<<EG_ / 256, 256, 0, stream>>>(dstA, cnt);
  k_scan<<<1, 256, 0, stream>>>(cnt, off);
  k_scatter<<<EG_ / 256, 256, 0, stream>>>(dstA, wcnt, off, perm);

  // weight prep: all 9 transposes in one launch
  k_wt9<<<384 + 4 * 768 + 4 * 1024, 256, 0, stream>>>(
      W1, q1W, k1W, v1W, s1W, q2W, k2W, v2W, s2W, wtb);

  // span attention partials -> att8
  k_span_m<<<1024, 256, 0, stream>>>(lh, w1t, b1, W2, att8);

  // 10-combo edge embeddings (rank-3 decomposition)
  (void)hipMemsetAsync(e1c, 0, 20 * C_ * sizeof(float), stream);
  k_combo2<<<128, 256, 0, stream>>>(Wr1, br1, Wm1, bm1, e1W,
                                    Wr2, br2, Wm2, bm2, e2W, e1c, e2c);

  // pooling: probs -> MFMA pool
  k_probs<<<256, 256, 0, stream>>>(att8, b2, mask, pr);
  k_pool_m<<<384, 256, 0, stream>>>(lh, pr, node0);

  // conv1
  k_gemm4_m<<<512, 256, 0, stream>>>(node0, D_, wt1,
                                     q1b, k1b, v1b, s1b, qb, kb, vb, nA);
  k_agg<<<N_, 256, 0, stream>>>(qb, kb, vb, e1c, srcA, etype, emain, off, perm, nA);

  // conv2
  k_gemm4_m<<<512, 256, 0, stream>>>(nA, C_, wt2,
                                     q2b, k2b, v2b, s2b, qb, kb, vb, nBuf);
  k_agg<<<N_, 256, 0, stream>>>(qb, kb, vb, e2c, srcA, etype, emain, off, perm, nBuf);

  // final
  k_final<<<B_, 256, 0, stream>>>(nBuf, lens, fcW, fcb, (float*)d_out);
}

// Round 11
// 251.347 us; speedup vs baseline: 4.5150x; 1.0205x over previous
//
#include <hip/hip_runtime.h>
#include <math.h>
#include <stdint.h>

#define B_  64
#define E_  32
#define L_  512
#define D_  768
#define C_  1024
#define H_  8
#define EG_ 32768
#define SH_ 512
#define N_  2048   // B*E
#define ND_ (N_ * D_)

typedef __bf16 bf16x8 __attribute__((ext_vector_type(8)));
typedef float f32x4 __attribute__((ext_vector_type(4)));
typedef unsigned short u16;
typedef u16 u16x4 __attribute__((ext_vector_type(4)));

// ---------------------------------------------------------------- helpers

__device__ __forceinline__ u16 bf16_rn(float x) {
  unsigned u = __builtin_bit_cast(unsigned, x);
  unsigned r = u + 0x7FFFu + ((u >> 16) & 1u);
  return (u16)(r >> 16);
}

__device__ __forceinline__ void gload16(const void* g, void* l) {
  __builtin_amdgcn_global_load_lds(
      (const __attribute__((address_space(1))) void*)(unsigned long long)(uintptr_t)g,
      (__attribute__((address_space(3))) void*)(unsigned int)(uintptr_t)l,
      16, 0, 0);
}

// ------------------------------------------------- merged weight prep (9 mats)
__global__ void k_wt9(const float* __restrict__ s0, const float* __restrict__ s1,
                      const float* __restrict__ s2, const float* __restrict__ s3,
                      const float* __restrict__ s4, const float* __restrict__ s5,
                      const float* __restrict__ s6, const float* __restrict__ s7,
                      const float* __restrict__ s8, u16* __restrict__ dstBase) {
  int x = blockIdx.x;
  const float* W; u16* TH; int K, Nc;
  if (x < 384) {                       // W1: 768x512
    W = s0; TH = dstBase; K = D_; Nc = SH_;
  } else if (x < 384 + 4 * 768) {      // conv1 q/k/v/s: 768x1024
    int i = (x - 384) / 768; x = (x - 384) % 768;
    W = (i == 0) ? s1 : (i == 1) ? s2 : (i == 2) ? s3 : s4;
    TH = dstBase + SH_ * D_ + (size_t)i * C_ * D_; K = D_; Nc = C_;
  } else {                             // conv2 q/k/v/s: 1024x1024
    int i = (x - 3456) / 1024; x = (x - 3456) % 1024;
    W = (i == 0) ? s5 : (i == 1) ? s6 : (i == 2) ? s7 : s8;
    TH = dstBase + SH_ * D_ + 4 * (size_t)C_ * D_ + (size_t)i * C_ * C_; K = C_; Nc = C_;
  }
  __shared__ float Ts[32][33];
  int nbk = K >> 5;
  int bk = x % nbk, bn = x / nbk;
  int tid = threadIdx.x;
  int tx = tid & 31, ty = tid >> 5;
  for (int r = ty; r < 32; r += 8)
    Ts[r][tx] = W[(size_t)(bk * 32 + r) * Nc + bn * 32 + tx];
  __syncthreads();
  for (int r = ty; r < 32; r += 8) {
    float v = Ts[tx][r];
    TH[(size_t)(bn * 32 + r) * K + bk * 32 + tx] = bf16_rn(v);
  }
}

// ------------------------------------------------- MFMA GEMM core, BK=64
// (used by k_gemm4_m) 128x128 tile, 4 waves.
__device__ __forceinline__ void gemm_core(
    const float* __restrict__ X, const u16* __restrict__ Bt,
    int K, int row0, int col0,
    u16* Ah, u16* Bh, f32x4 acc[4][4])
{
  int tid = threadIdx.x;
  int lane = tid & 63, w = tid >> 6;

  int aoff[4], boff[4];
#pragma unroll
  for (int i = 0; i < 4; i++) {
    int kc = lane >> 4;
    int rT = (w & 1) * 64 + i * 16 + (lane & 15);
    aoff[i] = rT * 128 + (((kc ^ (rT & 7)) & 7) << 4);
    int cT = (w >> 1) * 64 + i * 16 + (lane & 15);
    boff[i] = cT * 128 + (((kc ^ (cT & 7)) & 7) << 4);
  }

  int nkt = K >> 6;
  for (int kt = 0; kt < nkt; kt++) {
    int k0 = kt << 6;
    if (kt) __syncthreads();
#pragma unroll
    for (int p = 0; p < 8; p++) {
      int idx = tid + p * 256;           // 0..2047
      int r = idx >> 4, c4 = idx & 15;
      float4 v = *(const float4*)&X[(size_t)(row0 + r) * K + k0 + c4 * 4];
      u16x4 hv = {bf16_rn(v.x), bf16_rn(v.y), bf16_rn(v.z), bf16_rn(v.w)};
      int off = r * 128 + ((((c4 >> 1) ^ (r & 7)) & 7) << 4) + (c4 & 1) * 8;
      *(u16x4*)((char*)Ah + off) = hv;
    }
#pragma unroll
    for (int q = 0; q < 4; q++) {
      int rT = w * 32 + q * 8 + (lane >> 3);
      int cs = (lane & 7) ^ (rT & 7);
      size_t gb = (size_t)(col0 + rT) * K + k0 + cs * 8;
      int lb = (w * 32 + q * 8) * 64;
      gload16(&Bt[gb], &Bh[lb]);
    }
    __syncthreads();
    bf16x8 ah0[4], ah1[4];
#pragma unroll
    for (int i = 0; i < 4; i++) {
      ah0[i] = *(const bf16x8*)((const char*)Ah + aoff[i]);
      ah1[i] = *(const bf16x8*)((const char*)Ah + (aoff[i] ^ 64));
    }
#pragma unroll
    for (int j = 0; j < 4; j++) {
      bf16x8 bh0 = *(const bf16x8*)((const char*)Bh + boff[j]);
#pragma unroll
      for (int i = 0; i < 4; i++)
        acc[i][j] = __builtin_amdgcn_mfma_f32_16x16x32_bf16(ah0[i], bh0, acc[i][j], 0, 0, 0);
      bf16x8 bh1 = *(const bf16x8*)((const char*)Bh + (boff[j] ^ 64));
#pragma unroll
      for (int i = 0; i < 4; i++)
        acc[i][j] = __builtin_amdgcn_mfma_f32_16x16x32_bf16(ah1[i], bh1, acc[i][j], 0, 0, 0);
    }
  }
}

// ------------------------------------------------- span MLP: 128x512 tile/block
// grid 256 (row-strips); 8 waves (rh=w&1: 64 rows, cq=w>>1: 128 cols).
// lh read exactly once (no col-block redundancy); full epilogue in-block -> att.
__global__ __launch_bounds__(512, 2) void k_span_m(
    const float* __restrict__ lh, const u16* __restrict__ W1t,
    const float* __restrict__ b1, const float* __restrict__ W2,
    float* __restrict__ att) {
  __shared__ __align__(16) u16 Ah[128 * 64];   // 16 KB
  __shared__ __align__(16) u16 Bh[512 * 64];   // 64 KB
  int row0 = blockIdx.x * 128;
  int tid = threadIdx.x, lane = tid & 63, w = tid >> 6;
  int rh = w & 1, cq = w >> 1;

  f32x4 acc[4][8];
#pragma unroll
  for (int i = 0; i < 4; i++)
#pragma unroll
    for (int j = 0; j < 8; j++) acc[i][j] = (f32x4){0.f, 0.f, 0.f, 0.f};

  int kc = lane >> 4;
  int aoff[4], boff[8];
#pragma unroll
  for (int i = 0; i < 4; i++) {
    int rT = rh * 64 + i * 16 + (lane & 15);
    aoff[i] = rT * 128 + (((kc ^ (rT & 7)) & 7) << 4);
  }
#pragma unroll
  for (int j = 0; j < 8; j++) {
    int cT = cq * 128 + j * 16 + (lane & 15);
    boff[j] = cT * 128 + (((kc ^ (cT & 7)) & 7) << 4);
  }

  for (int kt = 0; kt < 12; kt++) {     // K = 768, BK = 64
    int k0 = kt << 6;
    if (kt) __syncthreads();
    // A: 128 rows x 64k from lh (fp32 -> bf16, swizzled)
#pragma unroll
    for (int p = 0; p < 4; p++) {
      int idx = tid + p * 512;           // 0..2047
      int r = idx >> 4, c4 = idx & 15;
      float4 v = *(const float4*)&lh[(size_t)(row0 + r) * D_ + k0 + c4 * 4];
      u16x4 hv = {bf16_rn(v.x), bf16_rn(v.y), bf16_rn(v.z), bf16_rn(v.w)};
      int off = r * 128 + ((((c4 >> 1) ^ (r & 7)) & 7) << 4) + (c4 & 1) * 8;
      *(u16x4*)((char*)Ah + off) = hv;
    }
    // B: all 512 W1t rows x 64k via global_load_lds (inverse-swizzled source)
#pragma unroll
    for (int q = 0; q < 8; q++) {
      int rT = w * 64 + q * 8 + (lane >> 3);
      int cs = (lane & 7) ^ (rT & 7);
      size_t gb = (size_t)rT * D_ + k0 + cs * 8;
      int lb = (w * 64 + q * 8) * 64;    // u16 units, wave-uniform
      gload16(&W1t[gb], &Bh[lb]);
    }
    __syncthreads();
    bf16x8 ah0[4], ah1[4];
#pragma unroll
    for (int i = 0; i < 4; i++) {
      ah0[i] = *(const bf16x8*)((const char*)Ah + aoff[i]);
      ah1[i] = *(const bf16x8*)((const char*)Ah + (aoff[i] ^ 64));
    }
#pragma unroll
    for (int j = 0; j < 8; j++) {
      bf16x8 bh0 = *(const bf16x8*)((const char*)Bh + boff[j]);
#pragma unroll
      for (int i = 0; i < 4; i++)
        acc[i][j] = __builtin_amdgcn_mfma_f32_16x16x32_bf16(ah0[i], bh0, acc[i][j], 0, 0, 0);
      bf16x8 bh1 = *(const bf16x8*)((const char*)Bh + (boff[j] ^ 64));
#pragma unroll
      for (int i = 0; i < 4; i++)
        acc[i][j] = __builtin_amdgcn_mfma_f32_16x16x32_bf16(ah1[i], bh1, acc[i][j], 0, 0, 0);
    }
  }

  // epilogue: s[row] = sum_j relu(acc + b1) * w2 over this wave's 128 cols,
  // then cross-wave (cq) reduce via LDS.
  float b1v[8], w2v[8];
#pragma unroll
  for (int j = 0; j < 8; j++) {
    int col = cq * 128 + j * 16 + (lane & 15);
    b1v[j] = b1[col]; w2v[j] = W2[col];
  }
  __syncthreads();                       // done with Ah; reuse as reduce buffer
  float* sred = (float*)Ah;              // [4][128]
#pragma unroll
  for (int i = 0; i < 4; i++) {
#pragma unroll
    for (int r = 0; r < 4; r++) {
      float s = 0.f;
#pragma unroll
      for (int j = 0; j < 8; j++) {
        float h = acc[i][j][r] + b1v[j];
        s += fmaxf(h, 0.f) * w2v[j];
      }
      s += __shfl_xor(s, 1); s += __shfl_xor(s, 2);
      s += __shfl_xor(s, 4); s += __shfl_xor(s, 8);
      if ((lane & 15) == 0)
        sred[cq * 128 + rh * 64 + i * 16 + (lane >> 4) * 4 + r] = s;
    }
  }
  __syncthreads();
  if (tid < 128)
    att[row0 + tid] = sred[tid] + sred[128 + tid] + sred[256 + tid] + sred[384 + tid];
}

// ------------------------------------------------- probs: masked softmax
__global__ void k_probs(const float* __restrict__ att, const float* __restrict__ b2,
                        const float* __restrict__ mask, float* __restrict__ pr) {
  int bi = blockIdx.x >> 2, eg = blockIdx.x & 3;
  int tid = threadIdx.x, lane = tid & 63, w = tid >> 6;
  __shared__ float att_s[512];
  float b2v = b2[0];
  int r0 = bi * 512 + tid;
  att_s[tid] = att[r0] + b2v;
  att_s[tid + 256] = att[r0 + 256] + b2v;
  __syncthreads();
#pragma unroll
  for (int it = 0; it < 2; it++) {
    int e = eg * 8 + it * 4 + w;
    const float* mrow = &mask[(size_t)(bi * E_ + e) * L_];
    float4 m0 = *(const float4*)&mrow[lane * 8];
    float4 m1 = *(const float4*)&mrow[lane * 8 + 4];
    float4 a0 = *(const float4*)&att_s[lane * 8];
    float4 a1 = *(const float4*)&att_s[lane * 8 + 4];
    float v[8];
    v[0] = a0.x - 1e5f * (1.f - m0.x); v[1] = a0.y - 1e5f * (1.f - m0.y);
    v[2] = a0.z - 1e5f * (1.f - m0.z); v[3] = a0.w - 1e5f * (1.f - m0.w);
    v[4] = a1.x - 1e5f * (1.f - m1.x); v[5] = a1.y - 1e5f * (1.f - m1.y);
    v[6] = a1.z - 1e5f * (1.f - m1.z); v[7] = a1.w - 1e5f * (1.f - m1.w);
    float mx = v[0];
#pragma unroll
    for (int i = 1; i < 8; i++) mx = fmaxf(mx, v[i]);
#pragma unroll
    for (int o = 32; o; o >>= 1) mx = fmaxf(mx, __shfl_xor(mx, o));
    float s = 0.f;
#pragma unroll
    for (int i = 0; i < 8; i++) { v[i] = expf(v[i] - mx); s += v[i]; }
#pragma unroll
    for (int o = 32; o; o >>= 1) s += __shfl_xor(s, o);
    float inv = 1.f / s;
    float4 o0 = {v[0] * inv, v[1] * inv, v[2] * inv, v[3] * inv};
    float4 o1 = {v[4] * inv, v[5] * inv, v[6] * inv, v[7] * inv};
    float* prow = &pr[(size_t)(bi * E_ + e) * L_];
    *(float4*)&prow[lane * 8] = o0;
    *(float4*)&prow[lane * 8 + 4] = o1;
  }
}

// ------------------------------------------------- pool via MFMA
__global__ __launch_bounds__(256) void k_pool_m(const float* __restrict__ lh,
    const float* __restrict__ pr, float* __restrict__ node0) {
  __shared__ __align__(16) u16 As[32 * 32];
  __shared__ __align__(16) u16 Bs[32 * 128];
  int bi = blockIdx.x / 6, dc = blockIdx.x % 6;
  int col0 = dc * 128;
  int tid = threadIdx.x, lane = tid & 63, w = tid >> 6;
  const float* lhb = lh + (size_t)bi * L_ * D_;
  const float* prb = pr + (size_t)bi * E_ * L_;

  f32x4 acc[2][2];
#pragma unroll
  for (int m = 0; m < 2; m++)
#pragma unroll
    for (int c = 0; c < 2; c++) acc[m][c] = (f32x4){0.f, 0.f, 0.f, 0.f};

  int aoff[2];
#pragma unroll
  for (int m = 0; m < 2; m++) {
    int kc = lane >> 4;
    int e = m * 16 + (lane & 15);
    aoff[m] = e * 64 + (((kc ^ ((e >> 1) & 3)) & 3) << 4);
  }
  int se = tid >> 3, sk4 = tid & 7;
  int saoff = se * 64 + ((((sk4 >> 1) ^ ((se >> 1) & 3)) & 3) << 4) + (sk4 & 1) * 8;

  for (int kt = 0; kt < 16; kt++) {
    int l0 = kt << 5;
    if (kt) __syncthreads();
    {
      float4 v = *(const float4*)&prb[(size_t)se * L_ + l0 + sk4 * 4];
      u16x4 hv = {bf16_rn(v.x), bf16_rn(v.y), bf16_rn(v.z), bf16_rn(v.w)};
      *(u16x4*)((char*)As + saoff) = hv;
    }
#pragma unroll
    for (int p = 0; p < 4; p++) {
      int idx = tid + p * 256;
      int k = idx >> 5, c4 = idx & 31;
      float4 v = *(const float4*)&lhb[(size_t)(l0 + k) * D_ + col0 + c4 * 4];
      u16x4 hv = {bf16_rn(v.x), bf16_rn(v.y), bf16_rn(v.z), bf16_rn(v.w)};
      *(u16x4*)&Bs[k * 128 + c4 * 4] = hv;
    }
    __syncthreads();
    bf16x8 af[2];
#pragma unroll
    for (int m = 0; m < 2; m++)
      af[m] = *(const bf16x8*)((const char*)As + aoff[m]);
#pragma unroll
    for (int c = 0; c < 2; c++) {
      int colT = w * 32 + c * 16 + (lane & 15);
      int kg = (lane >> 4) * 8;
      union { bf16x8 v; u16 u[8]; } bb;
#pragma unroll
      for (int j = 0; j < 8; j++) bb.u[j] = Bs[(kg + j) * 128 + colT];
#pragma unroll
      for (int m = 0; m < 2; m++)
        acc[m][c] = __builtin_amdgcn_mfma_f32_16x16x32_bf16(af[m], bb.v, acc[m][c], 0, 0, 0);
    }
  }
#pragma unroll
  for (int m = 0; m < 2; m++)
#pragma unroll
    for (int c = 0; c < 2; c++) {
      int col = col0 + w * 32 + c * 16 + (lane & 15);
#pragma unroll
      for (int r = 0; r < 4; r++) {
        int e = m * 16 + (lane >> 4) * 4 + r;
        node0[(size_t)(bi * E_ + e) * D_ + col] = acc[m][c][r];
      }
    }
}

// ------------------------------------------------- fused q/k/v/skip GEMM (MFMA)
__global__ __launch_bounds__(256) void k_gemm4_m(
    const float* __restrict__ X, int K,
    const u16* __restrict__ Wt,
    const float* __restrict__ bb0, const float* __restrict__ bb1,
    const float* __restrict__ bb2, const float* __restrict__ bb3,
    float* __restrict__ O0, float* __restrict__ O1,
    float* __restrict__ O2, float* __restrict__ O3) {
  __shared__ __align__(16) u16 Ah[128 * 64], Bh[128 * 64];
  int rb = blockIdx.x & 15, cbm = blockIdx.x >> 4;
  int mat = cbm >> 3;
  int col0 = (cbm & 7) * 128, row0 = rb * 128;
  const u16* Bt = Wt + (size_t)mat * C_ * K;
  const float* bias; float* O;
  if (mat == 0)      { bias = bb0; O = O0; }
  else if (mat == 1) { bias = bb1; O = O1; }
  else if (mat == 2) { bias = bb2; O = O2; }
  else               { bias = bb3; O = O3; }

  f32x4 acc[4][4];
#pragma unroll
  for (int i = 0; i < 4; i++)
#pragma unroll
    for (int j = 0; j < 4; j++) acc[i][j] = (f32x4){0.f, 0.f, 0.f, 0.f};
  gemm_core(X, Bt, K, row0, col0, Ah, Bh, acc);

  int lane = threadIdx.x & 63, w = threadIdx.x >> 6;
  int wrow = (w & 1) * 64, wcol = (w >> 1) * 64;
#pragma unroll
  for (int j = 0; j < 4; j++) {
    int col = col0 + wcol + j * 16 + (lane & 15);
    float bv = bias[col];
#pragma unroll
    for (int i = 0; i < 4; i++) {
      int rowb = row0 + wrow + i * 16 + (lane >> 4) * 4;
#pragma unroll
      for (int r = 0; r < 4; r++)
        O[(size_t)(rowb + r) * C_ + col] = acc[i][j][r] + bv;
    }
  }
}

// -------------------------------------- edge embedding @ We, rank-3 form
__global__ void k_combo2(const float* __restrict__ Wr1, const float* __restrict__ br1,
                         const float* __restrict__ Wm1, const float* __restrict__ bm1,
                         const float* __restrict__ e1W,
                         const float* __restrict__ Wr2, const float* __restrict__ br2,
                         const float* __restrict__ Wm2, const float* __restrict__ bm2,
                         const float* __restrict__ e2W,
                         float* __restrict__ e1c, float* __restrict__ e2c) {
  int x = blockIdx.x;
  int conv = x >> 6;
  int jb = x & 3, kb = (x >> 2) & 15;
  const float *Wr, *br, *Wm, *bm, *eW; float* out;
  if (conv == 0) { Wr = Wr1; br = br1; Wm = Wm1; bm = bm1; eW = e1W; out = e1c; }
  else           { Wr = Wr2; br = br2; Wm = Wm2; bm = bm2; eW = e2W; out = e2c; }
  int tid = threadIdx.x;
  __shared__ float sw[3][64];
  int k0 = kb * 64;
  if (tid < 64) {
    sw[0][tid] = Wr[k0 + tid];
    sw[1][tid] = Wm[k0 + tid];
    sw[2][tid] = br[k0 + tid] + bm[k0 + tid];
  }
  __syncthreads();
  int j = jb * 256 + tid;
  float a0 = 0.f, a1 = 0.f, a2 = 0.f;
#pragma unroll 8
  for (int kk = 0; kk < 64; kk++) {
    float w = eW[(size_t)(k0 + kk) * C_ + j];
    a0 += sw[0][kk] * w; a1 += sw[1][kk] * w; a2 += sw[2][kk] * w;
  }
#pragma unroll
  for (int c = 0; c < 10; c++)
    atomicAdd(&out[c * C_ + j], (float)(c >> 1) * a0 + (float)(c & 1) * a1 + a2);
}

// ------------------------------------------------- CSR build
__global__ void k_count(const int* __restrict__ dst, int* __restrict__ cnt) {
  int eg = blockIdx.x * 256 + threadIdx.x;
  atomicAdd(&cnt[dst[eg]], 1);
}

__global__ void k_scan(const int* __restrict__ cnt, int* __restrict__ off) {
  __shared__ int part[256];
  int t = threadIdx.x;
  int local[8]; int s = 0;
#pragma unroll
  for (int i = 0; i < 8; i++) { local[i] = cnt[t * 8 + i]; s += local[i]; }
  part[t] = s;
  __syncthreads();
  if (t == 0) {
    int r = 0;
    for (int i = 0; i < 256; i++) { int v = part[i]; part[i] = r; r += v; }
    off[N_] = r;
  }
  __syncthreads();
  int r = part[t];
#pragma unroll
  for (int i = 0; i < 8; i++) { off[t * 8 + i] = r; r += local[i]; }
}

__global__ void k_scatter(const int* __restrict__ dst, int* __restrict__ wcnt,
                          const int* __restrict__ off, int* __restrict__ perm) {
  int eg = blockIdx.x * 256 + threadIdx.x;
  int d = dst[eg];
  int p = atomicAdd(&wcnt[d], 1);
  perm[off[d] + p] = eg;
}

// ------------------------------------------------- per-dst attention agg
__global__ void k_agg(const float* __restrict__ q, const float* __restrict__ k,
                      const float* __restrict__ v, const float* __restrict__ ec,
                      const int* __restrict__ srcA, const float* __restrict__ etype,
                      const float* __restrict__ emain, const int* __restrict__ off,
                      const int* __restrict__ perm, float* __restrict__ O) {
  int dst = blockIdx.x;
  int beg = off[dst];
  int cntE = off[dst + 1] - beg;
  if (cntE == 0) return;
  if (cntE > 128) cntE = 128;
  int tid = threadIdx.x;
  __shared__ float lg[128][8];
  __shared__ int srcs[128];
  __shared__ int cids[128];
  for (int e = tid; e < cntE; e += 256) {
    int eg = perm[beg + e];
    srcs[e] = srcA[eg];
    cids[e] = ((int)(etype[eg] + 0.5f)) * 2 + (int)(emain[eg] + 0.5f);
  }
  __syncthreads();
  int c = tid * 4;
  int h = tid >> 5;
  float4 qv = *(const float4*)&q[dst * C_ + c];
  const float scale = 0.08838834764831845f;  // 1/sqrt(128)
  for (int e = 0; e < cntE; e++) {
    int s = srcs[e], ci = cids[e];
    float4 kv = *(const float4*)&k[s * C_ + c];
    float4 ev = *(const float4*)&ec[ci * C_ + c];
    float p = qv.x * (kv.x + ev.x) + qv.y * (kv.y + ev.y) +
              qv.z * (kv.z + ev.z) + qv.w * (kv.w + ev.w);
#pragma unroll
    for (int o = 16; o; o >>= 1) p += __shfl_xor(p, o);
    if ((tid & 31) == 0) lg[e][h] = p * scale;
  }
  __syncthreads();
  if (tid < 8) {
    float m = -1e30f;
    for (int e = 0; e < cntE; e++) m = fmaxf(m, lg[e][tid]);
    float ssum = 0.f;
    for (int e = 0; e < cntE; e++) { float x = expf(lg[e][tid] - m); lg[e][tid] = x; ssum += x; }
    float inv = 1.f / ssum;
    for (int e = 0; e < cntE; e++) lg[e][tid] *= inv;
  }
  __syncthreads();
  float4 acc = {0.f, 0.f, 0.f, 0.f};
  for (int e = 0; e < cntE; e++) {
    float a = lg[e][h];
    int s = srcs[e], ci = cids[e];
    float4 vv = *(const float4*)&v[s * C_ + c];
    float4 ev = *(const float4*)&ec[ci * C_ + c];
    acc.x += a * (vv.x + ev.x); acc.y += a * (vv.y + ev.y);
    acc.z += a * (vv.z + ev.z); acc.w += a * (vv.w + ev.w);
  }
  float4 o = *(const float4*)&O[dst * C_ + c];
  o.x += acc.x; o.y += acc.y; o.z += acc.z; o.w += acc.w;
  *(float4*)&O[dst * C_ + c] = o;
}

// ------------------------------------------------- final gather + FC
__global__ void k_final(const float* __restrict__ nB, const int* __restrict__ lens,
                        const float* __restrict__ fcW, const float* __restrict__ fcb,
                        float* __restrict__ out) {
  int b = blockIdx.x;
  int idx = lens[b] - 1;
  const float* row = &nB[(b * E_ + idx) * C_];
  int tid = threadIdx.x;
  int c = tid * 4;
  float4 r = *(const float4*)&row[c];
  float4 w0 = *(const float4*)&fcW[(c + 0) * 4];
  float4 w1 = *(const float4*)&fcW[(c + 1) * 4];
  float4 w2 = *(const float4*)&fcW[(c + 2) * 4];
  float4 w3 = *(const float4*)&fcW[(c + 3) * 4];
  float p0 = r.x * w0.x + r.y * w1.x + r.z * w2.x + r.w * w3.x;
  float p1 = r.x * w0.y + r.y * w1.y + r.z * w2.y + r.w * w3.y;
  float p2 = r.x * w0.z + r.y * w1.z + r.z * w2.z + r.w * w3.z;
  float p3 = r.x * w0.w + r.y * w1.w + r.z * w2.w + r.w * w3.w;
#pragma unroll
  for (int o = 32; o; o >>= 1) {
    p0 += __shfl_xor(p0, o); p1 += __shfl_xor(p1, o);
    p2 += __shfl_xor(p2, o); p3 += __shfl_xor(p3, o);
  }
  __shared__ float red[4][4];
  if ((tid & 63) == 0) {
    int w = tid >> 6;
    red[w][0] = p0; red[w][1] = p1; red[w][2] = p2; red[w][3] = p3;
  }
  __syncthreads();
  if (tid == 0) {
#pragma unroll
    for (int j = 0; j < 4; j++)
      out[b * 4 + j] = red[0][j] + red[1][j] + red[2][j] + red[3][j] + fcb[j];
  }
}

// ================================================================ launch
extern "C" void kernel_launch(void* const* d_in, const int* in_sizes, int n_in,
                              void* d_out, int out_size, void* d_ws, size_t ws_size,
                              hipStream_t stream) {
  (void)in_sizes; (void)n_in; (void)out_size; (void)ws_size;
  const float* lh    = (const float*)d_in[0];
  const float* mask  = (const float*)d_in[1];
  const int*   lens  = (const int*)d_in[2];
  const int*   edge  = (const int*)d_in[3];
  const float* etype = (const float*)d_in[4];
  const float* emain = (const float*)d_in[5];
  const float* W1   = (const float*)d_in[6];
  const float* b1   = (const float*)d_in[7];
  const float* W2   = (const float*)d_in[8];
  const float* b2   = (const float*)d_in[9];
  const float* Wr1  = (const float*)d_in[10];
  const float* br1  = (const float*)d_in[11];
  const float* Wm1  = (const float*)d_in[12];
  const float* bm1  = (const float*)d_in[13];
  const float* Wr2  = (const float*)d_in[14];
  const float* br2  = (const float*)d_in[15];
  const float* Wm2  = (const float*)d_in[16];
  const float* bm2  = (const float*)d_in[17];
  const float* q1W  = (const float*)d_in[18];
  const float* q1b  = (const float*)d_in[19];
  const float* k1W  = (const float*)d_in[20];
  const float* k1b  = (const float*)d_in[21];
  const float* v1W  = (const float*)d_in[22];
  const float* v1b  = (const float*)d_in[23];
  const float* e1W  = (const float*)d_in[24];
  const float* s1W  = (const float*)d_in[25];
  const float* s1b  = (const float*)d_in[26];
  const float* q2W  = (const float*)d_in[27];
  const float* q2b  = (const float*)d_in[28];
  const float* k2W  = (const float*)d_in[29];
  const float* k2b  = (const float*)d_in[30];
  const float* v2W  = (const float*)d_in[31];
  const float* v2b  = (const float*)d_in[32];
  const float* e2W  = (const float*)d_in[33];
  const float* s2W  = (const float*)d_in[34];
  const float* s2b  = (const float*)d_in[35];
  const float* fcW  = (const float*)d_in[36];
  const float* fcb  = (const float*)d_in[37];

  float* ws    = (float*)d_ws;
  float* att   = ws;                       // 32768 (span logits, no b2)
  float* node0 = att + 32768;              // 2048*768
  float* e1c   = node0 + ND_;              // 10*1024
  float* e2c   = e1c + 10 * 1024;
  float* qb    = e2c + 10 * 1024;          // 2048*1024 each
  float* kb    = qb + N_ * C_;
  float* vb    = kb + N_ * C_;
  float* nA    = vb + N_ * C_;
  float* nBuf  = nA + N_ * C_;
  int* cnt  = (int*)(nBuf + N_ * C_);      // 2048
  int* wcnt = cnt + N_;                    // 2048
  int* off  = wcnt + N_;                   // 2049 (pad to 2056)
  int* perm = off + (N_ + 8);              // 32768
  u16* wtb  = (u16*)(perm + EG_);          // all 9 bf16 transposed weights
  u16* w1t  = wtb;                         // 512*768
  u16* wt1  = w1t + SH_ * D_;              // 4*1024*768
  u16* wt2  = wt1 + 4 * C_ * D_;           // 4*1024*1024

  // transient alias (consumed before conv1 gemm4 overwrites it)
  float* pr   = qb;                        // probs: 2048*512 fp32

  const int* srcA = edge;
  const int* dstA = edge + EG_;

  // CSR build (shared by both convs)
  (void)hipMemsetAsync(cnt, 0, 2 * N_ * sizeof(int), stream);
  k_count<<<EG_ / 256, 256, 0, stream>>>(dstA, cnt);
  k_scan<<<1, 256, 0, stream>>>(cnt, off);
  k_scatter<<<EG_ / 256, 256, 0, stream>>>(dstA, wcnt, off, perm);

  // weight prep: all 9 transposes in one launch
  k_wt9<<<384 + 4 * 768 + 4 * 1024, 256, 0, stream>>>(
      W1, q1W, k1W, v1W, s1W, q2W, k2W, v2W, s2W, wtb);

  // span attention -> att (full logits, one pass over lh)
  k_span_m<<<256, 512, 0, stream>>>(lh, w1t, b1, W2, att);

  // 10-combo edge embeddings (rank-3 decomposition)
  (void)hipMemsetAsync(e1c, 0, 20 * C_ * sizeof(float), stream);
  k_combo2<<<128, 256, 0, stream>>>(Wr1, br1, Wm1, bm1, e1W,
                                    Wr2, br2, Wm2, bm2, e2W, e1c, e2c);

  // pooling: probs -> MFMA pool
  k_probs<<<256, 256, 0, stream>>>(att, b2, mask, pr);
  k_pool_m<<<384, 256, 0, stream>>>(lh, pr, node0);

  // conv1
  k_gemm4_m<<<512, 256, 0, stream>>>(node0, D_, wt1,
                                     q1b, k1b, v1b, s1b, qb, kb, vb, nA);
  k_agg<<<N_, 256, 0, stream>>>(qb, kb, vb, e1c, srcA, etype, emain, off, perm, nA);

  // conv2
  k_gemm4_m<<<512, 256, 0, stream>>>(nA, C_, wt2,
                                     q2b, k2b, v2b, s2b, qb, kb, vb, nBuf);
  k_agg<<<N_, 256, 0, stream>>>(qb, kb, vb, e2c, srcA, etype, emain, off, perm, nBuf);

  // final
  k_final<<<B_, 256, 0, stream>>>(nBuf, lens, fcW, fcb, (float*)d_out);
}

// Round 12
// 244.502 us; speedup vs baseline: 4.6414x; 1.0280x over previous
//
#include <hip/hip_runtime.h>
#include <math.h>
#include <stdint.h>

#define B_  64
#define E_  32
#define L_  512
#define D_  768
#define C_  1024
#define H_  8
#define EG_ 32768
#define SH_ 512
#define N_  2048   // B*E
#define ND_ (N_ * D_)

typedef __bf16 bf16x8 __attribute__((ext_vector_type(8)));
typedef float f32x4 __attribute__((ext_vector_type(4)));
typedef unsigned short u16;
typedef u16 u16x4 __attribute__((ext_vector_type(4)));

// ---------------------------------------------------------------- helpers

__device__ __forceinline__ u16 bf16_rn(float x) {
  unsigned u = __builtin_bit_cast(unsigned, x);
  unsigned r = u + 0x7FFFu + ((u >> 16) & 1u);
  return (u16)(r >> 16);
}

__device__ __forceinline__ void gload16(const void* g, void* l) {
  __builtin_amdgcn_global_load_lds(
      (const __attribute__((address_space(1))) void*)(unsigned long long)(uintptr_t)g,
      (__attribute__((address_space(3))) void*)(unsigned int)(uintptr_t)l,
      16, 0, 0);
}

// ------------------------------------------------- merged weight prep (9 mats)
__global__ void k_wt9(const float* __restrict__ s0, const float* __restrict__ s1,
                      const float* __restrict__ s2, const float* __restrict__ s3,
                      const float* __restrict__ s4, const float* __restrict__ s5,
                      const float* __restrict__ s6, const float* __restrict__ s7,
                      const float* __restrict__ s8, u16* __restrict__ dstBase) {
  int x = blockIdx.x;
  const float* W; u16* TH; int K, Nc;
  if (x < 384) {                       // W1: 768x512
    W = s0; TH = dstBase; K = D_; Nc = SH_;
  } else if (x < 384 + 4 * 768) {      // conv1 q/k/v/s: 768x1024
    int i = (x - 384) / 768; x = (x - 384) % 768;
    W = (i == 0) ? s1 : (i == 1) ? s2 : (i == 2) ? s3 : s4;
    TH = dstBase + SH_ * D_ + (size_t)i * C_ * D_; K = D_; Nc = C_;
  } else {                             // conv2 q/k/v/s: 1024x1024
    int i = (x - 3456) / 1024; x = (x - 3456) % 1024;
    W = (i == 0) ? s5 : (i == 1) ? s6 : (i == 2) ? s7 : s8;
    TH = dstBase + SH_ * D_ + 4 * (size_t)C_ * D_ + (size_t)i * C_ * C_; K = C_; Nc = C_;
  }
  __shared__ float Ts[32][33];
  int nbk = K >> 5;
  int bk = x % nbk, bn = x / nbk;
  int tid = threadIdx.x;
  int tx = tid & 31, ty = tid >> 5;
  for (int r = ty; r < 32; r += 8)
    Ts[r][tx] = W[(size_t)(bk * 32 + r) * Nc + bn * 32 + tx];
  __syncthreads();
  for (int r = ty; r < 32; r += 8) {
    float v = Ts[tx][r];
    TH[(size_t)(bn * 32 + r) * K + bk * 32 + tx] = bf16_rn(v);
  }
}

// ------------------------------------------------- MFMA GEMM core, BK=64
// (used by k_gemm4_m) 128x128 tile, 4 waves.
__device__ __forceinline__ void gemm_core(
    const float* __restrict__ X, const u16* __restrict__ Bt,
    int K, int row0, int col0,
    u16* Ah, u16* Bh, f32x4 acc[4][4])
{
  int tid = threadIdx.x;
  int lane = tid & 63, w = tid >> 6;

  int aoff[4], boff[4];
#pragma unroll
  for (int i = 0; i < 4; i++) {
    int kc = lane >> 4;
    int rT = (w & 1) * 64 + i * 16 + (lane & 15);
    aoff[i] = rT * 128 + (((kc ^ (rT & 7)) & 7) << 4);
    int cT = (w >> 1) * 64 + i * 16 + (lane & 15);
    boff[i] = cT * 128 + (((kc ^ (cT & 7)) & 7) << 4);
  }

  int nkt = K >> 6;
  for (int kt = 0; kt < nkt; kt++) {
    int k0 = kt << 6;
    if (kt) __syncthreads();
#pragma unroll
    for (int p = 0; p < 8; p++) {
      int idx = tid + p * 256;           // 0..2047
      int r = idx >> 4, c4 = idx & 15;
      float4 v = *(const float4*)&X[(size_t)(row0 + r) * K + k0 + c4 * 4];
      u16x4 hv = {bf16_rn(v.x), bf16_rn(v.y), bf16_rn(v.z), bf16_rn(v.w)};
      int off = r * 128 + ((((c4 >> 1) ^ (r & 7)) & 7) << 4) + (c4 & 1) * 8;
      *(u16x4*)((char*)Ah + off) = hv;
    }
#pragma unroll
    for (int q = 0; q < 4; q++) {
      int rT = w * 32 + q * 8 + (lane >> 3);
      int cs = (lane & 7) ^ (rT & 7);
      size_t gb = (size_t)(col0 + rT) * K + k0 + cs * 8;
      int lb = (w * 32 + q * 8) * 64;
      gload16(&Bt[gb], &Bh[lb]);
    }
    __syncthreads();
    bf16x8 ah0[4], ah1[4];
#pragma unroll
    for (int i = 0; i < 4; i++) {
      ah0[i] = *(const bf16x8*)((const char*)Ah + aoff[i]);
      ah1[i] = *(const bf16x8*)((const char*)Ah + (aoff[i] ^ 64));
    }
#pragma unroll
    for (int j = 0; j < 4; j++) {
      bf16x8 bh0 = *(const bf16x8*)((const char*)Bh + boff[j]);
#pragma unroll
      for (int i = 0; i < 4; i++)
        acc[i][j] = __builtin_amdgcn_mfma_f32_16x16x32_bf16(ah0[i], bh0, acc[i][j], 0, 0, 0);
      bf16x8 bh1 = *(const bf16x8*)((const char*)Bh + (boff[j] ^ 64));
#pragma unroll
      for (int i = 0; i < 4; i++)
        acc[i][j] = __builtin_amdgcn_mfma_f32_16x16x32_bf16(ah1[i], bh1, acc[i][j], 0, 0, 0);
    }
  }
}

// ------------------------------------------------- span MLP: 64x512 tile/block
// grid 512 (row-strips, 2 blocks/CU); 8 waves, wave w owns 64 rows x 64 cols.
// lh read exactly once; full epilogue in-block -> att.
__global__ __launch_bounds__(512, 2) void k_span_m(
    const float* __restrict__ lh, const u16* __restrict__ W1t,
    const float* __restrict__ b1, const float* __restrict__ W2,
    float* __restrict__ att) {
  __shared__ __align__(16) u16 Ah[64 * 64];    // 8 KB
  __shared__ __align__(16) u16 Bh[512 * 64];   // 64 KB
  int row0 = blockIdx.x * 64;
  int tid = threadIdx.x, lane = tid & 63, w = tid >> 6;

  f32x4 acc[4][4];
#pragma unroll
  for (int i = 0; i < 4; i++)
#pragma unroll
    for (int j = 0; j < 4; j++) acc[i][j] = (f32x4){0.f, 0.f, 0.f, 0.f};

  int kc = lane >> 4;
  int aoff[4], boff[4];
#pragma unroll
  for (int i = 0; i < 4; i++) {
    int rT = i * 16 + (lane & 15);
    aoff[i] = rT * 128 + (((kc ^ (rT & 7)) & 7) << 4);
  }
#pragma unroll
  for (int j = 0; j < 4; j++) {
    int cT = w * 64 + j * 16 + (lane & 15);
    boff[j] = cT * 128 + (((kc ^ (cT & 7)) & 7) << 4);
  }

  for (int kt = 0; kt < 12; kt++) {     // K = 768, BK = 64
    int k0 = kt << 6;
    if (kt) __syncthreads();
    // A: 64 rows x 64k from lh (fp32 -> bf16, swizzled); 2 float4/thread
#pragma unroll
    for (int p = 0; p < 2; p++) {
      int idx = tid + p * 512;           // 0..1023
      int r = idx >> 4, c4 = idx & 15;
      float4 v = *(const float4*)&lh[(size_t)(row0 + r) * D_ + k0 + c4 * 4];
      u16x4 hv = {bf16_rn(v.x), bf16_rn(v.y), bf16_rn(v.z), bf16_rn(v.w)};
      int off = r * 128 + ((((c4 >> 1) ^ (r & 7)) & 7) << 4) + (c4 & 1) * 8;
      *(u16x4*)((char*)Ah + off) = hv;
    }
    // B: all 512 W1t rows x 64k via global_load_lds (inverse-swizzled source)
#pragma unroll
    for (int q = 0; q < 8; q++) {
      int rT = w * 64 + q * 8 + (lane >> 3);
      int cs = (lane & 7) ^ (rT & 7);
      size_t gb = (size_t)rT * D_ + k0 + cs * 8;
      int lb = (w * 64 + q * 8) * 64;    // u16 units, wave-uniform
      gload16(&W1t[gb], &Bh[lb]);
    }
    __syncthreads();
    bf16x8 ah0[4], ah1[4];
#pragma unroll
    for (int i = 0; i < 4; i++) {
      ah0[i] = *(const bf16x8*)((const char*)Ah + aoff[i]);
      ah1[i] = *(const bf16x8*)((const char*)Ah + (aoff[i] ^ 64));
    }
#pragma unroll
    for (int j = 0; j < 4; j++) {
      bf16x8 bh0 = *(const bf16x8*)((const char*)Bh + boff[j]);
#pragma unroll
      for (int i = 0; i < 4; i++)
        acc[i][j] = __builtin_amdgcn_mfma_f32_16x16x32_bf16(ah0[i], bh0, acc[i][j], 0, 0, 0);
      bf16x8 bh1 = *(const bf16x8*)((const char*)Bh + (boff[j] ^ 64));
#pragma unroll
      for (int i = 0; i < 4; i++)
        acc[i][j] = __builtin_amdgcn_mfma_f32_16x16x32_bf16(ah1[i], bh1, acc[i][j], 0, 0, 0);
    }
  }

  // epilogue: per-wave row sums over its 64 cols, then cross-wave LDS reduce.
  float b1v[4], w2v[4];
#pragma unroll
  for (int j = 0; j < 4; j++) {
    int col = w * 64 + j * 16 + (lane & 15);
    b1v[j] = b1[col]; w2v[j] = W2[col];
  }
  __syncthreads();                       // done with Ah; reuse as reduce buffer
  float* sred = (float*)Ah;              // [8][64]
#pragma unroll
  for (int i = 0; i < 4; i++) {
#pragma unroll
    for (int r = 0; r < 4; r++) {
      float s = 0.f;
#pragma unroll
      for (int j = 0; j < 4; j++) {
        float h = acc[i][j][r] + b1v[j];
        s += fmaxf(h, 0.f) * w2v[j];
      }
      s += __shfl_xor(s, 1); s += __shfl_xor(s, 2);
      s += __shfl_xor(s, 4); s += __shfl_xor(s, 8);
      if ((lane & 15) == 0)
        sred[w * 64 + i * 16 + (lane >> 4) * 4 + r] = s;
    }
  }
  __syncthreads();
  if (tid < 64) {
    float s = 0.f;
#pragma unroll
    for (int p = 0; p < 8; p++) s += sred[p * 64 + tid];
    att[row0 + tid] = s;
  }
}

// ------------------------------------------------- probs: masked softmax
__global__ void k_probs(const float* __restrict__ att, const float* __restrict__ b2,
                        const float* __restrict__ mask, float* __restrict__ pr) {
  int bi = blockIdx.x >> 2, eg = blockIdx.x & 3;
  int tid = threadIdx.x, lane = tid & 63, w = tid >> 6;
  __shared__ float att_s[512];
  float b2v = b2[0];
  int r0 = bi * 512 + tid;
  att_s[tid] = att[r0] + b2v;
  att_s[tid + 256] = att[r0 + 256] + b2v;
  __syncthreads();
#pragma unroll
  for (int it = 0; it < 2; it++) {
    int e = eg * 8 + it * 4 + w;
    const float* mrow = &mask[(size_t)(bi * E_ + e) * L_];
    float4 m0 = *(const float4*)&mrow[lane * 8];
    float4 m1 = *(const float4*)&mrow[lane * 8 + 4];
    float4 a0 = *(const float4*)&att_s[lane * 8];
    float4 a1 = *(const float4*)&att_s[lane * 8 + 4];
    float v[8];
    v[0] = a0.x - 1e5f * (1.f - m0.x); v[1] = a0.y - 1e5f * (1.f - m0.y);
    v[2] = a0.z - 1e5f * (1.f - m0.z); v[3] = a0.w - 1e5f * (1.f - m0.w);
    v[4] = a1.x - 1e5f * (1.f - m1.x); v[5] = a1.y - 1e5f * (1.f - m1.y);
    v[6] = a1.z - 1e5f * (1.f - m1.z); v[7] = a1.w - 1e5f * (1.f - m1.w);
    float mx = v[0];
#pragma unroll
    for (int i = 1; i < 8; i++) mx = fmaxf(mx, v[i]);
#pragma unroll
    for (int o = 32; o; o >>= 1) mx = fmaxf(mx, __shfl_xor(mx, o));
    float s = 0.f;
#pragma unroll
    for (int i = 0; i < 8; i++) { v[i] = expf(v[i] - mx); s += v[i]; }
#pragma unroll
    for (int o = 32; o; o >>= 1) s += __shfl_xor(s, o);
    float inv = 1.f / s;
    float4 o0 = {v[0] * inv, v[1] * inv, v[2] * inv, v[3] * inv};
    float4 o1 = {v[4] * inv, v[5] * inv, v[6] * inv, v[7] * inv};
    float* prow = &pr[(size_t)(bi * E_ + e) * L_];
    *(float4*)&prow[lane * 8] = o0;
    *(float4*)&prow[lane * 8 + 4] = o1;
  }
}

// ------------------------------------------------- pool via MFMA
__global__ __launch_bounds__(256) void k_pool_m(const float* __restrict__ lh,
    const float* __restrict__ pr, float* __restrict__ node0) {
  __shared__ __align__(16) u16 As[32 * 32];
  __shared__ __align__(16) u16 Bs[32 * 128];
  int bi = blockIdx.x / 6, dc = blockIdx.x % 6;
  int col0 = dc * 128;
  int tid = threadIdx.x, lane = tid & 63, w = tid >> 6;
  const float* lhb = lh + (size_t)bi * L_ * D_;
  const float* prb = pr + (size_t)bi * E_ * L_;

  f32x4 acc[2][2];
#pragma unroll
  for (int m = 0; m < 2; m++)
#pragma unroll
    for (int c = 0; c < 2; c++) acc[m][c] = (f32x4){0.f, 0.f, 0.f, 0.f};

  int aoff[2];
#pragma unroll
  for (int m = 0; m < 2; m++) {
    int kc = lane >> 4;
    int e = m * 16 + (lane & 15);
    aoff[m] = e * 64 + (((kc ^ ((e >> 1) & 3)) & 3) << 4);
  }
  int se = tid >> 3, sk4 = tid & 7;
  int saoff = se * 64 + ((((sk4 >> 1) ^ ((se >> 1) & 3)) & 3) << 4) + (sk4 & 1) * 8;

  for (int kt = 0; kt < 16; kt++) {
    int l0 = kt << 5;
    if (kt) __syncthreads();
    {
      float4 v = *(const float4*)&prb[(size_t)se * L_ + l0 + sk4 * 4];
      u16x4 hv = {bf16_rn(v.x), bf16_rn(v.y), bf16_rn(v.z), bf16_rn(v.w)};
      *(u16x4*)((char*)As + saoff) = hv;
    }
#pragma unroll
    for (int p = 0; p < 4; p++) {
      int idx = tid + p * 256;
      int k = idx >> 5, c4 = idx & 31;
      float4 v = *(const float4*)&lhb[(size_t)(l0 + k) * D_ + col0 + c4 * 4];
      u16x4 hv = {bf16_rn(v.x), bf16_rn(v.y), bf16_rn(v.z), bf16_rn(v.w)};
      *(u16x4*)&Bs[k * 128 + c4 * 4] = hv;
    }
    __syncthreads();
    bf16x8 af[2];
#pragma unroll
    for (int m = 0; m < 2; m++)
      af[m] = *(const bf16x8*)((const char*)As + aoff[m]);
#pragma unroll
    for (int c = 0; c < 2; c++) {
      int colT = w * 32 + c * 16 + (lane & 15);
      int kg = (lane >> 4) * 8;
      union { bf16x8 v; u16 u[8]; } bb;
#pragma unroll
      for (int j = 0; j < 8; j++) bb.u[j] = Bs[(kg + j) * 128 + colT];
#pragma unroll
      for (int m = 0; m < 2; m++)
        acc[m][c] = __builtin_amdgcn_mfma_f32_16x16x32_bf16(af[m], bb.v, acc[m][c], 0, 0, 0);
    }
  }
#pragma unroll
  for (int m = 0; m < 2; m++)
#pragma unroll
    for (int c = 0; c < 2; c++) {
      int col = col0 + w * 32 + c * 16 + (lane & 15);
#pragma unroll
      for (int r = 0; r < 4; r++) {
        int e = m * 16 + (lane >> 4) * 4 + r;
        node0[(size_t)(bi * E_ + e) * D_ + col] = acc[m][c][r];
      }
    }
}

// ------------------------------------------------- fused q/k/v/skip GEMM (MFMA)
__global__ __launch_bounds__(256) void k_gemm4_m(
    const float* __restrict__ X, int K,
    const u16* __restrict__ Wt,
    const float* __restrict__ bb0, const float* __restrict__ bb1,
    const float* __restrict__ bb2, const float* __restrict__ bb3,
    float* __restrict__ O0, float* __restrict__ O1,
    float* __restrict__ O2, float* __restrict__ O3) {
  __shared__ __align__(16) u16 Ah[128 * 64], Bh[128 * 64];
  int rb = blockIdx.x & 15, cbm = blockIdx.x >> 4;
  int mat = cbm >> 3;
  int col0 = (cbm & 7) * 128, row0 = rb * 128;
  const u16* Bt = Wt + (size_t)mat * C_ * K;
  const float* bias; float* O;
  if (mat == 0)      { bias = bb0; O = O0; }
  else if (mat == 1) { bias = bb1; O = O1; }
  else if (mat == 2) { bias = bb2; O = O2; }
  else               { bias = bb3; O = O3; }

  f32x4 acc[4][4];
#pragma unroll
  for (int i = 0; i < 4; i++)
#pragma unroll
    for (int j = 0; j < 4; j++) acc[i][j] = (f32x4){0.f, 0.f, 0.f, 0.f};
  gemm_core(X, Bt, K, row0, col0, Ah, Bh, acc);

  int lane = threadIdx.x & 63, w = threadIdx.x >> 6;
  int wrow = (w & 1) * 64, wcol = (w >> 1) * 64;
#pragma unroll
  for (int j = 0; j < 4; j++) {
    int col = col0 + wcol + j * 16 + (lane & 15);
    float bv = bias[col];
#pragma unroll
    for (int i = 0; i < 4; i++) {
      int rowb = row0 + wrow + i * 16 + (lane >> 4) * 4;
#pragma unroll
      for (int r = 0; r < 4; r++)
        O[(size_t)(rowb + r) * C_ + col] = acc[i][j][r] + bv;
    }
  }
}

// -------------------------------------- edge embedding @ We, rank-3 form
__global__ void k_combo2(const float* __restrict__ Wr1, const float* __restrict__ br1,
                         const float* __restrict__ Wm1, const float* __restrict__ bm1,
                         const float* __restrict__ e1W,
                         const float* __restrict__ Wr2, const float* __restrict__ br2,
                         const float* __restrict__ Wm2, const float* __restrict__ bm2,
                         const float* __restrict__ e2W,
                         float* __restrict__ e1c, float* __restrict__ e2c) {
  int x = blockIdx.x;
  int conv = x >> 6;
  int jb = x & 3, kb = (x >> 2) & 15;
  const float *Wr, *br, *Wm, *bm, *eW; float* out;
  if (conv == 0) { Wr = Wr1; br = br1; Wm = Wm1; bm = bm1; eW = e1W; out = e1c; }
  else           { Wr = Wr2; br = br2; Wm = Wm2; bm = bm2; eW = e2W; out = e2c; }
  int tid = threadIdx.x;
  __shared__ float sw[3][64];
  int k0 = kb * 64;
  if (tid < 64) {
    sw[0][tid] = Wr[k0 + tid];
    sw[1][tid] = Wm[k0 + tid];
    sw[2][tid] = br[k0 + tid] + bm[k0 + tid];
  }
  __syncthreads();
  int j = jb * 256 + tid;
  float a0 = 0.f, a1 = 0.f, a2 = 0.f;
#pragma unroll 8
  for (int kk = 0; kk < 64; kk++) {
    float w = eW[(size_t)(k0 + kk) * C_ + j];
    a0 += sw[0][kk] * w; a1 += sw[1][kk] * w; a2 += sw[2][kk] * w;
  }
#pragma unroll
  for (int c = 0; c < 10; c++)
    atomicAdd(&out[c * C_ + j], (float)(c >> 1) * a0 + (float)(c & 1) * a1 + a2);
}

// ------------------------------------------------- CSR build
__global__ void k_count(const int* __restrict__ dst, int* __restrict__ cnt) {
  int eg = blockIdx.x * 256 + threadIdx.x;
  atomicAdd(&cnt[dst[eg]], 1);
}

__global__ void k_scan(const int* __restrict__ cnt, int* __restrict__ off) {
  __shared__ int part[256];
  int t = threadIdx.x;
  int local[8]; int s = 0;
#pragma unroll
  for (int i = 0; i < 8; i++) { local[i] = cnt[t * 8 + i]; s += local[i]; }
  part[t] = s;
  __syncthreads();
  if (t == 0) {
    int r = 0;
    for (int i = 0; i < 256; i++) { int v = part[i]; part[i] = r; r += v; }
    off[N_] = r;
  }
  __syncthreads();
  int r = part[t];
#pragma unroll
  for (int i = 0; i < 8; i++) { off[t * 8 + i] = r; r += local[i]; }
}

__global__ void k_scatter(const int* __restrict__ dst, int* __restrict__ wcnt,
                          const int* __restrict__ off, int* __restrict__ perm) {
  int eg = blockIdx.x * 256 + threadIdx.x;
  int d = dst[eg];
  int p = atomicAdd(&wcnt[d], 1);
  perm[off[d] + p] = eg;
}

// ------------------------------------------------- per-dst attention agg
__global__ void k_agg(const float* __restrict__ q, const float* __restrict__ k,
                      const float* __restrict__ v, const float* __restrict__ ec,
                      const int* __restrict__ srcA, const float* __restrict__ etype,
                      const float* __restrict__ emain, const int* __restrict__ off,
                      const int* __restrict__ perm, float* __restrict__ O) {
  int dst = blockIdx.x;
  int beg = off[dst];
  int cntE = off[dst + 1] - beg;
  if (cntE == 0) return;
  if (cntE > 128) cntE = 128;
  int tid = threadIdx.x;
  __shared__ float lg[128][8];
  __shared__ int srcs[128];
  __shared__ int cids[128];
  for (int e = tid; e < cntE; e += 256) {
    int eg = perm[beg + e];
    srcs[e] = srcA[eg];
    cids[e] = ((int)(etype[eg] + 0.5f)) * 2 + (int)(emain[eg] + 0.5f);
  }
  __syncthreads();
  int c = tid * 4;
  int h = tid >> 5;
  float4 qv = *(const float4*)&q[dst * C_ + c];
  const float scale = 0.08838834764831845f;  // 1/sqrt(128)
  for (int e = 0; e < cntE; e++) {
    int s = srcs[e], ci = cids[e];
    float4 kv = *(const float4*)&k[s * C_ + c];
    float4 ev = *(const float4*)&ec[ci * C_ + c];
    float p = qv.x * (kv.x + ev.x) + qv.y * (kv.y + ev.y) +
              qv.z * (kv.z + ev.z) + qv.w * (kv.w + ev.w);
#pragma unroll
    for (int o = 16; o; o >>= 1) p += __shfl_xor(p, o);
    if ((tid & 31) == 0) lg[e][h] = p * scale;
  }
  __syncthreads();
  if (tid < 8) {
    float m = -1e30f;
    for (int e = 0; e < cntE; e++) m = fmaxf(m, lg[e][tid]);
    float ssum = 0.f;
    for (int e = 0; e < cntE; e++) { float x = expf(lg[e][tid] - m); lg[e][tid] = x; ssum += x; }
    float inv = 1.f / ssum;
    for (int e = 0; e < cntE; e++) lg[e][tid] *= inv;
  }
  __syncthreads();
  float4 acc = {0.f, 0.f, 0.f, 0.f};
  for (int e = 0; e < cntE; e++) {
    float a = lg[e][h];
    int s = srcs[e], ci = cids[e];
    float4 vv = *(const float4*)&v[s * C_ + c];
    float4 ev = *(const float4*)&ec[ci * C_ + c];
    acc.x += a * (vv.x + ev.x); acc.y += a * (vv.y + ev.y);
    acc.z += a * (vv.z + ev.z); acc.w += a * (vv.w + ev.w);
  }
  float4 o = *(const float4*)&O[dst * C_ + c];
  o.x += acc.x; o.y += acc.y; o.z += acc.z; o.w += acc.w;
  *(float4*)&O[dst * C_ + c] = o;
}

// ------------------------------------------------- final gather + FC
__global__ void k_final(const float* __restrict__ nB, const int* __restrict__ lens,
                        const float* __restrict__ fcW, const float* __restrict__ fcb,
                        float* __restrict__ out) {
  int b = blockIdx.x;
  int idx = lens[b] - 1;
  const float* row = &nB[(b * E_ + idx) * C_];
  int tid = threadIdx.x;
  int c = tid * 4;
  float4 r = *(const float4*)&row[c];
  float4 w0 = *(const float4*)&fcW[(c + 0) * 4];
  float4 w1 = *(const float4*)&fcW[(c + 1) * 4];
  float4 w2 = *(const float4*)&fcW[(c + 2) * 4];
  float4 w3 = *(const float4*)&fcW[(c + 3) * 4];
  float p0 = r.x * w0.x + r.y * w1.x + r.z * w2.x + r.w * w3.x;
  float p1 = r.x * w0.y + r.y * w1.y + r.z * w2.y + r.w * w3.y;
  float p2 = r.x * w0.z + r.y * w1.z + r.z * w2.z + r.w * w3.z;
  float p3 = r.x * w0.w + r.y * w1.w + r.z * w2.w + r.w * w3.w;
#pragma unroll
  for (int o = 32; o; o >>= 1) {
    p0 += __shfl_xor(p0, o); p1 += __shfl_xor(p1, o);
    p2 += __shfl_xor(p2, o); p3 += __shfl_xor(p3, o);
  }
  __shared__ float red[4][4];
  if ((tid & 63) == 0) {
    int w = tid >> 6;
    red[w][0] = p0; red[w][1] = p1; red[w][2] = p2; red[w][3] = p3;
  }
  __syncthreads();
  if (tid == 0) {
#pragma unroll
    for (int j = 0; j < 4; j++)
      out[b * 4 + j] = red[0][j] + red[1][j] + red[2][j] + red[3][j] + fcb[j];
  }
}

// ================================================================ launch
extern "C" void kernel_launch(void* const* d_in, const int* in_sizes, int n_in,
                              void* d_out, int out_size, void* d_ws, size_t ws_size,
                              hipStream_t stream) {
  (void)in_sizes; (void)n_in; (void)out_size; (void)ws_size;
  const float* lh    = (const float*)d_in[0];
  const float* mask  = (const float*)d_in[1];
  const int*   lens  = (const int*)d_in[2];
  const int*   edge  = (const int*)d_in[3];
  const float* etype = (const float*)d_in[4];
  const float* emain = (const float*)d_in[5];
  const float* W1   = (const float*)d_in[6];
  const float* b1   = (const float*)d_in[7];
  const float* W2   = (const float*)d_in[8];
  const float* b2   = (const float*)d_in[9];
  const float* Wr1  = (const float*)d_in[10];
  const float* br1  = (const float*)d_in[11];
  const float* Wm1  = (const float*)d_in[12];
  const float* bm1  = (const float*)d_in[13];
  const float* Wr2  = (const float*)d_in[14];
  const float* br2  = (const float*)d_in[15];
  const float* Wm2  = (const float*)d_in[16];
  const float* bm2  = (const float*)d_in[17];
  const float* q1W  = (const float*)d_in[18];
  const float* q1b  = (const float*)d_in[19];
  const float* k1W  = (const float*)d_in[20];
  const float* k1b  = (const float*)d_in[21];
  const float* v1W  = (const float*)d_in[22];
  const float* v1b  = (const float*)d_in[23];
  const float* e1W  = (const float*)d_in[24];
  const float* s1W  = (const float*)d_in[25];
  const float* s1b  = (const float*)d_in[26];
  const float* q2W  = (const float*)d_in[27];
  const float* q2b  = (const float*)d_in[28];
  const float* k2W  = (const float*)d_in[29];
  const float* k2b  = (const float*)d_in[30];
  const float* v2W  = (const float*)d_in[31];
  const float* v2b  = (const float*)d_in[32];
  const float* e2W  = (const float*)d_in[33];
  const float* s2W  = (const float*)d_in[34];
  const float* s2b  = (const float*)d_in[35];
  const float* fcW  = (const float*)d_in[36];
  const float* fcb  = (const float*)d_in[37];

  float* ws    = (float*)d_ws;
  float* att   = ws;                       // 32768 (span logits, no b2)
  float* node0 = att + 32768;              // 2048*768
  float* e1c   = node0 + ND_;              // 10*1024
  float* e2c   = e1c + 10 * 1024;
  float* qb    = e2c + 10 * 1024;          // 2048*1024 each
  float* kb    = qb + N_ * C_;
  float* vb    = kb + N_ * C_;
  float* nA    = vb + N_ * C_;
  float* nBuf  = nA + N_ * C_;
  int* cnt  = (int*)(nBuf + N_ * C_);      // 2048
  int* wcnt = cnt + N_;                    // 2048
  int* off  = wcnt + N_;                   // 2049 (pad to 2056)
  int* perm = off + (N_ + 8);              // 32768
  u16* wtb  = (u16*)(perm + EG_);          // all 9 bf16 transposed weights
  u16* w1t  = wtb;                         // 512*768
  u16* wt1  = w1t + SH_ * D_;              // 4*1024*768
  u16* wt2  = wt1 + 4 * C_ * D_;           // 4*1024*1024

  // transient alias (consumed before conv1 gemm4 overwrites it)
  float* pr   = qb;                        // probs: 2048*512 fp32

  const int* srcA = edge;
  const int* dstA = edge + EG_;

  // CSR build (shared by both convs)
  (void)hipMemsetAsync(cnt, 0, 2 * N_ * sizeof(int), stream);
  k_count<<<EG_ / 256, 256, 0, stream>>>(dstA, cnt);
  k_scan<<<1, 256, 0, stream>>>(cnt, off);
  k_scatter<<<EG_ / 256, 256, 0, stream>>>(dstA, wcnt, off, perm);

  // weight prep: all 9 transposes in one launch
  k_wt9<<<384 + 4 * 768 + 4 * 1024, 256, 0, stream>>>(
      W1, q1W, k1W, v1W, s1W, q2W, k2W, v2W, s2W, wtb);

  // span attention -> att (full logits, one pass over lh, 2 blocks/CU)
  k_span_m<<<512, 512, 0, stream>>>(lh, w1t, b1, W2, att);

  // 10-combo edge embeddings (rank-3 decomposition)
  (void)hipMemsetAsync(e1c, 0, 20 * C_ * sizeof(float), stream);
  k_combo2<<<128, 256, 0, stream>>>(Wr1, br1, Wm1, bm1, e1W,
                                    Wr2, br2, Wm2, bm2, e2W, e1c, e2c);

  // pooling: probs -> MFMA pool
  k_probs<<<256, 256, 0, stream>>>(att, b2, mask, pr);
  k_pool_m<<<384, 256, 0, stream>>>(lh, pr, node0);

  // conv1
  k_gemm4_m<<<512, 256, 0, stream>>>(node0, D_, wt1,
                                     q1b, k1b, v1b, s1b, qb, kb, vb, nA);
  k_agg<<<N_, 256, 0, stream>>>(qb, kb, vb, e1c, srcA, etype, emain, off, perm, nA);

  // conv2
  k_gemm4_m<<<512, 256, 0, stream>>>(nA, C_, wt2,
                                     q2b, k2b, v2b, s2b, qb, kb, vb, nBuf);
  k_agg<<<N_, 256, 0, stream>>>(qb, kb, vb, e2c, srcA, etype, emain, off, perm, nBuf);

  // final
  k_final<<<B_, 256, 0, stream>>>(nBuf, lens, fcW, fcb, (float*)d_out);
}